// Round 8
// baseline (284.748 us; speedup 1.0000x reference)
//
#include <hip/hip_runtime.h>
#include <cstdint>

// Problem constants (fixed by the reference)
#define N_SEQ 4096
#define DMODEL 1024

#define BM 128
#define BN 128
#define BK 32

typedef __bf16 bf16_t;
typedef _Float16 f16_t;
typedef bf16_t bf16x8 __attribute__((ext_vector_type(8)));
typedef bf16_t bf16x4 __attribute__((ext_vector_type(4)));
typedef f16_t f16x8 __attribute__((ext_vector_type(8)));
typedef f16_t f16x4 __attribute__((ext_vector_type(4)));
typedef float f32x4 __attribute__((ext_vector_type(4)));

typedef __attribute__((address_space(1))) void* as1ptr;
typedef __attribute__((address_space(3))) void* as3ptr;

__device__ __forceinline__ void gload16(const void* g, void* l) {
  __builtin_amdgcn_global_load_lds((as1ptr)(uintptr_t)g, (as3ptr)(uintptr_t)l,
                                   16, 0, 0);
}

// ================= fused QKV projection (z = 0:Q, 1:K, 2:V) =================
// z=0: qp = (qh+ql)@wq16^T + b -> fp16 hi/lo   (fp16 2-pass)
// z=1: kp = (kh+kl)@wk16^T + b -> fp16         (fp16 2-pass)
// z=2: vp = v@wv^T + b -> bf16 transposed      (bf16 1-pass)
// grid (8, 32, 3) = 768 blocks -> 3 blocks/CU.
__global__ __launch_bounds__(256)
void qkv_proj(const f16_t* __restrict__ qh16, const f16_t* __restrict__ ql16,
              const f16_t* __restrict__ wq16, const float* __restrict__ wq_b,
              const f16_t* __restrict__ kh16, const f16_t* __restrict__ kl16,
              const f16_t* __restrict__ wk16, const float* __restrict__ wk_b,
              const bf16_t* __restrict__ v_hi, const bf16_t* __restrict__ wv_hi,
              const float* __restrict__ wv_b,
              f16_t* __restrict__ QPh, f16_t* __restrict__ QPl,
              f16_t* __restrict__ KPh, bf16_t* __restrict__ VPt)
{
  __shared__ __align__(16) uint16_t lds[3 * BM * BK];   // 24 KiB
  uint16_t* lA0 = lds;
  uint16_t* lB0 = lds + BM * BK;
  uint16_t* lA1 = lds + 2 * BM * BK;

  const int z = blockIdx.z;
  const uint16_t *A0, *A1 = nullptr, *B0;
  const float* bias;
  if (z == 0)      { A0 = (const uint16_t*)qh16; A1 = (const uint16_t*)ql16;
                     B0 = (const uint16_t*)wq16; bias = wq_b; }
  else if (z == 1) { A0 = (const uint16_t*)kh16; A1 = (const uint16_t*)kl16;
                     B0 = (const uint16_t*)wk16; bias = wk_b; }
  else             { A0 = (const uint16_t*)v_hi;
                     B0 = (const uint16_t*)wv_hi; bias = wv_b; }
  const bool twop = (z < 2);

  const int M = N_SEQ, Nc = DMODEL, K = DMODEL;
  const int t = threadIdx.x;
  const int lane = t & 63;
  const int wave = t >> 6;
  const int wm = wave >> 1;
  const int wn = wave & 1;
  const int row0 = blockIdx.y * BM;
  const int col0 = blockIdx.x * BN;

  const int srow = t >> 2;
  const int scol = (t & 3) * 8;
  const int loff = srow * BK + scol;

  const int fr = lane & 15;
  const int kq = (lane >> 4) * 8;

  f32x4 acc[4][4] = {};

  for (int k0 = 0; k0 < K; k0 += BK) {
    const size_t ga = (size_t)(row0 + srow) * K + k0 + scol;
    const size_t gb = (size_t)(col0 + srow) * K + k0 + scol;
    gload16(A0 + ga, lA0 + loff);
    gload16(A0 + ga + (size_t)64 * K, lA0 + loff + 64 * BK);
    gload16(B0 + gb, lB0 + loff);
    gload16(B0 + gb + (size_t)64 * K, lB0 + loff + 64 * BK);
    if (twop) {
      gload16(A1 + ga, lA1 + loff);
      gload16(A1 + ga + (size_t)64 * K, lA1 + loff + 64 * BK);
    }
    __syncthreads();

    if (twop) {
      f16x8 ah[4], al[4], bh[4];
#pragma unroll
      for (int m = 0; m < 4; ++m) {
        ah[m] = *(const f16x8*)&lA0[(wm * 64 + m * 16 + fr) * BK + kq];
        al[m] = *(const f16x8*)&lA1[(wm * 64 + m * 16 + fr) * BK + kq];
      }
#pragma unroll
      for (int n = 0; n < 4; ++n)
        bh[n] = *(const f16x8*)&lB0[(wn * 64 + n * 16 + fr) * BK + kq];
#pragma unroll
      for (int m = 0; m < 4; ++m)
#pragma unroll
        for (int n = 0; n < 4; ++n) {
          acc[m][n] = __builtin_amdgcn_mfma_f32_16x16x32_f16(
              ah[m], bh[n], acc[m][n], 0, 0, 0);
          acc[m][n] = __builtin_amdgcn_mfma_f32_16x16x32_f16(
              al[m], bh[n], acc[m][n], 0, 0, 0);
        }
    } else {
      bf16x8 ah[4], bh[4];
#pragma unroll
      for (int m = 0; m < 4; ++m)
        ah[m] = *(const bf16x8*)&lA0[(wm * 64 + m * 16 + fr) * BK + kq];
#pragma unroll
      for (int n = 0; n < 4; ++n)
        bh[n] = *(const bf16x8*)&lB0[(wn * 64 + n * 16 + fr) * BK + kq];
#pragma unroll
      for (int m = 0; m < 4; ++m)
#pragma unroll
        for (int n = 0; n < 4; ++n)
          acc[m][n] = __builtin_amdgcn_mfma_f32_16x16x32_bf16(
              ah[m], bh[n], acc[m][n], 0, 0, 0);
    }
    __syncthreads();
  }

#pragma unroll
  for (int m = 0; m < 4; ++m) {
#pragma unroll
    for (int n = 0; n < 4; ++n) {
      const int grow0 = row0 + wm * 64 + m * 16 + (lane >> 4) * 4;
      const int gcol = col0 + wn * 64 + n * 16 + (lane & 15);
      const float bv = bias[gcol];
      if (z == 2) {
        bf16x4 p;
#pragma unroll
        for (int r = 0; r < 4; ++r) p[r] = (bf16_t)(acc[m][n][r] + bv);
        *(bf16x4*)&VPt[(size_t)gcol * M + grow0] = p;
      } else if (z == 0) {
#pragma unroll
        for (int r = 0; r < 4; ++r) {
          const float val = acc[m][n][r] + bv;
          const size_t idx = (size_t)(grow0 + r) * Nc + gcol;
          const f16_t h = (f16_t)val;
          QPh[idx] = h;
          QPl[idx] = (f16_t)(val - (float)h);
        }
      } else {
#pragma unroll
        for (int r = 0; r < 4; ++r) {
          const float val = acc[m][n][r] + bv;
          KPh[(size_t)(grow0 + r) * Nc + gcol] = (f16_t)val;
        }
      }
    }
  }
}

// ============ split-K bf16 GEMM, 128x64 tile -> fp32 partials ============
// C_part[z][M,Nc] = A[M, kbeg:kend] @ B[Nc, kbeg:kend]^T   (z = blockIdx.z)
// 128x64 tile: grid (Nc/64, M/128, 2) -> 1024 blocks = 4 blocks/CU.
#define BN2 64
__global__ __launch_bounds__(256)
void gemm_sk64(const bf16_t* __restrict__ A, const bf16_t* __restrict__ B,
               float* __restrict__ Part, int M, int Nc, int K, int kspl)
{
  __shared__ __align__(16) bf16_t lds[(BM + BN2) * BK];   // 12 KiB
  bf16_t* lA = lds;
  bf16_t* lB = lds + BM * BK;

  float* out = Part + (size_t)blockIdx.z * M * Nc;
  const int kbeg = blockIdx.z * kspl;
  const int kend = kbeg + kspl;

  const int t = threadIdx.x;
  const int lane = t & 63;
  const int wave = t >> 6;
  const int wm = wave >> 1;     // 0..1 (64-row half)
  const int wn = wave & 1;      // 0..1 (32-col half)
  const int row0 = blockIdx.y * BM;
  const int col0 = blockIdx.x * BN2;

  const int srow = t >> 2;
  const int scol = (t & 3) * 8;
  const int loff = srow * BK + scol;

  const int fr = lane & 15;
  const int kq = (lane >> 4) * 8;

  f32x4 acc[4][2] = {};

  for (int k0 = kbeg; k0 < kend; k0 += BK) {
    const size_t ga = (size_t)(row0 + srow) * K + k0 + scol;
    const size_t gb = (size_t)(col0 + srow) * K + k0 + scol;
    gload16(A + ga, lA + loff);
    gload16(A + ga + (size_t)64 * K, lA + loff + 64 * BK);
    gload16(B + gb, lB + loff);
    __syncthreads();

    bf16x8 ah[4], bh[2];
#pragma unroll
    for (int m = 0; m < 4; ++m)
      ah[m] = *(const bf16x8*)&lA[(wm * 64 + m * 16 + fr) * BK + kq];
#pragma unroll
    for (int n = 0; n < 2; ++n)
      bh[n] = *(const bf16x8*)&lB[(wn * 32 + n * 16 + fr) * BK + kq];

#pragma unroll
    for (int m = 0; m < 4; ++m)
#pragma unroll
      for (int n = 0; n < 2; ++n)
        acc[m][n] =
            __builtin_amdgcn_mfma_f32_16x16x32_bf16(ah[m], bh[n], acc[m][n], 0, 0, 0);
    __syncthreads();
  }

#pragma unroll
  for (int m = 0; m < 4; ++m) {
#pragma unroll
    for (int n = 0; n < 2; ++n) {
      const int grow0 = row0 + wm * 64 + m * 16 + (lane >> 4) * 4;
      const int gcol = col0 + wn * 32 + n * 16 + (lane & 15);
#pragma unroll
      for (int r = 0; r < 4; ++r)
        out[(size_t)(grow0 + r) * Nc + gcol] = acc[m][n][r];
    }
  }
}

// partial reducers
__global__ __launch_bounds__(256)
void reduce_bf16(const float4* __restrict__ p0, const float4* __restrict__ p1,
                 bf16x4* __restrict__ out, int n4)
{
  const int i = blockIdx.x * 256 + threadIdx.x;
  if (i >= n4) return;
  const float4 a = p0[i], b = p1[i];
  bf16x4 r;
  r[0] = (bf16_t)(a.x + b.x);
  r[1] = (bf16_t)(a.y + b.y);
  r[2] = (bf16_t)(a.z + b.z);
  r[3] = (bf16_t)(a.w + b.w);
  out[i] = r;
}

__global__ __launch_bounds__(256)
void reduce_out(const float4* __restrict__ p0, const float4* __restrict__ p1,
                const float* __restrict__ bias, float4* __restrict__ out, int n4)
{
  const int i = blockIdx.x * 256 + threadIdx.x;
  if (i >= n4) return;
  const float4 a = p0[i], b = p1[i];
  const int col = (i * 4) & (DMODEL - 1);
  const float4 bb = *(const float4*)(bias + col);
  float4 r;
  r.x = a.x + b.x + bb.x;
  r.y = a.y + b.y + bb.y;
  r.z = a.z + b.z + bb.z;
  r.w = a.w + b.w + bb.w;
  out[i] = r;
}

// ============ fp16 2-pass 256x256 scores GEMM (R4 structure) ============
#define TILE_ELEMS 16384   // 256 rows x 64 cols
#define UNIT_ELEMS 4096    // 64 rows x 64 cols
#define NT_SC 32

template <int V> struct ic { static constexpr int value = V; };

#define SBAR() asm volatile("s_barrier" ::: "memory")
#define WAITLGKM(n)                                              \
  do {                                                           \
    asm volatile("s_waitcnt lgkmcnt(" #n ")" ::: "memory");      \
    __builtin_amdgcn_sched_barrier(0);                           \
  } while (0)

template <int MH>
__device__ __forceinline__ void load_A8f(const f16_t* Ab, int wm, int fr,
                                         int kq, int sw, f16x8 (&af)[4][2]) {
#pragma unroll
  for (int m = 0; m < 4; ++m) {
    const int row = wm * 128 + (MH * 4 + m) * 16 + fr;
#pragma unroll
    for (int ks = 0; ks < 2; ++ks)
      af[m][ks] = *(const f16x8*)&Ab[row * 64 + ((ks * 32 + kq) ^ sw)];
  }
}

template <int NH>
__device__ __forceinline__ void load_B4f(const f16_t* Bb, int wn, int fr,
                                         int kq, int sw, f16x8 (&bfr)[2][2]) {
#pragma unroll
  for (int n = 0; n < 2; ++n) {
    const int row = wn * 64 + (NH * 2 + n) * 16 + fr;
#pragma unroll
    for (int ks = 0; ks < 2; ++ks)
      bfr[n][ks] = *(const f16x8*)&Bb[row * 64 + ((ks * 32 + kq) ^ sw)];
  }
}

template <int MH, int NH>
__device__ __forceinline__ void mfma16f(const f16x8 (&af)[4][2],
                                        const f16x8 (&bfr)[2][2],
                                        f32x4 (&acc)[8][4]) {
#pragma unroll
  for (int m = 0; m < 4; ++m)
#pragma unroll
    for (int n = 0; n < 2; ++n)
#pragma unroll
      for (int ks = 0; ks < 2; ++ks)
        acc[MH * 4 + m][NH * 2 + n] = __builtin_amdgcn_mfma_f32_16x16x32_f16(
            af[m][ks], bfr[n][ks], acc[MH * 4 + m][NH * 2 + n], 0, 0, 0);
}

__global__ __launch_bounds__(512, 2)
void gemm8f_scores(const f16_t* __restrict__ Qh, const f16_t* __restrict__ Ql,
                   const f16_t* __restrict__ Kh, float* __restrict__ C)
{
  __shared__ __align__(16) f16_t sm[2 * 2 * TILE_ELEMS];  // 128 KiB

  const int t = threadIdx.x;
  const int lane = t & 63;
  const int wave = t >> 6;
  const int wm = wave >> 2;      // 0..1
  const int wn = wave & 3;       // 0..3

  // XCD-aware block swizzle: grid 16x16 = 256 blocks, 256 = 8*32 (bijective)
  const int flat = blockIdx.y * 16 + blockIdx.x;
  const int swzb = (flat & 7) * 32 + (flat >> 3);
  const int brow = (swzb >> 4) * 256;
  const int bcol = (swzb & 15) * 256;

  const int srow = t >> 3;                               // 0..63
  const int scol = 8 * ((t & 7) ^ ((t >> 3) & 7));       // involution
  const int sdst = t * 8;

  const int fr = lane & 15;
  const int kq = (lane >> 4) * 8;
  const int sw = (fr & 7) << 3;                          // read-side swizzle

  auto stageA = [&](int buf, int u, int kt) {
    const f16_t* src = (kt >= 16) ? Ql : Qh;
    const int kk = (kt & 15) << 6;
    gload16(src + (size_t)(brow + u * 64 + srow) * DMODEL + kk + scol,
            &sm[(buf * 2 + 0) * TILE_ELEMS + u * UNIT_ELEMS + sdst]);
  };
  auto stageB = [&](int buf, int u, int kt) {
    const int kk = (kt & 15) << 6;
    gload16(Kh + (size_t)(bcol + u * 64 + srow) * DMODEL + kk + scol,
            &sm[(buf * 2 + 1) * TILE_ELEMS + u * UNIT_ELEMS + sdst]);
  };

  f32x4 acc[8][4] = {};
  f16x8 af0[4][2], af1[4][2];
  f16x8 b0[2][2], b1[2][2];

  // ---- prologue: tile0 all 8 units; tile1's Ua, V01, Ub (6 loads).
#pragma unroll
  for (int u = 0; u < 4; ++u) stageA(0, u, 0);
#pragma unroll
  for (int u = 0; u < 4; ++u) stageB(0, u, 0);
  stageA(1, 0, 1); stageA(1, 2, 1);   // Ua(1)
  stageB(1, 0, 1); stageB(1, 1, 1);   // V01(1)
  stageA(1, 1, 1); stageA(1, 3, 1);   // Ub(1)
  asm volatile("s_waitcnt vmcnt(6)" ::: "memory");  // tile0's 8 landed
  SBAR();

  auto tile = [&](auto Pc, int kt) {
    constexpr int p = decltype(Pc)::value;
    constexpr int q = p ^ 1;
    const bool n1 = (kt + 1 < NT_SC);
    const bool n2 = (kt + 2 < NT_SC);
    const f16_t* Ab = &sm[(p * 2 + 0) * TILE_ELEMS];
    const f16_t* Bb = &sm[(p * 2 + 1) * TILE_ELEMS];

    // ---- Phase 1
    load_A8f<0>(Ab, wm, fr, kq, sw, af0);
    load_B4f<0>(Bb, wn, fr, kq, sw, b0);
    if (n1) { stageB(q, 2, kt + 1); stageB(q, 3, kt + 1); }
    load_B4f<1>(Bb, wn, fr, kq, sw, b1);
    WAITLGKM(4);
    __builtin_amdgcn_s_setprio(1);
    mfma16f<0, 0>(af0, b0, acc);
    __builtin_amdgcn_s_setprio(0);
    __builtin_amdgcn_sched_barrier(0);
    SBAR();

    // ---- Phase 2
    if (n2) { stageA(p, 0, kt + 2); stageA(p, 2, kt + 2); }
    load_A8f<1>(Ab, wm, fr, kq, sw, af1);
    WAITLGKM(8);
    __builtin_amdgcn_s_setprio(1);
    mfma16f<0, 1>(af0, b1, acc);
    __builtin_amdgcn_s_setprio(0);
    __builtin_amdgcn_sched_barrier(0);
    SBAR();

    // ---- Phase 3
    if (n2) { stageB(p, 0, kt + 2); stageB(p, 1, kt + 2); }
    WAITLGKM(0);
    __builtin_amdgcn_s_setprio(1);
    mfma16f<1, 0>(af1, b0, acc);
    __builtin_amdgcn_s_setprio(0);
    __builtin_amdgcn_sched_barrier(0);
    SBAR();

    // ---- Phase 4
    if (n2) { stageA(p, 1, kt + 2); stageA(p, 3, kt + 2); }
    __builtin_amdgcn_s_setprio(1);
    mfma16f<1, 1>(af1, b1, acc);
    __builtin_amdgcn_s_setprio(0);
    __builtin_amdgcn_sched_barrier(0);
    if (n2)      asm volatile("s_waitcnt vmcnt(6)" ::: "memory");
    else if (n1) asm volatile("s_waitcnt vmcnt(0)" ::: "memory");
    SBAR();
  };

  for (int kt = 0; kt < NT_SC; kt += 2) {
    tile(ic<0>{}, kt);
    tile(ic<1>{}, kt + 1);
  }

  // ---- epilogue
#pragma unroll
  for (int mf = 0; mf < 8; ++mf) {
#pragma unroll
    for (int nf = 0; nf < 4; ++nf) {
      const int r0 = brow + wm * 128 + mf * 16 + (lane >> 4) * 4;
      const int c  = bcol + wn * 64 + nf * 16 + (lane & 15);
#pragma unroll
      for (int r = 0; r < 4; ++r)
        C[(size_t)(r0 + r) * N_SEQ + c] = acc[mf][nf][r];
    }
  }
}

// ======================= fused split =======================
// mode: 0 = bf16 hi only, 2 = fp16 hi/lo, 3 = fp16 hi only
struct SplitDesc {
  const float* src[7];
  void* hi[7];
  void* lo[7];
  int mode[7];
  int blk_start[8];
};

__global__ __launch_bounds__(256)
void split_all(SplitDesc d)
{
  const int b = blockIdx.x;
  int seg = 0;
#pragma unroll
  for (int s = 1; s < 7; ++s) seg += (b >= d.blk_start[s]) ? 1 : 0;
  const int i = (b - d.blk_start[seg]) * 256 + threadIdx.x;
  const float4 v = ((const float4*)d.src[seg])[i];
  const float vv[4] = {v.x, v.y, v.z, v.w};
  const int mode = d.mode[seg];
  if (mode == 0) {
    bf16x4 h;
#pragma unroll
    for (int j = 0; j < 4; ++j) h[j] = (bf16_t)vv[j];
    ((bf16x4*)d.hi[seg])[i] = h;
  } else {
    f16x4 h, l;
#pragma unroll
    for (int j = 0; j < 4; ++j) {
      const f16_t hh = (f16_t)vv[j];
      h[j] = hh;
      l[j] = (f16_t)(vv[j] - (float)hh);
    }
    ((f16x4*)d.hi[seg])[i] = h;
    if (mode == 2) ((f16x4*)d.lo[seg])[i] = l;
  }
}

// ======================= softmax =======================
__global__ __launch_bounds__(256)
void softmax_rows(float* __restrict__ S, bf16_t* __restrict__ P, int n)
{
  const int row = blockIdx.x;
  float* srow = S + (size_t)row * n;
  bf16_t* prow = P + (size_t)row * n;
  const int t = threadIdx.x;
  const int lane = t & 63;
  const int wave = t >> 6;
  __shared__ float red[8];

  float4 v[4];
  float mx = -3.4e38f;
#pragma unroll
  for (int i = 0; i < 4; ++i) {
    v[i] = *(const float4*)(srow + (size_t)(i * 256 + t) * 4);
    mx = fmaxf(mx, fmaxf(fmaxf(v[i].x, v[i].y), fmaxf(v[i].z, v[i].w)));
  }
#pragma unroll
  for (int off = 32; off > 0; off >>= 1) mx = fmaxf(mx, __shfl_xor(mx, off));
  if (lane == 0) red[wave] = mx;
  __syncthreads();
  mx = fmaxf(fmaxf(red[0], red[1]), fmaxf(red[2], red[3]));

  float e[16];
  float sum = 0.f;
#pragma unroll
  for (int i = 0; i < 4; ++i) {
    e[4 * i + 0] = __expf(v[i].x - mx);
    e[4 * i + 1] = __expf(v[i].y - mx);
    e[4 * i + 2] = __expf(v[i].z - mx);
    e[4 * i + 3] = __expf(v[i].w - mx);
    sum += e[4 * i + 0] + e[4 * i + 1] + e[4 * i + 2] + e[4 * i + 3];
  }
#pragma unroll
  for (int off = 32; off > 0; off >>= 1) sum += __shfl_xor(sum, off);
  if (lane == 0) red[4 + wave] = sum;
  __syncthreads();
  sum = red[4] + red[5] + red[6] + red[7];
  const float inv = 1.0f / sum;

#pragma unroll
  for (int i = 0; i < 4; ++i) {
    float4 w;
    w.x = e[4 * i + 0] * inv;
    w.y = e[4 * i + 1] * inv;
    w.z = e[4 * i + 2] * inv;
    w.w = e[4 * i + 3] * inv;
    *(float4*)(srow + (size_t)(i * 256 + t) * 4) = w;
    bf16x4 p;
    p[0] = (bf16_t)w.x;
    p[1] = (bf16_t)w.y;
    p[2] = (bf16_t)w.z;
    p[3] = (bf16_t)w.w;
    *(bf16x4*)(prow + (size_t)(i * 256 + t) * 4) = p;
  }
}

extern "C" void kernel_launch(void* const* d_in, const int* in_sizes, int n_in,
                              void* d_out, int out_size, void* d_ws, size_t ws_size,
                              hipStream_t stream) {
  const int N = N_SEQ, D = DMODEL;
  const float* q    = (const float*)d_in[0];
  const float* k    = (const float*)d_in[1];
  const float* v    = (const float*)d_in[2];
  const float* wq_w = (const float*)d_in[3];
  const float* wq_b = (const float*)d_in[4];
  const float* wk_w = (const float*)d_in[5];
  const float* wk_b = (const float*)d_in[6];
  const float* wv_w = (const float*)d_in[7];
  const float* wv_b = (const float*)d_in[8];
  const float* wo_w = (const float*)d_in[9];
  const float* wo_b = (const float*)d_in[10];

  float* x_out = (float*)d_out;                 // [N, D]
  float* attn  = x_out + (size_t)N * D;         // [N, N]

  char* wsp = (char*)d_ws;
  auto alloc = [&](size_t bytes) { char* p = wsp; wsp += bytes; return p; };
  const size_t ND = (size_t)N * D, DD = (size_t)D * D;
  f16_t*  qh16  = (f16_t*)alloc(ND * 2);
  f16_t*  ql16  = (f16_t*)alloc(ND * 2);
  f16_t*  kh16  = (f16_t*)alloc(ND * 2);
  f16_t*  kl16  = (f16_t*)alloc(ND * 2);
  bf16_t* v_hi  = (bf16_t*)alloc(ND * 2);
  f16_t*  wq16  = (f16_t*)alloc(DD * 2);
  f16_t*  wk16  = (f16_t*)alloc(DD * 2);
  bf16_t* wv_hi = (bf16_t*)alloc(DD * 2);
  bf16_t* wo_hi = (bf16_t*)alloc(DD * 2);
  f16_t*  QPh   = (f16_t*)alloc(ND * 2);        // fp16 qp hi
  f16_t*  QPl   = (f16_t*)alloc(ND * 2);        // fp16 qp lo
  f16_t*  KPh   = (f16_t*)alloc(ND * 2);        // fp16 kp
  bf16_t* spare = (bf16_t*)alloc(ND * 2);       // pad (keeps Pb region 32MB)
  bf16_t* VPt   = (bf16_t*)alloc(ND * 2);       // [D][N] transposed
  // aliases (producers run strictly after last readers of the underlying bufs)
  bf16_t* Pb    = (bf16_t*)QPh;  // 32 MB over QPh..spare (dead after scores)
  float*  Part  = (float*)qh16;  // 32 MB over qh16..kl16 (dead after qkv_proj)
  bf16_t* Xb    = v_hi;          // 8 MB over v_hi (dead after qkv_proj)
  (void)spare;

  // fused split: q,k -> fp16 hi+lo; wq,wk -> fp16; v,wv,wo -> bf16
  SplitDesc sd;
  sd.src[0] = q;    sd.hi[0] = qh16;  sd.lo[0] = ql16;    sd.mode[0] = 2;
  sd.src[1] = k;    sd.hi[1] = kh16;  sd.lo[1] = kl16;    sd.mode[1] = 2;
  sd.src[2] = v;    sd.hi[2] = v_hi;  sd.lo[2] = nullptr; sd.mode[2] = 0;
  sd.src[3] = wq_w; sd.hi[3] = wq16;  sd.lo[3] = nullptr; sd.mode[3] = 3;
  sd.src[4] = wk_w; sd.hi[4] = wk16;  sd.lo[4] = nullptr; sd.mode[4] = 3;
  sd.src[5] = wv_w; sd.hi[5] = wv_hi; sd.lo[5] = nullptr; sd.mode[5] = 0;
  sd.src[6] = wo_w; sd.hi[6] = wo_hi; sd.lo[6] = nullptr; sd.mode[6] = 0;
  const int nb_nd = (int)(ND / 4 / 256);   // 4096
  const int nb_dd = (int)(DD / 4 / 256);   // 1024
  sd.blk_start[0] = 0;
  sd.blk_start[1] = nb_nd;
  sd.blk_start[2] = 2 * nb_nd;
  sd.blk_start[3] = 3 * nb_nd;
  sd.blk_start[4] = 3 * nb_nd + nb_dd;
  sd.blk_start[5] = 3 * nb_nd + 2 * nb_dd;
  sd.blk_start[6] = 3 * nb_nd + 3 * nb_dd;
  sd.blk_start[7] = 3 * nb_nd + 4 * nb_dd;
  split_all<<<dim3(sd.blk_start[7]), dim3(256), 0, stream>>>(sd);

  const dim3 blk(256);
  const dim3 gsc(N / 256, N / 256);    // (16, 16)
  const int n4 = (int)(ND / 4);        // 1048576
  const dim3 gred((n4 + 255) / 256);

  // fused Q/K/V projections: grid (8,32,3) -> 3 blocks/CU
  qkv_proj<<<dim3(D / BN, N / BM, 3), blk, 0, stream>>>(
      qh16, ql16, wq16, wq_b,
      kh16, kl16, wk16, wk_b,
      v_hi, wv_hi, wv_b,
      QPh, QPl, KPh, VPt);

  // scores = (Qh+Ql) @ Kh^T  (fp16 2-pass, logical K=2048)
  gemm8f_scores<<<gsc, dim3(512), 0, stream>>>(QPh, QPl, KPh, attn);

  // softmax rows in-place + bf16 copy (Pb aliases QP/KP region: dead now)
  softmax_rows<<<dim3(N), blk, 0, stream>>>(attn, Pb, N);

  // X = P @ VP  (128x64 tile, split-K=2 -> fp32 partials -> bf16 Xb)
  gemm_sk64<<<dim3(D / BN2, N / BM, 2), blk, 0, stream>>>(
      Pb, VPt, Part, N, D, N, N / 2);
  reduce_bf16<<<gred, blk, 0, stream>>>(
      (const float4*)Part, (const float4*)(Part + ND), (bf16x4*)Xb, n4);

  // out = X @ wo^T + b  (128x64 tile, split-K=2 -> partials -> +bias -> d_out)
  gemm_sk64<<<dim3(D / BN2, N / BM, 2), blk, 0, stream>>>(
      Xb, wo_hi, Part, N, D, D, D / 2);
  reduce_out<<<gred, blk, 0, stream>>>(
      (const float4*)Part, (const float4*)(Part + ND), wo_b,
      (float4*)x_out, n4);
}

// Round 9
// 268.598 us; speedup vs baseline: 1.0601x; 1.0601x over previous
//
#include <hip/hip_runtime.h>
#include <cstdint>

// Problem constants (fixed by the reference)
#define N_SEQ 4096
#define DMODEL 1024

#define BM 128
#define BN 128
#define BK 32

typedef __bf16 bf16_t;
typedef _Float16 f16_t;
typedef f16_t f16x8 __attribute__((ext_vector_type(8)));
typedef f16_t f16x4 __attribute__((ext_vector_type(4)));
typedef float f32x4 __attribute__((ext_vector_type(4)));

typedef __attribute__((address_space(1))) void* as1ptr;
typedef __attribute__((address_space(3))) void* as3ptr;

__device__ __forceinline__ void gload16(const void* g, void* l) {
  __builtin_amdgcn_global_load_lds((as1ptr)(uintptr_t)g, (as3ptr)(uintptr_t)l,
                                   16, 0, 0);
}

// ================= fused QKV projection (z = 0:Q, 1:K, 2:V) =================
// All-fp16.  z=0: qp=(qh+ql)@wq^T+b -> fp16 hi/lo  (2-pass)
//            z=1: kp=(kh+kl)@wk^T+b -> fp16        (2-pass)
//            z=2: vp=vh@wv^T+b      -> fp16 transposed (1-pass)
// grid (8, 32, 3) = 768 blocks -> 3 blocks/CU.  Single fragment dtype ->
// register reuse across the twop branch (R8's mixed-dtype VGPR bloat fixed).
__global__ __launch_bounds__(256)
void qkv_proj(const f16_t* __restrict__ qh, const f16_t* __restrict__ ql,
              const f16_t* __restrict__ wq, const float* __restrict__ wq_b,
              const f16_t* __restrict__ kh, const f16_t* __restrict__ kl,
              const f16_t* __restrict__ wk, const float* __restrict__ wk_b,
              const f16_t* __restrict__ vh, const f16_t* __restrict__ wv,
              const float* __restrict__ wv_b,
              f16_t* __restrict__ QPh, f16_t* __restrict__ QPl,
              f16_t* __restrict__ KPh, f16_t* __restrict__ VPt)
{
  __shared__ __align__(16) f16_t lds[3 * BM * BK];   // 24 KiB
  f16_t* lA0 = lds;
  f16_t* lB0 = lds + BM * BK;
  f16_t* lA1 = lds + 2 * BM * BK;

  const int z = blockIdx.z;
  const f16_t *A0, *A1 = nullptr, *B0;
  const float* bias;
  if (z == 0)      { A0 = qh; A1 = ql; B0 = wq; bias = wq_b; }
  else if (z == 1) { A0 = kh; A1 = kl; B0 = wk; bias = wk_b; }
  else             { A0 = vh;          B0 = wv; bias = wv_b; }
  const bool twop = (z < 2);

  const int M = N_SEQ, Nc = DMODEL, K = DMODEL;
  const int t = threadIdx.x;
  const int lane = t & 63;
  const int wave = t >> 6;
  const int wm = wave >> 1;
  const int wn = wave & 1;
  const int row0 = blockIdx.y * BM;
  const int col0 = blockIdx.x * BN;

  const int srow = t >> 2;
  const int scol = (t & 3) * 8;
  const int loff = srow * BK + scol;

  const int fr = lane & 15;
  const int kq = (lane >> 4) * 8;

  f32x4 acc[4][4] = {};

  for (int k0 = 0; k0 < K; k0 += BK) {
    const size_t ga = (size_t)(row0 + srow) * K + k0 + scol;
    const size_t gb = (size_t)(col0 + srow) * K + k0 + scol;
    gload16(A0 + ga, lA0 + loff);
    gload16(A0 + ga + (size_t)64 * K, lA0 + loff + 64 * BK);
    gload16(B0 + gb, lB0 + loff);
    gload16(B0 + gb + (size_t)64 * K, lB0 + loff + 64 * BK);
    if (twop) {
      gload16(A1 + ga, lA1 + loff);
      gload16(A1 + ga + (size_t)64 * K, lA1 + loff + 64 * BK);
    }
    __syncthreads();

    f16x8 ah[4], al[4], bh[4];
#pragma unroll
    for (int m = 0; m < 4; ++m)
      ah[m] = *(const f16x8*)&lA0[(wm * 64 + m * 16 + fr) * BK + kq];
#pragma unroll
    for (int n = 0; n < 4; ++n)
      bh[n] = *(const f16x8*)&lB0[(wn * 64 + n * 16 + fr) * BK + kq];
    if (twop) {
#pragma unroll
      for (int m = 0; m < 4; ++m)
        al[m] = *(const f16x8*)&lA1[(wm * 64 + m * 16 + fr) * BK + kq];
    }

#pragma unroll
    for (int m = 0; m < 4; ++m)
#pragma unroll
      for (int n = 0; n < 4; ++n) {
        acc[m][n] = __builtin_amdgcn_mfma_f32_16x16x32_f16(
            ah[m], bh[n], acc[m][n], 0, 0, 0);
        if (twop)
          acc[m][n] = __builtin_amdgcn_mfma_f32_16x16x32_f16(
              al[m], bh[n], acc[m][n], 0, 0, 0);
      }
    __syncthreads();
  }

#pragma unroll
  for (int m = 0; m < 4; ++m) {
#pragma unroll
    for (int n = 0; n < 4; ++n) {
      const int grow0 = row0 + wm * 64 + m * 16 + (lane >> 4) * 4;
      const int gcol = col0 + wn * 64 + n * 16 + (lane & 15);
      const float bv = bias[gcol];
      if (z == 2) {
        f16x4 p;
#pragma unroll
        for (int r = 0; r < 4; ++r) p[r] = (f16_t)(acc[m][n][r] + bv);
        *(f16x4*)&VPt[(size_t)gcol * M + grow0] = p;
      } else if (z == 0) {
#pragma unroll
        for (int r = 0; r < 4; ++r) {
          const float val = acc[m][n][r] + bv;
          const size_t idx = (size_t)(grow0 + r) * Nc + gcol;
          const f16_t h = (f16_t)val;
          QPh[idx] = h;
          QPl[idx] = (f16_t)(val - (float)h);
        }
      } else {
#pragma unroll
        for (int r = 0; r < 4; ++r) {
          const float val = acc[m][n][r] + bv;
          KPh[(size_t)(grow0 + r) * Nc + gcol] = (f16_t)val;
        }
      }
    }
  }
}

// ========== split-K fp16 GEMM, 128x64 tile -> fp32 partials ==========
// C_part[z][M,Nc] = A[M, kbeg:kend] @ B[Nc, kbeg:kend]^T   (z = blockIdx.z)
#define BN2 64
__global__ __launch_bounds__(256)
void gemm_sk64f(const f16_t* __restrict__ A, const f16_t* __restrict__ B,
                float* __restrict__ Part, int M, int Nc, int K, int kspl)
{
  __shared__ __align__(16) f16_t lds[(BM + BN2) * BK];   // 12 KiB
  f16_t* lA = lds;
  f16_t* lB = lds + BM * BK;

  float* out = Part + (size_t)blockIdx.z * M * Nc;
  const int kbeg = blockIdx.z * kspl;
  const int kend = kbeg + kspl;

  const int t = threadIdx.x;
  const int lane = t & 63;
  const int wave = t >> 6;
  const int wm = wave >> 1;     // 0..1 (64-row half)
  const int wn = wave & 1;      // 0..1 (32-col half)
  const int row0 = blockIdx.y * BM;
  const int col0 = blockIdx.x * BN2;

  const int srow = t >> 2;
  const int scol = (t & 3) * 8;
  const int loff = srow * BK + scol;

  const int fr = lane & 15;
  const int kq = (lane >> 4) * 8;

  f32x4 acc[4][2] = {};

  for (int k0 = kbeg; k0 < kend; k0 += BK) {
    const size_t ga = (size_t)(row0 + srow) * K + k0 + scol;
    const size_t gb = (size_t)(col0 + srow) * K + k0 + scol;
    gload16(A + ga, lA + loff);
    gload16(A + ga + (size_t)64 * K, lA + loff + 64 * BK);
    gload16(B + gb, lB + loff);
    __syncthreads();

    f16x8 ah[4], bh[2];
#pragma unroll
    for (int m = 0; m < 4; ++m)
      ah[m] = *(const f16x8*)&lA[(wm * 64 + m * 16 + fr) * BK + kq];
#pragma unroll
    for (int n = 0; n < 2; ++n)
      bh[n] = *(const f16x8*)&lB[(wn * 32 + n * 16 + fr) * BK + kq];

#pragma unroll
    for (int m = 0; m < 4; ++m)
#pragma unroll
      for (int n = 0; n < 2; ++n)
        acc[m][n] =
            __builtin_amdgcn_mfma_f32_16x16x32_f16(ah[m], bh[n], acc[m][n], 0, 0, 0);
    __syncthreads();
  }

#pragma unroll
  for (int m = 0; m < 4; ++m) {
#pragma unroll
    for (int n = 0; n < 2; ++n) {
      const int grow0 = row0 + wm * 64 + m * 16 + (lane >> 4) * 4;
      const int gcol = col0 + wn * 32 + n * 16 + (lane & 15);
#pragma unroll
      for (int r = 0; r < 4; ++r)
        out[(size_t)(grow0 + r) * Nc + gcol] = acc[m][n][r];
    }
  }
}

// partial reducers
__global__ __launch_bounds__(256)
void reduce_f16(const float4* __restrict__ p0, const float4* __restrict__ p1,
                f16x4* __restrict__ out, int n4)
{
  const int i = blockIdx.x * 256 + threadIdx.x;
  if (i >= n4) return;
  const float4 a = p0[i], b = p1[i];
  f16x4 r;
  r[0] = (f16_t)(a.x + b.x);
  r[1] = (f16_t)(a.y + b.y);
  r[2] = (f16_t)(a.z + b.z);
  r[3] = (f16_t)(a.w + b.w);
  out[i] = r;
}

__global__ __launch_bounds__(256)
void reduce_out(const float4* __restrict__ p0, const float4* __restrict__ p1,
                const float* __restrict__ bias, float4* __restrict__ out, int n4)
{
  const int i = blockIdx.x * 256 + threadIdx.x;
  if (i >= n4) return;
  const float4 a = p0[i], b = p1[i];
  const int col = (i * 4) & (DMODEL - 1);
  const float4 bb = *(const float4*)(bias + col);
  float4 r;
  r.x = a.x + b.x + bb.x;
  r.y = a.y + b.y + bb.y;
  r.z = a.z + b.z + bb.z;
  r.w = a.w + b.w + bb.w;
  out[i] = r;
}

// ============ fp16 2-pass 256x256 scores GEMM (R4 structure) ============
#define TILE_ELEMS 16384   // 256 rows x 64 cols
#define UNIT_ELEMS 4096    // 64 rows x 64 cols
#define NT_SC 32

template <int V> struct ic { static constexpr int value = V; };

#define SBAR() asm volatile("s_barrier" ::: "memory")
#define WAITLGKM(n)                                              \
  do {                                                           \
    asm volatile("s_waitcnt lgkmcnt(" #n ")" ::: "memory");      \
    __builtin_amdgcn_sched_barrier(0);                           \
  } while (0)

template <int MH>
__device__ __forceinline__ void load_A8f(const f16_t* Ab, int wm, int fr,
                                         int kq, int sw, f16x8 (&af)[4][2]) {
#pragma unroll
  for (int m = 0; m < 4; ++m) {
    const int row = wm * 128 + (MH * 4 + m) * 16 + fr;
#pragma unroll
    for (int ks = 0; ks < 2; ++ks)
      af[m][ks] = *(const f16x8*)&Ab[row * 64 + ((ks * 32 + kq) ^ sw)];
  }
}

template <int NH>
__device__ __forceinline__ void load_B4f(const f16_t* Bb, int wn, int fr,
                                         int kq, int sw, f16x8 (&bfr)[2][2]) {
#pragma unroll
  for (int n = 0; n < 2; ++n) {
    const int row = wn * 64 + (NH * 2 + n) * 16 + fr;
#pragma unroll
    for (int ks = 0; ks < 2; ++ks)
      bfr[n][ks] = *(const f16x8*)&Bb[row * 64 + ((ks * 32 + kq) ^ sw)];
  }
}

template <int MH, int NH>
__device__ __forceinline__ void mfma16f(const f16x8 (&af)[4][2],
                                        const f16x8 (&bfr)[2][2],
                                        f32x4 (&acc)[8][4]) {
#pragma unroll
  for (int m = 0; m < 4; ++m)
#pragma unroll
    for (int n = 0; n < 2; ++n)
#pragma unroll
      for (int ks = 0; ks < 2; ++ks)
        acc[MH * 4 + m][NH * 2 + n] = __builtin_amdgcn_mfma_f32_16x16x32_f16(
            af[m][ks], bfr[n][ks], acc[MH * 4 + m][NH * 2 + n], 0, 0, 0);
}

__global__ __launch_bounds__(512, 2)
void gemm8f_scores(const f16_t* __restrict__ Qh, const f16_t* __restrict__ Ql,
                   const f16_t* __restrict__ Kh, float* __restrict__ C)
{
  __shared__ __align__(16) f16_t sm[2 * 2 * TILE_ELEMS];  // 128 KiB

  const int t = threadIdx.x;
  const int lane = t & 63;
  const int wave = t >> 6;
  const int wm = wave >> 2;      // 0..1
  const int wn = wave & 3;       // 0..3

  // XCD-aware block swizzle: grid 16x16 = 256 blocks, 256 = 8*32 (bijective)
  const int flat = blockIdx.y * 16 + blockIdx.x;
  const int swzb = (flat & 7) * 32 + (flat >> 3);
  const int brow = (swzb >> 4) * 256;
  const int bcol = (swzb & 15) * 256;

  const int srow = t >> 3;                               // 0..63
  const int scol = 8 * ((t & 7) ^ ((t >> 3) & 7));       // involution
  const int sdst = t * 8;

  const int fr = lane & 15;
  const int kq = (lane >> 4) * 8;
  const int sw = (fr & 7) << 3;                          // read-side swizzle

  auto stageA = [&](int buf, int u, int kt) {
    const f16_t* src = (kt >= 16) ? Ql : Qh;
    const int kk = (kt & 15) << 6;
    gload16(src + (size_t)(brow + u * 64 + srow) * DMODEL + kk + scol,
            &sm[(buf * 2 + 0) * TILE_ELEMS + u * UNIT_ELEMS + sdst]);
  };
  auto stageB = [&](int buf, int u, int kt) {
    const int kk = (kt & 15) << 6;
    gload16(Kh + (size_t)(bcol + u * 64 + srow) * DMODEL + kk + scol,
            &sm[(buf * 2 + 1) * TILE_ELEMS + u * UNIT_ELEMS + sdst]);
  };

  f32x4 acc[8][4] = {};
  f16x8 af0[4][2], af1[4][2];
  f16x8 b0[2][2], b1[2][2];

  // ---- prologue: tile0 all 8 units; tile1's Ua, V01, Ub (6 loads).
#pragma unroll
  for (int u = 0; u < 4; ++u) stageA(0, u, 0);
#pragma unroll
  for (int u = 0; u < 4; ++u) stageB(0, u, 0);
  stageA(1, 0, 1); stageA(1, 2, 1);   // Ua(1)
  stageB(1, 0, 1); stageB(1, 1, 1);   // V01(1)
  stageA(1, 1, 1); stageA(1, 3, 1);   // Ub(1)
  asm volatile("s_waitcnt vmcnt(6)" ::: "memory");  // tile0's 8 landed
  SBAR();

  auto tile = [&](auto Pc, int kt) {
    constexpr int p = decltype(Pc)::value;
    constexpr int q = p ^ 1;
    const bool n1 = (kt + 1 < NT_SC);
    const bool n2 = (kt + 2 < NT_SC);
    const f16_t* Ab = &sm[(p * 2 + 0) * TILE_ELEMS];
    const f16_t* Bb = &sm[(p * 2 + 1) * TILE_ELEMS];

    // ---- Phase 1
    load_A8f<0>(Ab, wm, fr, kq, sw, af0);
    load_B4f<0>(Bb, wn, fr, kq, sw, b0);
    if (n1) { stageB(q, 2, kt + 1); stageB(q, 3, kt + 1); }
    load_B4f<1>(Bb, wn, fr, kq, sw, b1);
    WAITLGKM(4);
    __builtin_amdgcn_s_setprio(1);
    mfma16f<0, 0>(af0, b0, acc);
    __builtin_amdgcn_s_setprio(0);
    __builtin_amdgcn_sched_barrier(0);
    SBAR();

    // ---- Phase 2
    if (n2) { stageA(p, 0, kt + 2); stageA(p, 2, kt + 2); }
    load_A8f<1>(Ab, wm, fr, kq, sw, af1);
    WAITLGKM(8);
    __builtin_amdgcn_s_setprio(1);
    mfma16f<0, 1>(af0, b1, acc);
    __builtin_amdgcn_s_setprio(0);
    __builtin_amdgcn_sched_barrier(0);
    SBAR();

    // ---- Phase 3
    if (n2) { stageB(p, 0, kt + 2); stageB(p, 1, kt + 2); }
    WAITLGKM(0);
    __builtin_amdgcn_s_setprio(1);
    mfma16f<1, 0>(af1, b0, acc);
    __builtin_amdgcn_s_setprio(0);
    __builtin_amdgcn_sched_barrier(0);
    SBAR();

    // ---- Phase 4
    if (n2) { stageA(p, 1, kt + 2); stageA(p, 3, kt + 2); }
    __builtin_amdgcn_s_setprio(1);
    mfma16f<1, 1>(af1, b1, acc);
    __builtin_amdgcn_s_setprio(0);
    __builtin_amdgcn_sched_barrier(0);
    if (n2)      asm volatile("s_waitcnt vmcnt(6)" ::: "memory");
    else if (n1) asm volatile("s_waitcnt vmcnt(0)" ::: "memory");
    SBAR();
  };

  for (int kt = 0; kt < NT_SC; kt += 2) {
    tile(ic<0>{}, kt);
    tile(ic<1>{}, kt + 1);
  }

  // ---- epilogue
#pragma unroll
  for (int mf = 0; mf < 8; ++mf) {
#pragma unroll
    for (int nf = 0; nf < 4; ++nf) {
      const int r0 = brow + wm * 128 + mf * 16 + (lane >> 4) * 4;
      const int c  = bcol + wn * 64 + nf * 16 + (lane & 15);
#pragma unroll
      for (int r = 0; r < 4; ++r)
        C[(size_t)(r0 + r) * N_SEQ + c] = acc[mf][nf][r];
    }
  }
}

// ======================= fused split (all fp16) =======================
// mode: 2 = fp16 hi/lo, 3 = fp16 hi only
struct SplitDesc {
  const float* src[7];
  f16_t* hi[7];
  f16_t* lo[7];
  int mode[7];
  int blk_start[8];
};

__global__ __launch_bounds__(256)
void split_all(SplitDesc d)
{
  const int b = blockIdx.x;
  int seg = 0;
#pragma unroll
  for (int s = 1; s < 7; ++s) seg += (b >= d.blk_start[s]) ? 1 : 0;
  const int i = (b - d.blk_start[seg]) * 256 + threadIdx.x;
  const float4 v = ((const float4*)d.src[seg])[i];
  const float vv[4] = {v.x, v.y, v.z, v.w};
  f16x4 h, l;
#pragma unroll
  for (int j = 0; j < 4; ++j) {
    const f16_t hh = (f16_t)vv[j];
    h[j] = hh;
    l[j] = (f16_t)(vv[j] - (float)hh);
  }
  ((f16x4*)d.hi[seg])[i] = h;
  if (d.mode[seg] == 2) ((f16x4*)d.lo[seg])[i] = l;
}

// ======================= softmax =======================
__global__ __launch_bounds__(256)
void softmax_rows(float* __restrict__ S, f16_t* __restrict__ P, int n)
{
  const int row = blockIdx.x;
  float* srow = S + (size_t)row * n;
  f16_t* prow = P + (size_t)row * n;
  const int t = threadIdx.x;
  const int lane = t & 63;
  const int wave = t >> 6;
  __shared__ float red[8];

  float4 v[4];
  float mx = -3.4e38f;
#pragma unroll
  for (int i = 0; i < 4; ++i) {
    v[i] = *(const float4*)(srow + (size_t)(i * 256 + t) * 4);
    mx = fmaxf(mx, fmaxf(fmaxf(v[i].x, v[i].y), fmaxf(v[i].z, v[i].w)));
  }
#pragma unroll
  for (int off = 32; off > 0; off >>= 1) mx = fmaxf(mx, __shfl_xor(mx, off));
  if (lane == 0) red[wave] = mx;
  __syncthreads();
  mx = fmaxf(fmaxf(red[0], red[1]), fmaxf(red[2], red[3]));

  float e[16];
  float sum = 0.f;
#pragma unroll
  for (int i = 0; i < 4; ++i) {
    e[4 * i + 0] = __expf(v[i].x - mx);
    e[4 * i + 1] = __expf(v[i].y - mx);
    e[4 * i + 2] = __expf(v[i].z - mx);
    e[4 * i + 3] = __expf(v[i].w - mx);
    sum += e[4 * i + 0] + e[4 * i + 1] + e[4 * i + 2] + e[4 * i + 3];
  }
#pragma unroll
  for (int off = 32; off > 0; off >>= 1) sum += __shfl_xor(sum, off);
  if (lane == 0) red[4 + wave] = sum;
  __syncthreads();
  sum = red[4] + red[5] + red[6] + red[7];
  const float inv = 1.0f / sum;

#pragma unroll
  for (int i = 0; i < 4; ++i) {
    float4 w;
    w.x = e[4 * i + 0] * inv;
    w.y = e[4 * i + 1] * inv;
    w.z = e[4 * i + 2] * inv;
    w.w = e[4 * i + 3] * inv;
    *(float4*)(srow + (size_t)(i * 256 + t) * 4) = w;
    f16x4 p;
    p[0] = (f16_t)w.x;
    p[1] = (f16_t)w.y;
    p[2] = (f16_t)w.z;
    p[3] = (f16_t)w.w;
    *(f16x4*)(prow + (size_t)(i * 256 + t) * 4) = p;
  }
}

extern "C" void kernel_launch(void* const* d_in, const int* in_sizes, int n_in,
                              void* d_out, int out_size, void* d_ws, size_t ws_size,
                              hipStream_t stream) {
  const int N = N_SEQ, D = DMODEL;
  const float* q    = (const float*)d_in[0];
  const float* k    = (const float*)d_in[1];
  const float* v    = (const float*)d_in[2];
  const float* wq_w = (const float*)d_in[3];
  const float* wq_b = (const float*)d_in[4];
  const float* wk_w = (const float*)d_in[5];
  const float* wk_b = (const float*)d_in[6];
  const float* wv_w = (const float*)d_in[7];
  const float* wv_b = (const float*)d_in[8];
  const float* wo_w = (const float*)d_in[9];
  const float* wo_b = (const float*)d_in[10];

  float* x_out = (float*)d_out;                 // [N, D]
  float* attn  = x_out + (size_t)N * D;         // [N, N]

  char* wsp = (char*)d_ws;
  auto alloc = [&](size_t bytes) { char* p = wsp; wsp += bytes; return p; };
  const size_t ND = (size_t)N * D, DD = (size_t)D * D;
  f16_t*  qh16  = (f16_t*)alloc(ND * 2);
  f16_t*  ql16  = (f16_t*)alloc(ND * 2);
  f16_t*  kh16  = (f16_t*)alloc(ND * 2);
  f16_t*  kl16  = (f16_t*)alloc(ND * 2);
  f16_t*  vh16  = (f16_t*)alloc(ND * 2);
  f16_t*  wq16  = (f16_t*)alloc(DD * 2);
  f16_t*  wk16  = (f16_t*)alloc(DD * 2);
  f16_t*  wv16  = (f16_t*)alloc(DD * 2);
  f16_t*  wo16  = (f16_t*)alloc(DD * 2);
  f16_t*  QPh   = (f16_t*)alloc(ND * 2);        // fp16 qp hi
  f16_t*  QPl   = (f16_t*)alloc(ND * 2);        // fp16 qp lo
  f16_t*  KPh   = (f16_t*)alloc(ND * 2);        // fp16 kp
  f16_t*  spare = (f16_t*)alloc(ND * 2);        // pad (keeps Pb region 32MB)
  f16_t*  VPt   = (f16_t*)alloc(ND * 2);        // [D][N] transposed fp16
  // aliases (producers run strictly after last readers of the underlying bufs)
  f16_t*  Pb    = QPh;          // 32 MB over QPh..spare (dead after scores)
  float*  Part  = (float*)qh16; // 32 MB over qh16..kl16 (dead after qkv_proj)
  f16_t*  Xb    = vh16;         // 8 MB over vh16 (dead after qkv_proj)
  (void)spare;

  // fused split: q,k -> fp16 hi+lo; v -> fp16; all weights -> fp16
  SplitDesc sd;
  sd.src[0] = q;    sd.hi[0] = qh16;  sd.lo[0] = ql16;    sd.mode[0] = 2;
  sd.src[1] = k;    sd.hi[1] = kh16;  sd.lo[1] = kl16;    sd.mode[1] = 2;
  sd.src[2] = v;    sd.hi[2] = vh16;  sd.lo[2] = nullptr; sd.mode[2] = 3;
  sd.src[3] = wq_w; sd.hi[3] = wq16;  sd.lo[3] = nullptr; sd.mode[3] = 3;
  sd.src[4] = wk_w; sd.hi[4] = wk16;  sd.lo[4] = nullptr; sd.mode[4] = 3;
  sd.src[5] = wv_w; sd.hi[5] = wv16;  sd.lo[5] = nullptr; sd.mode[5] = 3;
  sd.src[6] = wo_w; sd.hi[6] = wo16;  sd.lo[6] = nullptr; sd.mode[6] = 3;
  const int nb_nd = (int)(ND / 4 / 256);   // 4096
  const int nb_dd = (int)(DD / 4 / 256);   // 1024
  sd.blk_start[0] = 0;
  sd.blk_start[1] = nb_nd;
  sd.blk_start[2] = 2 * nb_nd;
  sd.blk_start[3] = 3 * nb_nd;
  sd.blk_start[4] = 3 * nb_nd + nb_dd;
  sd.blk_start[5] = 3 * nb_nd + 2 * nb_dd;
  sd.blk_start[6] = 3 * nb_nd + 3 * nb_dd;
  sd.blk_start[7] = 3 * nb_nd + 4 * nb_dd;
  split_all<<<dim3(sd.blk_start[7]), dim3(256), 0, stream>>>(sd);

  const dim3 blk(256);
  const dim3 gsc(N / 256, N / 256);    // (16, 16)
  const int n4 = (int)(ND / 4);        // 1048576
  const dim3 gred((n4 + 255) / 256);

  // fused Q/K/V projections: grid (8,32,3) -> 3 blocks/CU, all-fp16
  qkv_proj<<<dim3(D / BN, N / BM, 3), blk, 0, stream>>>(
      qh16, ql16, wq16, wq_b,
      kh16, kl16, wk16, wk_b,
      vh16, wv16, wv_b,
      QPh, QPl, KPh, VPt);

  // scores = (Qh+Ql) @ Kh^T  (fp16 2-pass, logical K=2048)
  gemm8f_scores<<<gsc, dim3(512), 0, stream>>>(QPh, QPl, KPh, attn);

  // softmax rows in-place + fp16 copy (Pb aliases QP/KP region: dead now)
  softmax_rows<<<dim3(N), blk, 0, stream>>>(attn, Pb, N);

  // X = P @ VP  (fp16, 128x64 tile, split-K=2 -> fp32 partials -> fp16 Xb)
  gemm_sk64f<<<dim3(D / BN2, N / BM, 2), blk, 0, stream>>>(
      Pb, VPt, Part, N, D, N, N / 2);
  reduce_f16<<<gred, blk, 0, stream>>>(
      (const float4*)Part, (const float4*)(Part + ND), (f16x4*)Xb, n4);

  // out = X @ wo^T + b  (fp16, split-K=2 -> partials -> +bias -> d_out)
  gemm_sk64f<<<dim3(D / BN2, N / BM, 2), blk, 0, stream>>>(
      Xb, wo16, Part, N, D, D, D / 2);
  reduce_out<<<gred, blk, 0, stream>>>(
      (const float4*)Part, (const float4*)(Part + ND), wo_b,
      (float4*)x_out, n4);
}

// Round 10
// 260.554 us; speedup vs baseline: 1.0929x; 1.0309x over previous
//
#include <hip/hip_runtime.h>
#include <cstdint>

// Problem constants (fixed by the reference)
#define N_SEQ 4096
#define DMODEL 1024

#define BM 128
#define BN 128
#define BK 32
#define BN2 64

typedef __bf16 bf16_t;
typedef _Float16 f16_t;
typedef f16_t f16x8 __attribute__((ext_vector_type(8)));
typedef f16_t f16x4 __attribute__((ext_vector_type(4)));
typedef float f32x4 __attribute__((ext_vector_type(4)));

typedef __attribute__((address_space(1))) void* as1ptr;
typedef __attribute__((address_space(3))) void* as3ptr;

__device__ __forceinline__ void gload16(const void* g, void* l) {
  __builtin_amdgcn_global_load_lds((as1ptr)(uintptr_t)g, (as3ptr)(uintptr_t)l,
                                   16, 0, 0);
}

// ================= fused QKV projection (z = 0:Q, 1:K, 2:V) =================
// All-fp16.  z=0: qp=(qh+ql)@wq^T+b -> fp16 hi/lo  (2-pass)
//            z=1: kp=(kh+kl)@wk^T+b -> fp16        (2-pass)
//            z=2: vp=vh@wv^T+b      -> fp16 transposed (1-pass)
__global__ __launch_bounds__(256)
void qkv_proj(const f16_t* __restrict__ qh, const f16_t* __restrict__ ql,
              const f16_t* __restrict__ wq, const float* __restrict__ wq_b,
              const f16_t* __restrict__ kh, const f16_t* __restrict__ kl,
              const f16_t* __restrict__ wk, const float* __restrict__ wk_b,
              const f16_t* __restrict__ vh, const f16_t* __restrict__ wv,
              const float* __restrict__ wv_b,
              f16_t* __restrict__ QPh, f16_t* __restrict__ QPl,
              f16_t* __restrict__ KPh, f16_t* __restrict__ VPt)
{
  __shared__ __align__(16) f16_t lds[3 * BM * BK];   // 24 KiB
  f16_t* lA0 = lds;
  f16_t* lB0 = lds + BM * BK;
  f16_t* lA1 = lds + 2 * BM * BK;

  const int z = blockIdx.z;
  const f16_t *A0, *A1 = nullptr, *B0;
  const float* bias;
  if (z == 0)      { A0 = qh; A1 = ql; B0 = wq; bias = wq_b; }
  else if (z == 1) { A0 = kh; A1 = kl; B0 = wk; bias = wk_b; }
  else             { A0 = vh;          B0 = wv; bias = wv_b; }
  const bool twop = (z < 2);

  const int M = N_SEQ, Nc = DMODEL, K = DMODEL;
  const int t = threadIdx.x;
  const int lane = t & 63;
  const int wave = t >> 6;
  const int wm = wave >> 1;
  const int wn = wave & 1;
  const int row0 = blockIdx.y * BM;
  const int col0 = blockIdx.x * BN;

  const int srow = t >> 2;
  const int scol = (t & 3) * 8;
  const int loff = srow * BK + scol;

  const int fr = lane & 15;
  const int kq = (lane >> 4) * 8;

  f32x4 acc[4][4] = {};

  for (int k0 = 0; k0 < K; k0 += BK) {
    const size_t ga = (size_t)(row0 + srow) * K + k0 + scol;
    const size_t gb = (size_t)(col0 + srow) * K + k0 + scol;
    gload16(A0 + ga, lA0 + loff);
    gload16(A0 + ga + (size_t)64 * K, lA0 + loff + 64 * BK);
    gload16(B0 + gb, lB0 + loff);
    gload16(B0 + gb + (size_t)64 * K, lB0 + loff + 64 * BK);
    if (twop) {
      gload16(A1 + ga, lA1 + loff);
      gload16(A1 + ga + (size_t)64 * K, lA1 + loff + 64 * BK);
    }
    __syncthreads();

    f16x8 ah[4], al[4], bh[4];
#pragma unroll
    for (int m = 0; m < 4; ++m)
      ah[m] = *(const f16x8*)&lA0[(wm * 64 + m * 16 + fr) * BK + kq];
#pragma unroll
    for (int n = 0; n < 4; ++n)
      bh[n] = *(const f16x8*)&lB0[(wn * 64 + n * 16 + fr) * BK + kq];
    if (twop) {
#pragma unroll
      for (int m = 0; m < 4; ++m)
        al[m] = *(const f16x8*)&lA1[(wm * 64 + m * 16 + fr) * BK + kq];
    }

#pragma unroll
    for (int m = 0; m < 4; ++m)
#pragma unroll
      for (int n = 0; n < 4; ++n) {
        acc[m][n] = __builtin_amdgcn_mfma_f32_16x16x32_f16(
            ah[m], bh[n], acc[m][n], 0, 0, 0);
        if (twop)
          acc[m][n] = __builtin_amdgcn_mfma_f32_16x16x32_f16(
              al[m], bh[n], acc[m][n], 0, 0, 0);
      }
    __syncthreads();
  }

#pragma unroll
  for (int m = 0; m < 4; ++m) {
#pragma unroll
    for (int n = 0; n < 4; ++n) {
      const int grow0 = row0 + wm * 64 + m * 16 + (lane >> 4) * 4;
      const int gcol = col0 + wn * 64 + n * 16 + (lane & 15);
      const float bv = bias[gcol];
      if (z == 2) {
        f16x4 p;
#pragma unroll
        for (int r = 0; r < 4; ++r) p[r] = (f16_t)(acc[m][n][r] + bv);
        *(f16x4*)&VPt[(size_t)gcol * M + grow0] = p;
      } else if (z == 0) {
#pragma unroll
        for (int r = 0; r < 4; ++r) {
          const float val = acc[m][n][r] + bv;
          const size_t idx = (size_t)(grow0 + r) * Nc + gcol;
          const f16_t h = (f16_t)val;
          QPh[idx] = h;
          QPl[idx] = (f16_t)(val - (float)h);
        }
      } else {
#pragma unroll
        for (int r = 0; r < 4; ++r) {
          const float val = acc[m][n][r] + bv;
          KPh[(size_t)(grow0 + r) * Nc + gcol] = (f16_t)val;
        }
      }
    }
  }
}

// ========== direct fp16 GEMM, 128x64 tile, full K ==========
// OUT_F32=0: C = A@B^T           -> f16 Cf16
// OUT_F32=1: C = A@B^T + bias    -> f32 Cf32
// grid (Nc/64, M/128) = 512 blocks -> 2 blocks/CU; bijective XCD swizzle.
template <int OUT_F32>
__global__ __launch_bounds__(256)
void gemm_f16d(const f16_t* __restrict__ A, const f16_t* __restrict__ B,
               const float* __restrict__ bias,
               f16_t* __restrict__ Cf16, float* __restrict__ Cf32,
               int M, int Nc, int K)
{
  __shared__ __align__(16) f16_t lds[(BM + BN2) * BK];   // 12 KiB
  f16_t* lA = lds;
  f16_t* lB = lds + BM * BK;

  // XCD swizzle: nwg = gx*gy (both grids here are 16x32=512, 512%8==0)
  const int gx = gridDim.x;
  const int nwg = gx * gridDim.y;
  const int flat = blockIdx.y * gx + blockIdx.x;
  const int swz = (flat & 7) * (nwg >> 3) + (flat >> 3);
  const int bx = swz % gx;
  const int by = swz / gx;

  const int t = threadIdx.x;
  const int lane = t & 63;
  const int wave = t >> 6;
  const int wm = wave >> 1;     // 0..1 (64-row half)
  const int wn = wave & 1;      // 0..1 (32-col half)
  const int row0 = by * BM;
  const int col0 = bx * BN2;

  const int srow = t >> 2;
  const int scol = (t & 3) * 8;
  const int loff = srow * BK + scol;

  const int fr = lane & 15;
  const int kq = (lane >> 4) * 8;

  f32x4 acc[4][2] = {};

  for (int k0 = 0; k0 < K; k0 += BK) {
    const size_t ga = (size_t)(row0 + srow) * K + k0 + scol;
    const size_t gb = (size_t)(col0 + srow) * K + k0 + scol;
    gload16(A + ga, lA + loff);
    gload16(A + ga + (size_t)64 * K, lA + loff + 64 * BK);
    gload16(B + gb, lB + loff);
    __syncthreads();

    f16x8 ah[4], bh[2];
#pragma unroll
    for (int m = 0; m < 4; ++m)
      ah[m] = *(const f16x8*)&lA[(wm * 64 + m * 16 + fr) * BK + kq];
#pragma unroll
    for (int n = 0; n < 2; ++n)
      bh[n] = *(const f16x8*)&lB[(wn * 32 + n * 16 + fr) * BK + kq];

#pragma unroll
    for (int m = 0; m < 4; ++m)
#pragma unroll
      for (int n = 0; n < 2; ++n)
        acc[m][n] =
            __builtin_amdgcn_mfma_f32_16x16x32_f16(ah[m], bh[n], acc[m][n], 0, 0, 0);
    __syncthreads();
  }

#pragma unroll
  for (int m = 0; m < 4; ++m) {
#pragma unroll
    for (int n = 0; n < 2; ++n) {
      const int grow0 = row0 + wm * 64 + m * 16 + (lane >> 4) * 4;
      const int gcol = col0 + wn * 32 + n * 16 + (lane & 15);
#pragma unroll
      for (int r = 0; r < 4; ++r) {
        const size_t idx = (size_t)(grow0 + r) * Nc + gcol;
        if (OUT_F32) Cf32[idx] = acc[m][n][r] + bias[gcol];
        else         Cf16[idx] = (f16_t)acc[m][n][r];
      }
    }
  }
}

// ============ fp16 2-pass 256x256 scores GEMM (R4 structure) ============
#define TILE_ELEMS 16384   // 256 rows x 64 cols
#define UNIT_ELEMS 4096    // 64 rows x 64 cols
#define NT_SC 32

template <int V> struct ic { static constexpr int value = V; };

#define SBAR() asm volatile("s_barrier" ::: "memory")
#define WAITLGKM(n)                                              \
  do {                                                           \
    asm volatile("s_waitcnt lgkmcnt(" #n ")" ::: "memory");      \
    __builtin_amdgcn_sched_barrier(0);                           \
  } while (0)

template <int MH>
__device__ __forceinline__ void load_A8f(const f16_t* Ab, int wm, int fr,
                                         int kq, int sw, f16x8 (&af)[4][2]) {
#pragma unroll
  for (int m = 0; m < 4; ++m) {
    const int row = wm * 128 + (MH * 4 + m) * 16 + fr;
#pragma unroll
    for (int ks = 0; ks < 2; ++ks)
      af[m][ks] = *(const f16x8*)&Ab[row * 64 + ((ks * 32 + kq) ^ sw)];
  }
}

template <int NH>
__device__ __forceinline__ void load_B4f(const f16_t* Bb, int wn, int fr,
                                         int kq, int sw, f16x8 (&bfr)[2][2]) {
#pragma unroll
  for (int n = 0; n < 2; ++n) {
    const int row = wn * 64 + (NH * 2 + n) * 16 + fr;
#pragma unroll
    for (int ks = 0; ks < 2; ++ks)
      bfr[n][ks] = *(const f16x8*)&Bb[row * 64 + ((ks * 32 + kq) ^ sw)];
  }
}

template <int MH, int NH>
__device__ __forceinline__ void mfma16f(const f16x8 (&af)[4][2],
                                        const f16x8 (&bfr)[2][2],
                                        f32x4 (&acc)[8][4]) {
#pragma unroll
  for (int m = 0; m < 4; ++m)
#pragma unroll
    for (int n = 0; n < 2; ++n)
#pragma unroll
      for (int ks = 0; ks < 2; ++ks)
        acc[MH * 4 + m][NH * 2 + n] = __builtin_amdgcn_mfma_f32_16x16x32_f16(
            af[m][ks], bfr[n][ks], acc[MH * 4 + m][NH * 2 + n], 0, 0, 0);
}

__global__ __launch_bounds__(512, 2)
void gemm8f_scores(const f16_t* __restrict__ Qh, const f16_t* __restrict__ Ql,
                   const f16_t* __restrict__ Kh, float* __restrict__ C)
{
  __shared__ __align__(16) f16_t sm[2 * 2 * TILE_ELEMS];  // 128 KiB

  const int t = threadIdx.x;
  const int lane = t & 63;
  const int wave = t >> 6;
  const int wm = wave >> 2;      // 0..1
  const int wn = wave & 3;       // 0..3

  // XCD-aware block swizzle: grid 16x16 = 256 blocks, 256 = 8*32 (bijective)
  const int flat = blockIdx.y * 16 + blockIdx.x;
  const int swzb = (flat & 7) * 32 + (flat >> 3);
  const int brow = (swzb >> 4) * 256;
  const int bcol = (swzb & 15) * 256;

  const int srow = t >> 3;                               // 0..63
  const int scol = 8 * ((t & 7) ^ ((t >> 3) & 7));       // involution
  const int sdst = t * 8;

  const int fr = lane & 15;
  const int kq = (lane >> 4) * 8;
  const int sw = (fr & 7) << 3;                          // read-side swizzle

  auto stageA = [&](int buf, int u, int kt) {
    const f16_t* src = (kt >= 16) ? Ql : Qh;
    const int kk = (kt & 15) << 6;
    gload16(src + (size_t)(brow + u * 64 + srow) * DMODEL + kk + scol,
            &sm[(buf * 2 + 0) * TILE_ELEMS + u * UNIT_ELEMS + sdst]);
  };
  auto stageB = [&](int buf, int u, int kt) {
    const int kk = (kt & 15) << 6;
    gload16(Kh + (size_t)(bcol + u * 64 + srow) * DMODEL + kk + scol,
            &sm[(buf * 2 + 1) * TILE_ELEMS + u * UNIT_ELEMS + sdst]);
  };

  f32x4 acc[8][4] = {};
  f16x8 af0[4][2], af1[4][2];
  f16x8 b0[2][2], b1[2][2];

  // ---- prologue: tile0 all 8 units; tile1's Ua, V01, Ub (6 loads).
#pragma unroll
  for (int u = 0; u < 4; ++u) stageA(0, u, 0);
#pragma unroll
  for (int u = 0; u < 4; ++u) stageB(0, u, 0);
  stageA(1, 0, 1); stageA(1, 2, 1);   // Ua(1)
  stageB(1, 0, 1); stageB(1, 1, 1);   // V01(1)
  stageA(1, 1, 1); stageA(1, 3, 1);   // Ub(1)
  asm volatile("s_waitcnt vmcnt(6)" ::: "memory");  // tile0's 8 landed
  SBAR();

  auto tile = [&](auto Pc, int kt) {
    constexpr int p = decltype(Pc)::value;
    constexpr int q = p ^ 1;
    const bool n1 = (kt + 1 < NT_SC);
    const bool n2 = (kt + 2 < NT_SC);
    const f16_t* Ab = &sm[(p * 2 + 0) * TILE_ELEMS];
    const f16_t* Bb = &sm[(p * 2 + 1) * TILE_ELEMS];

    // ---- Phase 1
    load_A8f<0>(Ab, wm, fr, kq, sw, af0);
    load_B4f<0>(Bb, wn, fr, kq, sw, b0);
    if (n1) { stageB(q, 2, kt + 1); stageB(q, 3, kt + 1); }
    load_B4f<1>(Bb, wn, fr, kq, sw, b1);
    WAITLGKM(4);
    __builtin_amdgcn_s_setprio(1);
    mfma16f<0, 0>(af0, b0, acc);
    __builtin_amdgcn_s_setprio(0);
    __builtin_amdgcn_sched_barrier(0);
    SBAR();

    // ---- Phase 2
    if (n2) { stageA(p, 0, kt + 2); stageA(p, 2, kt + 2); }
    load_A8f<1>(Ab, wm, fr, kq, sw, af1);
    WAITLGKM(8);
    __builtin_amdgcn_s_setprio(1);
    mfma16f<0, 1>(af0, b1, acc);
    __builtin_amdgcn_s_setprio(0);
    __builtin_amdgcn_sched_barrier(0);
    SBAR();

    // ---- Phase 3
    if (n2) { stageB(p, 0, kt + 2); stageB(p, 1, kt + 2); }
    WAITLGKM(0);
    __builtin_amdgcn_s_setprio(1);
    mfma16f<1, 0>(af1, b0, acc);
    __builtin_amdgcn_s_setprio(0);
    __builtin_amdgcn_sched_barrier(0);
    SBAR();

    // ---- Phase 4
    if (n2) { stageA(p, 1, kt + 2); stageA(p, 3, kt + 2); }
    __builtin_amdgcn_s_setprio(1);
    mfma16f<1, 1>(af1, b1, acc);
    __builtin_amdgcn_s_setprio(0);
    __builtin_amdgcn_sched_barrier(0);
    if (n2)      asm volatile("s_waitcnt vmcnt(6)" ::: "memory");
    else if (n1) asm volatile("s_waitcnt vmcnt(0)" ::: "memory");
    SBAR();
  };

  for (int kt = 0; kt < NT_SC; kt += 2) {
    tile(ic<0>{}, kt);
    tile(ic<1>{}, kt + 1);
  }

  // ---- epilogue
#pragma unroll
  for (int mf = 0; mf < 8; ++mf) {
#pragma unroll
    for (int nf = 0; nf < 4; ++nf) {
      const int r0 = brow + wm * 128 + mf * 16 + (lane >> 4) * 4;
      const int c  = bcol + wn * 64 + nf * 16 + (lane & 15);
#pragma unroll
      for (int r = 0; r < 4; ++r)
        C[(size_t)(r0 + r) * N_SEQ + c] = acc[mf][nf][r];
    }
  }
}

// ======================= fused split (all fp16) =======================
// mode: 2 = fp16 hi/lo, 3 = fp16 hi only
struct SplitDesc {
  const float* src[7];
  f16_t* hi[7];
  f16_t* lo[7];
  int mode[7];
  int blk_start[8];
};

__global__ __launch_bounds__(256)
void split_all(SplitDesc d)
{
  const int b = blockIdx.x;
  int seg = 0;
#pragma unroll
  for (int s = 1; s < 7; ++s) seg += (b >= d.blk_start[s]) ? 1 : 0;
  const int i = (b - d.blk_start[seg]) * 256 + threadIdx.x;
  const float4 v = ((const float4*)d.src[seg])[i];
  const float vv[4] = {v.x, v.y, v.z, v.w};
  f16x4 h, l;
#pragma unroll
  for (int j = 0; j < 4; ++j) {
    const f16_t hh = (f16_t)vv[j];
    h[j] = hh;
    l[j] = (f16_t)(vv[j] - (float)hh);
  }
  ((f16x4*)d.hi[seg])[i] = h;
  if (d.mode[seg] == 2) ((f16x4*)d.lo[seg])[i] = l;
}

// ======================= softmax =======================
__global__ __launch_bounds__(256)
void softmax_rows(float* __restrict__ S, f16_t* __restrict__ P, int n)
{
  const int row = blockIdx.x;
  float* srow = S + (size_t)row * n;
  f16_t* prow = P + (size_t)row * n;
  const int t = threadIdx.x;
  const int lane = t & 63;
  const int wave = t >> 6;
  __shared__ float red[8];

  float4 v[4];
  float mx = -3.4e38f;
#pragma unroll
  for (int i = 0; i < 4; ++i) {
    v[i] = *(const float4*)(srow + (size_t)(i * 256 + t) * 4);
    mx = fmaxf(mx, fmaxf(fmaxf(v[i].x, v[i].y), fmaxf(v[i].z, v[i].w)));
  }
#pragma unroll
  for (int off = 32; off > 0; off >>= 1) mx = fmaxf(mx, __shfl_xor(mx, off));
  if (lane == 0) red[wave] = mx;
  __syncthreads();
  mx = fmaxf(fmaxf(red[0], red[1]), fmaxf(red[2], red[3]));

  float e[16];
  float sum = 0.f;
#pragma unroll
  for (int i = 0; i < 4; ++i) {
    e[4 * i + 0] = __expf(v[i].x - mx);
    e[4 * i + 1] = __expf(v[i].y - mx);
    e[4 * i + 2] = __expf(v[i].z - mx);
    e[4 * i + 3] = __expf(v[i].w - mx);
    sum += e[4 * i + 0] + e[4 * i + 1] + e[4 * i + 2] + e[4 * i + 3];
  }
#pragma unroll
  for (int off = 32; off > 0; off >>= 1) sum += __shfl_xor(sum, off);
  if (lane == 0) red[4 + wave] = sum;
  __syncthreads();
  sum = red[4] + red[5] + red[6] + red[7];
  const float inv = 1.0f / sum;

#pragma unroll
  for (int i = 0; i < 4; ++i) {
    float4 w;
    w.x = e[4 * i + 0] * inv;
    w.y = e[4 * i + 1] * inv;
    w.z = e[4 * i + 2] * inv;
    w.w = e[4 * i + 3] * inv;
    *(float4*)(srow + (size_t)(i * 256 + t) * 4) = w;
    f16x4 p;
    p[0] = (f16_t)w.x;
    p[1] = (f16_t)w.y;
    p[2] = (f16_t)w.z;
    p[3] = (f16_t)w.w;
    *(f16x4*)(prow + (size_t)(i * 256 + t) * 4) = p;
  }
}

extern "C" void kernel_launch(void* const* d_in, const int* in_sizes, int n_in,
                              void* d_out, int out_size, void* d_ws, size_t ws_size,
                              hipStream_t stream) {
  const int N = N_SEQ, D = DMODEL;
  const float* q    = (const float*)d_in[0];
  const float* k    = (const float*)d_in[1];
  const float* v    = (const float*)d_in[2];
  const float* wq_w = (const float*)d_in[3];
  const float* wq_b = (const float*)d_in[4];
  const float* wk_w = (const float*)d_in[5];
  const float* wk_b = (const float*)d_in[6];
  const float* wv_w = (const float*)d_in[7];
  const float* wv_b = (const float*)d_in[8];
  const float* wo_w = (const float*)d_in[9];
  const float* wo_b = (const float*)d_in[10];

  float* x_out = (float*)d_out;                 // [N, D]
  float* attn  = x_out + (size_t)N * D;         // [N, N]

  char* wsp = (char*)d_ws;
  auto alloc = [&](size_t bytes) { char* p = wsp; wsp += bytes; return p; };
  const size_t ND = (size_t)N * D, DD = (size_t)D * D;
  f16_t*  qh16  = (f16_t*)alloc(ND * 2);
  f16_t*  ql16  = (f16_t*)alloc(ND * 2);
  f16_t*  kh16  = (f16_t*)alloc(ND * 2);
  f16_t*  kl16  = (f16_t*)alloc(ND * 2);
  f16_t*  vh16  = (f16_t*)alloc(ND * 2);
  f16_t*  wq16  = (f16_t*)alloc(DD * 2);
  f16_t*  wk16  = (f16_t*)alloc(DD * 2);
  f16_t*  wv16  = (f16_t*)alloc(DD * 2);
  f16_t*  wo16  = (f16_t*)alloc(DD * 2);
  f16_t*  QPh   = (f16_t*)alloc(ND * 2);        // fp16 qp hi
  f16_t*  QPl   = (f16_t*)alloc(ND * 2);        // fp16 qp lo
  f16_t*  KPh   = (f16_t*)alloc(ND * 2);        // fp16 kp
  f16_t*  spare = (f16_t*)alloc(ND * 2);        // pad (keeps Pb region 32MB)
  f16_t*  VPt   = (f16_t*)alloc(ND * 2);        // [D][N] transposed fp16
  // aliases (producers run strictly after last readers of the underlying bufs)
  f16_t*  Pb    = QPh;          // 32 MB over QPh..spare (dead after scores)
  f16_t*  Xb    = vh16;         // 8 MB over vh16 (dead after qkv_proj)
  (void)spare;

  // fused split: q,k -> fp16 hi+lo; v -> fp16; all weights -> fp16
  SplitDesc sd;
  sd.src[0] = q;    sd.hi[0] = qh16;  sd.lo[0] = ql16;    sd.mode[0] = 2;
  sd.src[1] = k;    sd.hi[1] = kh16;  sd.lo[1] = kl16;    sd.mode[1] = 2;
  sd.src[2] = v;    sd.hi[2] = vh16;  sd.lo[2] = nullptr; sd.mode[2] = 3;
  sd.src[3] = wq_w; sd.hi[3] = wq16;  sd.lo[3] = nullptr; sd.mode[3] = 3;
  sd.src[4] = wk_w; sd.hi[4] = wk16;  sd.lo[4] = nullptr; sd.mode[4] = 3;
  sd.src[5] = wv_w; sd.hi[5] = wv16;  sd.lo[5] = nullptr; sd.mode[5] = 3;
  sd.src[6] = wo_w; sd.hi[6] = wo16;  sd.lo[6] = nullptr; sd.mode[6] = 3;
  const int nb_nd = (int)(ND / 4 / 256);   // 4096
  const int nb_dd = (int)(DD / 4 / 256);   // 1024
  sd.blk_start[0] = 0;
  sd.blk_start[1] = nb_nd;
  sd.blk_start[2] = 2 * nb_nd;
  sd.blk_start[3] = 3 * nb_nd;
  sd.blk_start[4] = 3 * nb_nd + nb_dd;
  sd.blk_start[5] = 3 * nb_nd + 2 * nb_dd;
  sd.blk_start[6] = 3 * nb_nd + 3 * nb_dd;
  sd.blk_start[7] = 3 * nb_nd + 4 * nb_dd;
  split_all<<<dim3(sd.blk_start[7]), dim3(256), 0, stream>>>(sd);

  const dim3 blk(256);
  const dim3 gsc(N / 256, N / 256);    // (16, 16)
  const dim3 gd(D / BN2, N / BM);      // (16, 32) = 512 blocks

  // fused Q/K/V projections: grid (8,32,3) -> 3 blocks/CU, all-fp16
  qkv_proj<<<dim3(D / BN, N / BM, 3), blk, 0, stream>>>(
      qh16, ql16, wq16, wq_b,
      kh16, kl16, wk16, wk_b,
      vh16, wv16, wv_b,
      QPh, QPl, KPh, VPt);

  // scores = (Qh+Ql) @ Kh^T  (fp16 2-pass, logical K=2048)
  gemm8f_scores<<<gsc, dim3(512), 0, stream>>>(QPh, QPl, KPh, attn);

  // softmax rows in-place + fp16 copy (Pb aliases QP/KP region: dead now)
  softmax_rows<<<dim3(N), blk, 0, stream>>>(attn, Pb, N);

  // X = P @ VP  (direct fp16, 128x64 tile, full K=4096 -> fp16 Xb)
  gemm_f16d<0><<<gd, blk, 0, stream>>>(
      Pb, VPt, nullptr, Xb, nullptr, N, D, N);

  // out = X @ wo^T + b  (direct, full K=1024 -> fp32 d_out with bias)
  gemm_f16d<1><<<gd, blk, 0, stream>>>(
      Xb, wo16, wo_b, nullptr, x_out, N, D, D);
}

// Round 11
// 246.322 us; speedup vs baseline: 1.1560x; 1.0578x over previous
//
#include <hip/hip_runtime.h>
#include <cstdint>

// Problem constants (fixed by the reference)
#define N_SEQ 4096
#define DMODEL 1024

#define BM 128
#define BN 128
#define BK 32
#define BN2 64

typedef __bf16 bf16_t;
typedef _Float16 f16_t;
typedef f16_t f16x8 __attribute__((ext_vector_type(8)));
typedef f16_t f16x4 __attribute__((ext_vector_type(4)));
typedef float f32x4 __attribute__((ext_vector_type(4)));

typedef __attribute__((address_space(1))) void* as1ptr;
typedef __attribute__((address_space(3))) void* as3ptr;

__device__ __forceinline__ void gload16(const void* g, void* l) {
  __builtin_amdgcn_global_load_lds((as1ptr)(uintptr_t)g, (as3ptr)(uintptr_t)l,
                                   16, 0, 0);
}

// ================= fused QKV projection (z = 0:Q, 1:K, 2:V) =================
// All-fp16.  z=0: qp=(qh+ql)@wq^T+b -> fp16 hi/lo  (2-pass)
//            z=1: kp=(kh+kl)@wk^T+b -> fp16        (2-pass)
//            z=2: vp=vh@wv^T+b      -> fp16 transposed (1-pass)
__global__ __launch_bounds__(256)
void qkv_proj(const f16_t* __restrict__ qh, const f16_t* __restrict__ ql,
              const f16_t* __restrict__ wq, const float* __restrict__ wq_b,
              const f16_t* __restrict__ kh, const f16_t* __restrict__ kl,
              const f16_t* __restrict__ wk, const float* __restrict__ wk_b,
              const f16_t* __restrict__ vh, const f16_t* __restrict__ wv,
              const float* __restrict__ wv_b,
              f16_t* __restrict__ QPh, f16_t* __restrict__ QPl,
              f16_t* __restrict__ KPh, f16_t* __restrict__ VPt)
{
  __shared__ __align__(16) f16_t lds[3 * BM * BK];   // 24 KiB
  f16_t* lA0 = lds;
  f16_t* lB0 = lds + BM * BK;
  f16_t* lA1 = lds + 2 * BM * BK;

  const int z = blockIdx.z;
  const f16_t *A0, *A1 = nullptr, *B0;
  const float* bias;
  if (z == 0)      { A0 = qh; A1 = ql; B0 = wq; bias = wq_b; }
  else if (z == 1) { A0 = kh; A1 = kl; B0 = wk; bias = wk_b; }
  else             { A0 = vh;          B0 = wv; bias = wv_b; }
  const bool twop = (z < 2);

  const int M = N_SEQ, Nc = DMODEL, K = DMODEL;
  const int t = threadIdx.x;
  const int lane = t & 63;
  const int wave = t >> 6;
  const int wm = wave >> 1;
  const int wn = wave & 1;
  const int row0 = blockIdx.y * BM;
  const int col0 = blockIdx.x * BN;

  const int srow = t >> 2;
  const int scol = (t & 3) * 8;
  const int loff = srow * BK + scol;

  const int fr = lane & 15;
  const int kq = (lane >> 4) * 8;

  f32x4 acc[4][4] = {};

  for (int k0 = 0; k0 < K; k0 += BK) {
    const size_t ga = (size_t)(row0 + srow) * K + k0 + scol;
    const size_t gb = (size_t)(col0 + srow) * K + k0 + scol;
    gload16(A0 + ga, lA0 + loff);
    gload16(A0 + ga + (size_t)64 * K, lA0 + loff + 64 * BK);
    gload16(B0 + gb, lB0 + loff);
    gload16(B0 + gb + (size_t)64 * K, lB0 + loff + 64 * BK);
    if (twop) {
      gload16(A1 + ga, lA1 + loff);
      gload16(A1 + ga + (size_t)64 * K, lA1 + loff + 64 * BK);
    }
    __syncthreads();

    f16x8 ah[4], al[4], bh[4];
#pragma unroll
    for (int m = 0; m < 4; ++m)
      ah[m] = *(const f16x8*)&lA0[(wm * 64 + m * 16 + fr) * BK + kq];
#pragma unroll
    for (int n = 0; n < 4; ++n)
      bh[n] = *(const f16x8*)&lB0[(wn * 64 + n * 16 + fr) * BK + kq];
    if (twop) {
#pragma unroll
      for (int m = 0; m < 4; ++m)
        al[m] = *(const f16x8*)&lA1[(wm * 64 + m * 16 + fr) * BK + kq];
    }

#pragma unroll
    for (int m = 0; m < 4; ++m)
#pragma unroll
      for (int n = 0; n < 4; ++n) {
        acc[m][n] = __builtin_amdgcn_mfma_f32_16x16x32_f16(
            ah[m], bh[n], acc[m][n], 0, 0, 0);
        if (twop)
          acc[m][n] = __builtin_amdgcn_mfma_f32_16x16x32_f16(
              al[m], bh[n], acc[m][n], 0, 0, 0);
      }
    __syncthreads();
  }

#pragma unroll
  for (int m = 0; m < 4; ++m) {
#pragma unroll
    for (int n = 0; n < 4; ++n) {
      const int grow0 = row0 + wm * 64 + m * 16 + (lane >> 4) * 4;
      const int gcol = col0 + wn * 64 + n * 16 + (lane & 15);
      const float bv = bias[gcol];
      if (z == 2) {
        f16x4 p;
#pragma unroll
        for (int r = 0; r < 4; ++r) p[r] = (f16_t)(acc[m][n][r] + bv);
        *(f16x4*)&VPt[(size_t)gcol * M + grow0] = p;
      } else if (z == 0) {
#pragma unroll
        for (int r = 0; r < 4; ++r) {
          const float val = acc[m][n][r] + bv;
          const size_t idx = (size_t)(grow0 + r) * Nc + gcol;
          const f16_t h = (f16_t)val;
          QPh[idx] = h;
          QPl[idx] = (f16_t)(val - (float)h);
        }
      } else {
#pragma unroll
        for (int r = 0; r < 4; ++r) {
          const float val = acc[m][n][r] + bv;
          KPh[(size_t)(grow0 + r) * Nc + gcol] = (f16_t)val;
        }
      }
    }
  }
}

// ========== direct fp16 GEMM, 128x64 tile, BK=64, swizzled LDS ==========
// OUT_F32=0: C = A@B^T        -> f16 Cf16
// OUT_F32=1: C = A@B^T + bias -> f32 Cf32
// LDS: 3 units of [64 rows][64 cols] fp16 (A-u0, A-u1, B), full-XOR swizzle
// (pre-swizzled global source col + ^sw read — 0-conflict pattern from the
// scores kernel). 16 MFMA/wave per barrier-pair (vs 8 at BK=32).
#define UNITE 4096   // 64x64 f16 elems
template <int OUT_F32>
__global__ __launch_bounds__(256)
void gemm_f16e(const f16_t* __restrict__ A, const f16_t* __restrict__ B,
               const float* __restrict__ bias,
               f16_t* __restrict__ Cf16, float* __restrict__ Cf32,
               int M, int Nc, int K)
{
  __shared__ __align__(16) f16_t lds[3 * UNITE];   // 24 KiB

  // XCD swizzle (grids here are multiples of 8 blocks)
  const int gx = gridDim.x;
  const int nwg = gx * gridDim.y;
  const int flat = blockIdx.y * gx + blockIdx.x;
  const int swz = (flat & 7) * (nwg >> 3) + (flat >> 3);
  const int bx = swz % gx;
  const int by = swz / gx;

  const int t = threadIdx.x;
  const int lane = t & 63;
  const int wave = t >> 6;
  const int wm = wave >> 1;     // 0..1 (64-row half)
  const int wn = wave & 1;      // 0..1 (32-col half)
  const int row0 = by * BM;
  const int col0 = bx * BN2;

  // staging: 256 thr cover one 32-row half-unit per gload16 (8 f16/thread)
  const int srw = t >> 3;                                // 0..31
  const int scol = 8 * ((t & 7) ^ ((t >> 3) & 7));       // pre-swizzled src
  const int sdst = t * 8;

  const int fr = lane & 15;
  const int kq = (lane >> 4) * 8;
  const int sw = (fr & 7) << 3;                          // read-side swizzle

  f32x4 acc[4][2] = {};

  for (int k0 = 0; k0 < K; k0 += 64) {
#pragma unroll
    for (int h = 0; h < 2; ++h) {
      const int r = h * 32 + srw;
      gload16(A + (size_t)(row0 + r) * K + k0 + scol,
              &lds[0 * UNITE + h * 2048 + sdst]);
      gload16(A + (size_t)(row0 + 64 + r) * K + k0 + scol,
              &lds[1 * UNITE + h * 2048 + sdst]);
      gload16(B + (size_t)(col0 + r) * K + k0 + scol,
              &lds[2 * UNITE + h * 2048 + sdst]);
    }
    __syncthreads();

    f16x8 ah[4][2], bh[2][2];
#pragma unroll
    for (int m = 0; m < 4; ++m) {
      const int base = wm * UNITE + (m * 16 + fr) * 64;
#pragma unroll
      for (int ks = 0; ks < 2; ++ks)
        ah[m][ks] = *(const f16x8*)&lds[base + ((ks * 32 + kq) ^ sw)];
    }
#pragma unroll
    for (int n = 0; n < 2; ++n) {
      const int base = 2 * UNITE + (wn * 32 + n * 16 + fr) * 64;
#pragma unroll
      for (int ks = 0; ks < 2; ++ks)
        bh[n][ks] = *(const f16x8*)&lds[base + ((ks * 32 + kq) ^ sw)];
    }

#pragma unroll
    for (int m = 0; m < 4; ++m)
#pragma unroll
      for (int n = 0; n < 2; ++n)
#pragma unroll
        for (int ks = 0; ks < 2; ++ks)
          acc[m][n] = __builtin_amdgcn_mfma_f32_16x16x32_f16(
              ah[m][ks], bh[n][ks], acc[m][n], 0, 0, 0);
    __syncthreads();
  }

#pragma unroll
  for (int m = 0; m < 4; ++m) {
#pragma unroll
    for (int n = 0; n < 2; ++n) {
      const int grow0 = row0 + wm * 64 + m * 16 + (lane >> 4) * 4;
      const int gcol = col0 + wn * 32 + n * 16 + (lane & 15);
#pragma unroll
      for (int r = 0; r < 4; ++r) {
        const size_t idx = (size_t)(grow0 + r) * Nc + gcol;
        if (OUT_F32) Cf32[idx] = acc[m][n][r] + bias[gcol];
        else         Cf16[idx] = (f16_t)acc[m][n][r];
      }
    }
  }
}

// ============ fp16 2-pass 256x256 scores GEMM (R4 structure) ============
#define TILE_ELEMS 16384   // 256 rows x 64 cols
#define UNIT_ELEMS 4096    // 64 rows x 64 cols
#define NT_SC 32

template <int V> struct ic { static constexpr int value = V; };

#define SBAR() asm volatile("s_barrier" ::: "memory")
#define WAITLGKM(n)                                              \
  do {                                                           \
    asm volatile("s_waitcnt lgkmcnt(" #n ")" ::: "memory");      \
    __builtin_amdgcn_sched_barrier(0);                           \
  } while (0)

template <int MH>
__device__ __forceinline__ void load_A8f(const f16_t* Ab, int wm, int fr,
                                         int kq, int sw, f16x8 (&af)[4][2]) {
#pragma unroll
  for (int m = 0; m < 4; ++m) {
    const int row = wm * 128 + (MH * 4 + m) * 16 + fr;
#pragma unroll
    for (int ks = 0; ks < 2; ++ks)
      af[m][ks] = *(const f16x8*)&Ab[row * 64 + ((ks * 32 + kq) ^ sw)];
  }
}

template <int NH>
__device__ __forceinline__ void load_B4f(const f16_t* Bb, int wn, int fr,
                                         int kq, int sw, f16x8 (&bfr)[2][2]) {
#pragma unroll
  for (int n = 0; n < 2; ++n) {
    const int row = wn * 64 + (NH * 2 + n) * 16 + fr;
#pragma unroll
    for (int ks = 0; ks < 2; ++ks)
      bfr[n][ks] = *(const f16x8*)&Bb[row * 64 + ((ks * 32 + kq) ^ sw)];
  }
}

template <int MH, int NH>
__device__ __forceinline__ void mfma16f(const f16x8 (&af)[4][2],
                                        const f16x8 (&bfr)[2][2],
                                        f32x4 (&acc)[8][4]) {
#pragma unroll
  for (int m = 0; m < 4; ++m)
#pragma unroll
    for (int n = 0; n < 2; ++n)
#pragma unroll
      for (int ks = 0; ks < 2; ++ks)
        acc[MH * 4 + m][NH * 2 + n] = __builtin_amdgcn_mfma_f32_16x16x32_f16(
            af[m][ks], bfr[n][ks], acc[MH * 4 + m][NH * 2 + n], 0, 0, 0);
}

__global__ __launch_bounds__(512, 2)
void gemm8f_scores(const f16_t* __restrict__ Qh, const f16_t* __restrict__ Ql,
                   const f16_t* __restrict__ Kh, float* __restrict__ C)
{
  __shared__ __align__(16) f16_t sm[2 * 2 * TILE_ELEMS];  // 128 KiB

  const int t = threadIdx.x;
  const int lane = t & 63;
  const int wave = t >> 6;
  const int wm = wave >> 2;      // 0..1
  const int wn = wave & 3;       // 0..3

  // XCD-aware block swizzle: grid 16x16 = 256 blocks, 256 = 8*32 (bijective)
  const int flat = blockIdx.y * 16 + blockIdx.x;
  const int swzb = (flat & 7) * 32 + (flat >> 3);
  const int brow = (swzb >> 4) * 256;
  const int bcol = (swzb & 15) * 256;

  const int srow = t >> 3;                               // 0..63
  const int scol = 8 * ((t & 7) ^ ((t >> 3) & 7));       // involution
  const int sdst = t * 8;

  const int fr = lane & 15;
  const int kq = (lane >> 4) * 8;
  const int sw = (fr & 7) << 3;                          // read-side swizzle

  auto stageA = [&](int buf, int u, int kt) {
    const f16_t* src = (kt >= 16) ? Ql : Qh;
    const int kk = (kt & 15) << 6;
    gload16(src + (size_t)(brow + u * 64 + srow) * DMODEL + kk + scol,
            &sm[(buf * 2 + 0) * TILE_ELEMS + u * UNIT_ELEMS + sdst]);
  };
  auto stageB = [&](int buf, int u, int kt) {
    const int kk = (kt & 15) << 6;
    gload16(Kh + (size_t)(bcol + u * 64 + srow) * DMODEL + kk + scol,
            &sm[(buf * 2 + 1) * TILE_ELEMS + u * UNIT_ELEMS + sdst]);
  };

  f32x4 acc[8][4] = {};
  f16x8 af0[4][2], af1[4][2];
  f16x8 b0[2][2], b1[2][2];

  // ---- prologue: tile0 all 8 units; tile1's Ua, V01, Ub (6 loads).
#pragma unroll
  for (int u = 0; u < 4; ++u) stageA(0, u, 0);
#pragma unroll
  for (int u = 0; u < 4; ++u) stageB(0, u, 0);
  stageA(1, 0, 1); stageA(1, 2, 1);   // Ua(1)
  stageB(1, 0, 1); stageB(1, 1, 1);   // V01(1)
  stageA(1, 1, 1); stageA(1, 3, 1);   // Ub(1)
  asm volatile("s_waitcnt vmcnt(6)" ::: "memory");  // tile0's 8 landed
  SBAR();

  auto tile = [&](auto Pc, int kt) {
    constexpr int p = decltype(Pc)::value;
    constexpr int q = p ^ 1;
    const bool n1 = (kt + 1 < NT_SC);
    const bool n2 = (kt + 2 < NT_SC);
    const f16_t* Ab = &sm[(p * 2 + 0) * TILE_ELEMS];
    const f16_t* Bb = &sm[(p * 2 + 1) * TILE_ELEMS];

    // ---- Phase 1
    load_A8f<0>(Ab, wm, fr, kq, sw, af0);
    load_B4f<0>(Bb, wn, fr, kq, sw, b0);
    if (n1) { stageB(q, 2, kt + 1); stageB(q, 3, kt + 1); }
    load_B4f<1>(Bb, wn, fr, kq, sw, b1);
    WAITLGKM(4);
    __builtin_amdgcn_s_setprio(1);
    mfma16f<0, 0>(af0, b0, acc);
    __builtin_amdgcn_s_setprio(0);
    __builtin_amdgcn_sched_barrier(0);
    SBAR();

    // ---- Phase 2
    if (n2) { stageA(p, 0, kt + 2); stageA(p, 2, kt + 2); }
    load_A8f<1>(Ab, wm, fr, kq, sw, af1);
    WAITLGKM(8);
    __builtin_amdgcn_s_setprio(1);
    mfma16f<0, 1>(af0, b1, acc);
    __builtin_amdgcn_s_setprio(0);
    __builtin_amdgcn_sched_barrier(0);
    SBAR();

    // ---- Phase 3
    if (n2) { stageB(p, 0, kt + 2); stageB(p, 1, kt + 2); }
    WAITLGKM(0);
    __builtin_amdgcn_s_setprio(1);
    mfma16f<1, 0>(af1, b0, acc);
    __builtin_amdgcn_s_setprio(0);
    __builtin_amdgcn_sched_barrier(0);
    SBAR();

    // ---- Phase 4
    if (n2) { stageA(p, 1, kt + 2); stageA(p, 3, kt + 2); }
    __builtin_amdgcn_s_setprio(1);
    mfma16f<1, 1>(af1, b1, acc);
    __builtin_amdgcn_s_setprio(0);
    __builtin_amdgcn_sched_barrier(0);
    if (n2)      asm volatile("s_waitcnt vmcnt(6)" ::: "memory");
    else if (n1) asm volatile("s_waitcnt vmcnt(0)" ::: "memory");
    SBAR();
  };

  for (int kt = 0; kt < NT_SC; kt += 2) {
    tile(ic<0>{}, kt);
    tile(ic<1>{}, kt + 1);
  }

  // ---- epilogue
#pragma unroll
  for (int mf = 0; mf < 8; ++mf) {
#pragma unroll
    for (int nf = 0; nf < 4; ++nf) {
      const int r0 = brow + wm * 128 + mf * 16 + (lane >> 4) * 4;
      const int c  = bcol + wn * 64 + nf * 16 + (lane & 15);
#pragma unroll
      for (int r = 0; r < 4; ++r)
        C[(size_t)(r0 + r) * N_SEQ + c] = acc[mf][nf][r];
    }
  }
}

// ======================= fused split (all fp16) =======================
// mode: 2 = fp16 hi/lo, 3 = fp16 hi only
struct SplitDesc {
  const float* src[7];
  f16_t* hi[7];
  f16_t* lo[7];
  int mode[7];
  int blk_start[8];
};

__global__ __launch_bounds__(256)
void split_all(SplitDesc d)
{
  const int b = blockIdx.x;
  int seg = 0;
#pragma unroll
  for (int s = 1; s < 7; ++s) seg += (b >= d.blk_start[s]) ? 1 : 0;
  const int i = (b - d.blk_start[seg]) * 256 + threadIdx.x;
  const float4 v = ((const float4*)d.src[seg])[i];
  const float vv[4] = {v.x, v.y, v.z, v.w};
  f16x4 h, l;
#pragma unroll
  for (int j = 0; j < 4; ++j) {
    const f16_t hh = (f16_t)vv[j];
    h[j] = hh;
    l[j] = (f16_t)(vv[j] - (float)hh);
  }
  ((f16x4*)d.hi[seg])[i] = h;
  if (d.mode[seg] == 2) ((f16x4*)d.lo[seg])[i] = l;
}

// ======================= softmax =======================
__global__ __launch_bounds__(256)
void softmax_rows(float* __restrict__ S, f16_t* __restrict__ P, int n)
{
  const int row = blockIdx.x;
  float* srow = S + (size_t)row * n;
  f16_t* prow = P + (size_t)row * n;
  const int t = threadIdx.x;
  const int lane = t & 63;
  const int wave = t >> 6;
  __shared__ float red[8];

  float4 v[4];
  float mx = -3.4e38f;
#pragma unroll
  for (int i = 0; i < 4; ++i) {
    v[i] = *(const float4*)(srow + (size_t)(i * 256 + t) * 4);
    mx = fmaxf(mx, fmaxf(fmaxf(v[i].x, v[i].y), fmaxf(v[i].z, v[i].w)));
  }
#pragma unroll
  for (int off = 32; off > 0; off >>= 1) mx = fmaxf(mx, __shfl_xor(mx, off));
  if (lane == 0) red[wave] = mx;
  __syncthreads();
  mx = fmaxf(fmaxf(red[0], red[1]), fmaxf(red[2], red[3]));

  float e[16];
  float sum = 0.f;
#pragma unroll
  for (int i = 0; i < 4; ++i) {
    e[4 * i + 0] = __expf(v[i].x - mx);
    e[4 * i + 1] = __expf(v[i].y - mx);
    e[4 * i + 2] = __expf(v[i].z - mx);
    e[4 * i + 3] = __expf(v[i].w - mx);
    sum += e[4 * i + 0] + e[4 * i + 1] + e[4 * i + 2] + e[4 * i + 3];
  }
#pragma unroll
  for (int off = 32; off > 0; off >>= 1) sum += __shfl_xor(sum, off);
  if (lane == 0) red[4 + wave] = sum;
  __syncthreads();
  sum = red[4] + red[5] + red[6] + red[7];
  const float inv = 1.0f / sum;

#pragma unroll
  for (int i = 0; i < 4; ++i) {
    float4 w;
    w.x = e[4 * i + 0] * inv;
    w.y = e[4 * i + 1] * inv;
    w.z = e[4 * i + 2] * inv;
    w.w = e[4 * i + 3] * inv;
    *(float4*)(srow + (size_t)(i * 256 + t) * 4) = w;
    f16x4 p;
    p[0] = (f16_t)w.x;
    p[1] = (f16_t)w.y;
    p[2] = (f16_t)w.z;
    p[3] = (f16_t)w.w;
    *(f16x4*)(prow + (size_t)(i * 256 + t) * 4) = p;
  }
}

extern "C" void kernel_launch(void* const* d_in, const int* in_sizes, int n_in,
                              void* d_out, int out_size, void* d_ws, size_t ws_size,
                              hipStream_t stream) {
  const int N = N_SEQ, D = DMODEL;
  const float* q    = (const float*)d_in[0];
  const float* k    = (const float*)d_in[1];
  const float* v    = (const float*)d_in[2];
  const float* wq_w = (const float*)d_in[3];
  const float* wq_b = (const float*)d_in[4];
  const float* wk_w = (const float*)d_in[5];
  const float* wk_b = (const float*)d_in[6];
  const float* wv_w = (const float*)d_in[7];
  const float* wv_b = (const float*)d_in[8];
  const float* wo_w = (const float*)d_in[9];
  const float* wo_b = (const float*)d_in[10];

  float* x_out = (float*)d_out;                 // [N, D]
  float* attn  = x_out + (size_t)N * D;         // [N, N]

  char* wsp = (char*)d_ws;
  auto alloc = [&](size_t bytes) { char* p = wsp; wsp += bytes; return p; };
  const size_t ND = (size_t)N * D, DD = (size_t)D * D;
  f16_t*  qh16  = (f16_t*)alloc(ND * 2);
  f16_t*  ql16  = (f16_t*)alloc(ND * 2);
  f16_t*  kh16  = (f16_t*)alloc(ND * 2);
  f16_t*  kl16  = (f16_t*)alloc(ND * 2);
  f16_t*  vh16  = (f16_t*)alloc(ND * 2);
  f16_t*  wq16  = (f16_t*)alloc(DD * 2);
  f16_t*  wk16  = (f16_t*)alloc(DD * 2);
  f16_t*  wv16  = (f16_t*)alloc(DD * 2);
  f16_t*  wo16  = (f16_t*)alloc(DD * 2);
  f16_t*  QPh   = (f16_t*)alloc(ND * 2);        // fp16 qp hi
  f16_t*  QPl   = (f16_t*)alloc(ND * 2);        // fp16 qp lo
  f16_t*  KPh   = (f16_t*)alloc(ND * 2);        // fp16 kp
  f16_t*  spare = (f16_t*)alloc(ND * 2);        // pad (keeps Pb region 32MB)
  f16_t*  VPt   = (f16_t*)alloc(ND * 2);        // [D][N] transposed fp16
  // aliases (producers run strictly after last readers of the underlying bufs)
  f16_t*  Pb    = QPh;          // 32 MB over QPh..spare (dead after scores)
  f16_t*  Xb    = vh16;         // 8 MB over vh16 (dead after qkv_proj)
  (void)spare;

  // fused split: q,k -> fp16 hi+lo; v -> fp16; all weights -> fp16
  SplitDesc sd;
  sd.src[0] = q;    sd.hi[0] = qh16;  sd.lo[0] = ql16;    sd.mode[0] = 2;
  sd.src[1] = k;    sd.hi[1] = kh16;  sd.lo[1] = kl16;    sd.mode[1] = 2;
  sd.src[2] = v;    sd.hi[2] = vh16;  sd.lo[2] = nullptr; sd.mode[2] = 3;
  sd.src[3] = wq_w; sd.hi[3] = wq16;  sd.lo[3] = nullptr; sd.mode[3] = 3;
  sd.src[4] = wk_w; sd.hi[4] = wk16;  sd.lo[4] = nullptr; sd.mode[4] = 3;
  sd.src[5] = wv_w; sd.hi[5] = wv16;  sd.lo[5] = nullptr; sd.mode[5] = 3;
  sd.src[6] = wo_w; sd.hi[6] = wo16;  sd.lo[6] = nullptr; sd.mode[6] = 3;
  const int nb_nd = (int)(ND / 4 / 256);   // 4096
  const int nb_dd = (int)(DD / 4 / 256);   // 1024
  sd.blk_start[0] = 0;
  sd.blk_start[1] = nb_nd;
  sd.blk_start[2] = 2 * nb_nd;
  sd.blk_start[3] = 3 * nb_nd;
  sd.blk_start[4] = 3 * nb_nd + nb_dd;
  sd.blk_start[5] = 3 * nb_nd + 2 * nb_dd;
  sd.blk_start[6] = 3 * nb_nd + 3 * nb_dd;
  sd.blk_start[7] = 3 * nb_nd + 4 * nb_dd;
  split_all<<<dim3(sd.blk_start[7]), dim3(256), 0, stream>>>(sd);

  const dim3 blk(256);
  const dim3 gsc(N / 256, N / 256);    // (16, 16)
  const dim3 gd(D / BN2, N / BM);      // (16, 32) = 512 blocks

  // fused Q/K/V projections: grid (8,32,3) -> 3 blocks/CU, all-fp16
  qkv_proj<<<dim3(D / BN, N / BM, 3), blk, 0, stream>>>(
      qh16, ql16, wq16, wq_b,
      kh16, kl16, wk16, wk_b,
      vh16, wv16, wv_b,
      QPh, QPl, KPh, VPt);

  // scores = (Qh+Ql) @ Kh^T  (fp16 2-pass, logical K=2048)
  gemm8f_scores<<<gsc, dim3(512), 0, stream>>>(QPh, QPl, KPh, attn);

  // softmax rows in-place + fp16 copy (Pb aliases QP/KP region: dead now)
  softmax_rows<<<dim3(N), blk, 0, stream>>>(attn, Pb, N);

  // X = P @ VP  (BK=64 swizzled, full K=4096 -> fp16 Xb)
  gemm_f16e<0><<<gd, blk, 0, stream>>>(
      Pb, VPt, nullptr, Xb, nullptr, N, D, N);

  // out = X @ wo^T + b  (BK=64 swizzled, full K=1024 -> fp32 d_out + bias)
  gemm_f16e<1><<<gd, blk, 0, stream>>>(
      Xb, wo16, wo_b, nullptr, x_out, N, D, D);
}

// Round 12
// 242.324 us; speedup vs baseline: 1.1751x; 1.0165x over previous
//
#include <hip/hip_runtime.h>
#include <cstdint>

// Problem constants (fixed by the reference)
#define N_SEQ 4096
#define DMODEL 1024

#define BM 128
#define BN 128
#define BN2 64
#define UNITE 4096   // one 64x64 f16 unit (8 KiB)

typedef __bf16 bf16_t;
typedef _Float16 f16_t;
typedef f16_t f16x8 __attribute__((ext_vector_type(8)));
typedef f16_t f16x4 __attribute__((ext_vector_type(4)));
typedef float f32x4 __attribute__((ext_vector_type(4)));

typedef __attribute__((address_space(1))) void* as1ptr;
typedef __attribute__((address_space(3))) void* as3ptr;

__device__ __forceinline__ void gload16(const void* g, void* l) {
  __builtin_amdgcn_global_load_lds((as1ptr)(uintptr_t)g, (as3ptr)(uintptr_t)l,
                                   16, 0, 0);
}

// ================= fused QKV projection (z = 0:Q, 1:K, 2:V) =================
// All-fp16, BK=64 swizzled units.  LDS 48 KiB -> 3 blocks/CU.
// slots: 0,1 = A0 (row-units); 2,3 = A1; 4,5 = B
__global__ __launch_bounds__(256)
void qkv_proj(const f16_t* __restrict__ qh, const f16_t* __restrict__ ql,
              const f16_t* __restrict__ wq, const float* __restrict__ wq_b,
              const f16_t* __restrict__ kh, const f16_t* __restrict__ kl,
              const f16_t* __restrict__ wk, const float* __restrict__ wk_b,
              const f16_t* __restrict__ vh, const f16_t* __restrict__ wv,
              const float* __restrict__ wv_b,
              f16_t* __restrict__ QPh, f16_t* __restrict__ QPl,
              f16_t* __restrict__ KPh, f16_t* __restrict__ VPt)
{
  __shared__ __align__(16) f16_t lds[6 * UNITE];   // 48 KiB

  const int z = blockIdx.z;
  const f16_t *A0, *A1 = nullptr, *B0;
  const float* bias;
  if (z == 0)      { A0 = qh; A1 = ql; B0 = wq; bias = wq_b; }
  else if (z == 1) { A0 = kh; A1 = kl; B0 = wk; bias = wk_b; }
  else             { A0 = vh;          B0 = wv; bias = wv_b; }
  const bool twop = (z < 2);

  const int M = N_SEQ, Nc = DMODEL, K = DMODEL;
  const int t = threadIdx.x;
  const int lane = t & 63;
  const int wave = t >> 6;
  const int wm = wave >> 1;     // 0..1 (row half of 128)
  const int wn = wave & 1;      // 0..1 (col half of 128)
  const int row0 = blockIdx.y * BM;
  const int col0 = blockIdx.x * BN;

  const int srw = t >> 3;                                // 0..31
  const int scol = 8 * ((t & 7) ^ ((t >> 3) & 7));       // pre-swizzled src
  const int sdst = t * 8;

  const int fr = lane & 15;
  const int kq = (lane >> 4) * 8;
  const int sw = (fr & 7) << 3;                          // read-side swizzle

  f32x4 acc[4][4] = {};

  for (int k0 = 0; k0 < K; k0 += 64) {
#pragma unroll
    for (int h = 0; h < 2; ++h) {
      const int r = h * 32 + srw;
      gload16(A0 + (size_t)(row0 + r) * K + k0 + scol,
              &lds[0 * UNITE + h * 2048 + sdst]);
      gload16(A0 + (size_t)(row0 + 64 + r) * K + k0 + scol,
              &lds[1 * UNITE + h * 2048 + sdst]);
      gload16(B0 + (size_t)(col0 + r) * K + k0 + scol,
              &lds[4 * UNITE + h * 2048 + sdst]);
      gload16(B0 + (size_t)(col0 + 64 + r) * K + k0 + scol,
              &lds[5 * UNITE + h * 2048 + sdst]);
      if (twop) {
        gload16(A1 + (size_t)(row0 + r) * K + k0 + scol,
                &lds[2 * UNITE + h * 2048 + sdst]);
        gload16(A1 + (size_t)(row0 + 64 + r) * K + k0 + scol,
                &lds[3 * UNITE + h * 2048 + sdst]);
      }
    }
    __syncthreads();

    f16x8 ah[4][2], al[4][2], bh[4][2];
#pragma unroll
    for (int m = 0; m < 4; ++m) {
      const int r = (m * 16 + fr) * 64;
#pragma unroll
      for (int ks = 0; ks < 2; ++ks) {
        const int c = (ks * 32 + kq) ^ sw;
        ah[m][ks] = *(const f16x8*)&lds[wm * UNITE + r + c];
        if (twop) al[m][ks] = *(const f16x8*)&lds[(2 + wm) * UNITE + r + c];
      }
    }
#pragma unroll
    for (int n = 0; n < 4; ++n) {
      const int r = (n * 16 + fr) * 64;
#pragma unroll
      for (int ks = 0; ks < 2; ++ks)
        bh[n][ks] = *(const f16x8*)&lds[(4 + wn) * UNITE + r +
                                        (((ks * 32 + kq)) ^ sw)];
    }

#pragma unroll
    for (int m = 0; m < 4; ++m)
#pragma unroll
      for (int n = 0; n < 4; ++n)
#pragma unroll
        for (int ks = 0; ks < 2; ++ks) {
          acc[m][n] = __builtin_amdgcn_mfma_f32_16x16x32_f16(
              ah[m][ks], bh[n][ks], acc[m][n], 0, 0, 0);
          if (twop)
            acc[m][n] = __builtin_amdgcn_mfma_f32_16x16x32_f16(
                al[m][ks], bh[n][ks], acc[m][n], 0, 0, 0);
        }
    __syncthreads();
  }

#pragma unroll
  for (int m = 0; m < 4; ++m) {
#pragma unroll
    for (int n = 0; n < 4; ++n) {
      const int grow0 = row0 + wm * 64 + m * 16 + (lane >> 4) * 4;
      const int gcol = col0 + wn * 64 + n * 16 + (lane & 15);
      const float bv = bias[gcol];
      if (z == 2) {
        f16x4 p;
#pragma unroll
        for (int r = 0; r < 4; ++r) p[r] = (f16_t)(acc[m][n][r] + bv);
        *(f16x4*)&VPt[(size_t)gcol * M + grow0] = p;
      } else if (z == 0) {
#pragma unroll
        for (int r = 0; r < 4; ++r) {
          const float val = acc[m][n][r] + bv;
          const size_t idx = (size_t)(grow0 + r) * Nc + gcol;
          const f16_t h = (f16_t)val;
          QPh[idx] = h;
          QPl[idx] = (f16_t)(val - (float)h);
        }
      } else {
#pragma unroll
        for (int r = 0; r < 4; ++r) {
          const float val = acc[m][n][r] + bv;
          KPh[(size_t)(grow0 + r) * Nc + gcol] = (f16_t)val;
        }
      }
    }
  }
}

// ========== direct fp16 GEMM, 128x64 tile, BK=128, swizzled units ==========
// OUT_F32=0: C = A@B^T        -> f16 Cf16
// OUT_F32=1: C = A@B^T + bias -> f32 Cf32
// LDS 48 KiB: A units [rb][cb] slots 0..3, B units [cb] slots 4,5.
template <int OUT_F32>
__global__ __launch_bounds__(256)
void gemm_f16e(const f16_t* __restrict__ A, const f16_t* __restrict__ B,
               const float* __restrict__ bias,
               f16_t* __restrict__ Cf16, float* __restrict__ Cf32,
               int M, int Nc, int K)
{
  __shared__ __align__(16) f16_t lds[6 * UNITE];   // 48 KiB

  // XCD swizzle (grids here are multiples of 8 blocks)
  const int gx = gridDim.x;
  const int nwg = gx * gridDim.y;
  const int flat = blockIdx.y * gx + blockIdx.x;
  const int swz = (flat & 7) * (nwg >> 3) + (flat >> 3);
  const int bx = swz % gx;
  const int by = swz / gx;

  const int t = threadIdx.x;
  const int lane = t & 63;
  const int wave = t >> 6;
  const int wm = wave >> 1;     // 0..1 (64-row half)
  const int wn = wave & 1;      // 0..1 (32-col half)
  const int row0 = by * BM;
  const int col0 = bx * BN2;

  const int srw = t >> 3;                                // 0..31
  const int scol = 8 * ((t & 7) ^ ((t >> 3) & 7));       // pre-swizzled src
  const int sdst = t * 8;

  const int fr = lane & 15;
  const int kq = (lane >> 4) * 8;
  const int sw = (fr & 7) << 3;                          // read-side swizzle

  f32x4 acc[4][2] = {};

  for (int k0 = 0; k0 < K; k0 += 128) {
#pragma unroll
    for (int h = 0; h < 2; ++h) {
      const int r = h * 32 + srw;
      gload16(A + (size_t)(row0 + r) * K + k0 + scol,
              &lds[0 * UNITE + h * 2048 + sdst]);           // rb0 cb0
      gload16(A + (size_t)(row0 + r) * K + k0 + 64 + scol,
              &lds[1 * UNITE + h * 2048 + sdst]);           // rb0 cb1
      gload16(A + (size_t)(row0 + 64 + r) * K + k0 + scol,
              &lds[2 * UNITE + h * 2048 + sdst]);           // rb1 cb0
      gload16(A + (size_t)(row0 + 64 + r) * K + k0 + 64 + scol,
              &lds[3 * UNITE + h * 2048 + sdst]);           // rb1 cb1
      gload16(B + (size_t)(col0 + r) * K + k0 + scol,
              &lds[4 * UNITE + h * 2048 + sdst]);           // cb0
      gload16(B + (size_t)(col0 + r) * K + k0 + 64 + scol,
              &lds[5 * UNITE + h * 2048 + sdst]);           // cb1
    }
    __syncthreads();

    f16x8 ah[4][4], bh[2][4];
#pragma unroll
    for (int m = 0; m < 4; ++m) {
      const int r = (m * 16 + fr) * 64;
#pragma unroll
      for (int ks = 0; ks < 4; ++ks) {
        const int unit = wm * 2 + (ks >> 1);
        ah[m][ks] = *(const f16x8*)&lds[unit * UNITE + r +
                                        ((((ks & 1) * 32 + kq)) ^ sw)];
      }
    }
#pragma unroll
    for (int n = 0; n < 2; ++n) {
      const int r = (wn * 32 + n * 16 + fr) * 64;
#pragma unroll
      for (int ks = 0; ks < 4; ++ks) {
        const int unit = 4 + (ks >> 1);
        bh[n][ks] = *(const f16x8*)&lds[unit * UNITE + r +
                                        ((((ks & 1) * 32 + kq)) ^ sw)];
      }
    }

#pragma unroll
    for (int m = 0; m < 4; ++m)
#pragma unroll
      for (int n = 0; n < 2; ++n)
#pragma unroll
        for (int ks = 0; ks < 4; ++ks)
          acc[m][n] = __builtin_amdgcn_mfma_f32_16x16x32_f16(
              ah[m][ks], bh[n][ks], acc[m][n], 0, 0, 0);
    __syncthreads();
  }

#pragma unroll
  for (int m = 0; m < 4; ++m) {
#pragma unroll
    for (int n = 0; n < 2; ++n) {
      const int grow0 = row0 + wm * 64 + m * 16 + (lane >> 4) * 4;
      const int gcol = col0 + wn * 32 + n * 16 + (lane & 15);
#pragma unroll
      for (int r = 0; r < 4; ++r) {
        const size_t idx = (size_t)(grow0 + r) * Nc + gcol;
        if (OUT_F32) Cf32[idx] = acc[m][n][r] + bias[gcol];
        else         Cf16[idx] = (f16_t)acc[m][n][r];
      }
    }
  }
}

// ============ fp16 2-pass 256x256 scores GEMM (R4 structure) ============
#define TILE_ELEMS 16384   // 256 rows x 64 cols
#define UNIT_ELEMS 4096    // 64 rows x 64 cols
#define NT_SC 32

template <int V> struct ic { static constexpr int value = V; };

#define SBAR() asm volatile("s_barrier" ::: "memory")
#define WAITLGKM(n)                                              \
  do {                                                           \
    asm volatile("s_waitcnt lgkmcnt(" #n ")" ::: "memory");      \
    __builtin_amdgcn_sched_barrier(0);                           \
  } while (0)

template <int MH>
__device__ __forceinline__ void load_A8f(const f16_t* Ab, int wm, int fr,
                                         int kq, int sw, f16x8 (&af)[4][2]) {
#pragma unroll
  for (int m = 0; m < 4; ++m) {
    const int row = wm * 128 + (MH * 4 + m) * 16 + fr;
#pragma unroll
    for (int ks = 0; ks < 2; ++ks)
      af[m][ks] = *(const f16x8*)&Ab[row * 64 + ((ks * 32 + kq) ^ sw)];
  }
}

template <int NH>
__device__ __forceinline__ void load_B4f(const f16_t* Bb, int wn, int fr,
                                         int kq, int sw, f16x8 (&bfr)[2][2]) {
#pragma unroll
  for (int n = 0; n < 2; ++n) {
    const int row = wn * 64 + (NH * 2 + n) * 16 + fr;
#pragma unroll
    for (int ks = 0; ks < 2; ++ks)
      bfr[n][ks] = *(const f16x8*)&Bb[row * 64 + ((ks * 32 + kq) ^ sw)];
  }
}

template <int MH, int NH>
__device__ __forceinline__ void mfma16f(const f16x8 (&af)[4][2],
                                        const f16x8 (&bfr)[2][2],
                                        f32x4 (&acc)[8][4]) {
#pragma unroll
  for (int m = 0; m < 4; ++m)
#pragma unroll
    for (int n = 0; n < 2; ++n)
#pragma unroll
      for (int ks = 0; ks < 2; ++ks)
        acc[MH * 4 + m][NH * 2 + n] = __builtin_amdgcn_mfma_f32_16x16x32_f16(
            af[m][ks], bfr[n][ks], acc[MH * 4 + m][NH * 2 + n], 0, 0, 0);
}

__global__ __launch_bounds__(512, 2)
void gemm8f_scores(const f16_t* __restrict__ Qh, const f16_t* __restrict__ Ql,
                   const f16_t* __restrict__ Kh, float* __restrict__ C)
{
  __shared__ __align__(16) f16_t sm[2 * 2 * TILE_ELEMS];  // 128 KiB

  const int t = threadIdx.x;
  const int lane = t & 63;
  const int wave = t >> 6;
  const int wm = wave >> 2;      // 0..1
  const int wn = wave & 3;       // 0..3

  // XCD-aware block swizzle: grid 16x16 = 256 blocks, 256 = 8*32 (bijective)
  const int flat = blockIdx.y * 16 + blockIdx.x;
  const int swzb = (flat & 7) * 32 + (flat >> 3);
  const int brow = (swzb >> 4) * 256;
  const int bcol = (swzb & 15) * 256;

  const int srow = t >> 3;                               // 0..63
  const int scol = 8 * ((t & 7) ^ ((t >> 3) & 7));       // involution
  const int sdst = t * 8;

  const int fr = lane & 15;
  const int kq = (lane >> 4) * 8;
  const int sw = (fr & 7) << 3;                          // read-side swizzle

  auto stageA = [&](int buf, int u, int kt) {
    const f16_t* src = (kt >= 16) ? Ql : Qh;
    const int kk = (kt & 15) << 6;
    gload16(src + (size_t)(brow + u * 64 + srow) * DMODEL + kk + scol,
            &sm[(buf * 2 + 0) * TILE_ELEMS + u * UNIT_ELEMS + sdst]);
  };
  auto stageB = [&](int buf, int u, int kt) {
    const int kk = (kt & 15) << 6;
    gload16(Kh + (size_t)(bcol + u * 64 + srow) * DMODEL + kk + scol,
            &sm[(buf * 2 + 1) * TILE_ELEMS + u * UNIT_ELEMS + sdst]);
  };

  f32x4 acc[8][4] = {};
  f16x8 af0[4][2], af1[4][2];
  f16x8 b0[2][2], b1[2][2];

  // ---- prologue: tile0 all 8 units; tile1's Ua, V01, Ub (6 loads).
#pragma unroll
  for (int u = 0; u < 4; ++u) stageA(0, u, 0);
#pragma unroll
  for (int u = 0; u < 4; ++u) stageB(0, u, 0);
  stageA(1, 0, 1); stageA(1, 2, 1);   // Ua(1)
  stageB(1, 0, 1); stageB(1, 1, 1);   // V01(1)
  stageA(1, 1, 1); stageA(1, 3, 1);   // Ub(1)
  asm volatile("s_waitcnt vmcnt(6)" ::: "memory");  // tile0's 8 landed
  SBAR();

  auto tile = [&](auto Pc, int kt) {
    constexpr int p = decltype(Pc)::value;
    constexpr int q = p ^ 1;
    const bool n1 = (kt + 1 < NT_SC);
    const bool n2 = (kt + 2 < NT_SC);
    const f16_t* Ab = &sm[(p * 2 + 0) * TILE_ELEMS];
    const f16_t* Bb = &sm[(p * 2 + 1) * TILE_ELEMS];

    // ---- Phase 1
    load_A8f<0>(Ab, wm, fr, kq, sw, af0);
    load_B4f<0>(Bb, wn, fr, kq, sw, b0);
    if (n1) { stageB(q, 2, kt + 1); stageB(q, 3, kt + 1); }
    load_B4f<1>(Bb, wn, fr, kq, sw, b1);
    WAITLGKM(4);
    __builtin_amdgcn_s_setprio(1);
    mfma16f<0, 0>(af0, b0, acc);
    __builtin_amdgcn_s_setprio(0);
    __builtin_amdgcn_sched_barrier(0);
    SBAR();

    // ---- Phase 2
    if (n2) { stageA(p, 0, kt + 2); stageA(p, 2, kt + 2); }
    load_A8f<1>(Ab, wm, fr, kq, sw, af1);
    WAITLGKM(8);
    __builtin_amdgcn_s_setprio(1);
    mfma16f<0, 1>(af0, b1, acc);
    __builtin_amdgcn_s_setprio(0);
    __builtin_amdgcn_sched_barrier(0);
    SBAR();

    // ---- Phase 3
    if (n2) { stageB(p, 0, kt + 2); stageB(p, 1, kt + 2); }
    WAITLGKM(0);
    __builtin_amdgcn_s_setprio(1);
    mfma16f<1, 0>(af1, b0, acc);
    __builtin_amdgcn_s_setprio(0);
    __builtin_amdgcn_sched_barrier(0);
    SBAR();

    // ---- Phase 4
    if (n2) { stageA(p, 1, kt + 2); stageA(p, 3, kt + 2); }
    __builtin_amdgcn_s_setprio(1);
    mfma16f<1, 1>(af1, b1, acc);
    __builtin_amdgcn_s_setprio(0);
    __builtin_amdgcn_sched_barrier(0);
    if (n2)      asm volatile("s_waitcnt vmcnt(6)" ::: "memory");
    else if (n1) asm volatile("s_waitcnt vmcnt(0)" ::: "memory");
    SBAR();
  };

  for (int kt = 0; kt < NT_SC; kt += 2) {
    tile(ic<0>{}, kt);
    tile(ic<1>{}, kt + 1);
  }

  // ---- epilogue
#pragma unroll
  for (int mf = 0; mf < 8; ++mf) {
#pragma unroll
    for (int nf = 0; nf < 4; ++nf) {
      const int r0 = brow + wm * 128 + mf * 16 + (lane >> 4) * 4;
      const int c  = bcol + wn * 64 + nf * 16 + (lane & 15);
#pragma unroll
      for (int r = 0; r < 4; ++r)
        C[(size_t)(r0 + r) * N_SEQ + c] = acc[mf][nf][r];
    }
  }
}

// ======================= fused split (all fp16) =======================
// mode: 2 = fp16 hi/lo, 3 = fp16 hi only
struct SplitDesc {
  const float* src[7];
  f16_t* hi[7];
  f16_t* lo[7];
  int mode[7];
  int blk_start[8];
};

__global__ __launch_bounds__(256)
void split_all(SplitDesc d)
{
  const int b = blockIdx.x;
  int seg = 0;
#pragma unroll
  for (int s = 1; s < 7; ++s) seg += (b >= d.blk_start[s]) ? 1 : 0;
  const int i = (b - d.blk_start[seg]) * 256 + threadIdx.x;
  const float4 v = ((const float4*)d.src[seg])[i];
  const float vv[4] = {v.x, v.y, v.z, v.w};
  f16x4 h, l;
#pragma unroll
  for (int j = 0; j < 4; ++j) {
    const f16_t hh = (f16_t)vv[j];
    h[j] = hh;
    l[j] = (f16_t)(vv[j] - (float)hh);
  }
  ((f16x4*)d.hi[seg])[i] = h;
  if (d.mode[seg] == 2) ((f16x4*)d.lo[seg])[i] = l;
}

// ======================= softmax =======================
__global__ __launch_bounds__(256)
void softmax_rows(float* __restrict__ S, f16_t* __restrict__ P, int n)
{
  const int row = blockIdx.x;
  float* srow = S + (size_t)row * n;
  f16_t* prow = P + (size_t)row * n;
  const int t = threadIdx.x;
  const int lane = t & 63;
  const int wave = t >> 6;
  __shared__ float red[8];

  float4 v[4];
  float mx = -3.4e38f;
#pragma unroll
  for (int i = 0; i < 4; ++i) {
    v[i] = *(const float4*)(srow + (size_t)(i * 256 + t) * 4);
    mx = fmaxf(mx, fmaxf(fmaxf(v[i].x, v[i].y), fmaxf(v[i].z, v[i].w)));
  }
#pragma unroll
  for (int off = 32; off > 0; off >>= 1) mx = fmaxf(mx, __shfl_xor(mx, off));
  if (lane == 0) red[wave] = mx;
  __syncthreads();
  mx = fmaxf(fmaxf(red[0], red[1]), fmaxf(red[2], red[3]));

  float e[16];
  float sum = 0.f;
#pragma unroll
  for (int i = 0; i < 4; ++i) {
    e[4 * i + 0] = __expf(v[i].x - mx);
    e[4 * i + 1] = __expf(v[i].y - mx);
    e[4 * i + 2] = __expf(v[i].z - mx);
    e[4 * i + 3] = __expf(v[i].w - mx);
    sum += e[4 * i + 0] + e[4 * i + 1] + e[4 * i + 2] + e[4 * i + 3];
  }
#pragma unroll
  for (int off = 32; off > 0; off >>= 1) sum += __shfl_xor(sum, off);
  if (lane == 0) red[4 + wave] = sum;
  __syncthreads();
  sum = red[4] + red[5] + red[6] + red[7];
  const float inv = 1.0f / sum;

#pragma unroll
  for (int i = 0; i < 4; ++i) {
    float4 w;
    w.x = e[4 * i + 0] * inv;
    w.y = e[4 * i + 1] * inv;
    w.z = e[4 * i + 2] * inv;
    w.w = e[4 * i + 3] * inv;
    *(float4*)(srow + (size_t)(i * 256 + t) * 4) = w;
    f16x4 p;
    p[0] = (f16_t)w.x;
    p[1] = (f16_t)w.y;
    p[2] = (f16_t)w.z;
    p[3] = (f16_t)w.w;
    *(f16x4*)(prow + (size_t)(i * 256 + t) * 4) = p;
  }
}

extern "C" void kernel_launch(void* const* d_in, const int* in_sizes, int n_in,
                              void* d_out, int out_size, void* d_ws, size_t ws_size,
                              hipStream_t stream) {
  const int N = N_SEQ, D = DMODEL;
  const float* q    = (const float*)d_in[0];
  const float* k    = (const float*)d_in[1];
  const float* v    = (const float*)d_in[2];
  const float* wq_w = (const float*)d_in[3];
  const float* wq_b = (const float*)d_in[4];
  const float* wk_w = (const float*)d_in[5];
  const float* wk_b = (const float*)d_in[6];
  const float* wv_w = (const float*)d_in[7];
  const float* wv_b = (const float*)d_in[8];
  const float* wo_w = (const float*)d_in[9];
  const float* wo_b = (const float*)d_in[10];

  float* x_out = (float*)d_out;                 // [N, D]
  float* attn  = x_out + (size_t)N * D;         // [N, N]

  char* wsp = (char*)d_ws;
  auto alloc = [&](size_t bytes) { char* p = wsp; wsp += bytes; return p; };
  const size_t ND = (size_t)N * D, DD = (size_t)D * D;
  f16_t*  qh16  = (f16_t*)alloc(ND * 2);
  f16_t*  ql16  = (f16_t*)alloc(ND * 2);
  f16_t*  kh16  = (f16_t*)alloc(ND * 2);
  f16_t*  kl16  = (f16_t*)alloc(ND * 2);
  f16_t*  vh16  = (f16_t*)alloc(ND * 2);
  f16_t*  wq16  = (f16_t*)alloc(DD * 2);
  f16_t*  wk16  = (f16_t*)alloc(DD * 2);
  f16_t*  wv16  = (f16_t*)alloc(DD * 2);
  f16_t*  wo16  = (f16_t*)alloc(DD * 2);
  f16_t*  QPh   = (f16_t*)alloc(ND * 2);        // fp16 qp hi
  f16_t*  QPl   = (f16_t*)alloc(ND * 2);        // fp16 qp lo
  f16_t*  KPh   = (f16_t*)alloc(ND * 2);        // fp16 kp
  f16_t*  spare = (f16_t*)alloc(ND * 2);        // pad (keeps Pb region 32MB)
  f16_t*  VPt   = (f16_t*)alloc(ND * 2);        // [D][N] transposed fp16
  // aliases (producers run strictly after last readers of the underlying bufs)
  f16_t*  Pb    = QPh;          // 32 MB over QPh..spare (dead after scores)
  f16_t*  Xb    = vh16;         // 8 MB over vh16 (dead after qkv_proj)
  (void)spare;

  // fused split: q,k -> fp16 hi+lo; v -> fp16; all weights -> fp16
  SplitDesc sd;
  sd.src[0] = q;    sd.hi[0] = qh16;  sd.lo[0] = ql16;    sd.mode[0] = 2;
  sd.src[1] = k;    sd.hi[1] = kh16;  sd.lo[1] = kl16;    sd.mode[1] = 2;
  sd.src[2] = v;    sd.hi[2] = vh16;  sd.lo[2] = nullptr; sd.mode[2] = 3;
  sd.src[3] = wq_w; sd.hi[3] = wq16;  sd.lo[3] = nullptr; sd.mode[3] = 3;
  sd.src[4] = wk_w; sd.hi[4] = wk16;  sd.lo[4] = nullptr; sd.mode[4] = 3;
  sd.src[5] = wv_w; sd.hi[5] = wv16;  sd.lo[5] = nullptr; sd.mode[5] = 3;
  sd.src[6] = wo_w; sd.hi[6] = wo16;  sd.lo[6] = nullptr; sd.mode[6] = 3;
  const int nb_nd = (int)(ND / 4 / 256);   // 4096
  const int nb_dd = (int)(DD / 4 / 256);   // 1024
  sd.blk_start[0] = 0;
  sd.blk_start[1] = nb_nd;
  sd.blk_start[2] = 2 * nb_nd;
  sd.blk_start[3] = 3 * nb_nd;
  sd.blk_start[4] = 3 * nb_nd + nb_dd;
  sd.blk_start[5] = 3 * nb_nd + 2 * nb_dd;
  sd.blk_start[6] = 3 * nb_nd + 3 * nb_dd;
  sd.blk_start[7] = 3 * nb_nd + 4 * nb_dd;
  split_all<<<dim3(sd.blk_start[7]), dim3(256), 0, stream>>>(sd);

  const dim3 blk(256);
  const dim3 gsc(N / 256, N / 256);    // (16, 16)
  const dim3 gd(D / BN2, N / BM);      // (16, 32) = 512 blocks

  // fused Q/K/V projections: grid (8,32,3) -> 3 blocks/CU, all-fp16, BK=64
  qkv_proj<<<dim3(D / BN, N / BM, 3), blk, 0, stream>>>(
      qh16, ql16, wq16, wq_b,
      kh16, kl16, wk16, wk_b,
      vh16, wv16, wv_b,
      QPh, QPl, KPh, VPt);

  // scores = (Qh+Ql) @ Kh^T  (fp16 2-pass, logical K=2048)
  gemm8f_scores<<<gsc, dim3(512), 0, stream>>>(QPh, QPl, KPh, attn);

  // softmax rows in-place + fp16 copy (Pb aliases QP/KP region: dead now)
  softmax_rows<<<dim3(N), blk, 0, stream>>>(attn, Pb, N);

  // X = P @ VP  (BK=128 swizzled, full K=4096 -> fp16 Xb)
  gemm_f16e<0><<<gd, blk, 0, stream>>>(
      Pb, VPt, nullptr, Xb, nullptr, N, D, N);

  // out = X @ wo^T + b  (BK=128 swizzled, full K=1024 -> fp32 d_out + bias)
  gemm_f16e<1><<<gd, blk, 0, stream>>>(
      Xb, wo16, wo_b, nullptr, x_out, N, D, D);
}

// Round 13
// 235.900 us; speedup vs baseline: 1.2071x; 1.0272x over previous
//
#include <hip/hip_runtime.h>
#include <cstdint>

// Problem constants (fixed by the reference)
#define N_SEQ 4096
#define DMODEL 1024

#define BM 128
#define BN 128
#define BN2 64
#define UNITE 4096   // one 64x64 f16 unit (8 KiB)

typedef __bf16 bf16_t;
typedef _Float16 f16_t;
typedef f16_t f16x8 __attribute__((ext_vector_type(8)));
typedef f16_t f16x4 __attribute__((ext_vector_type(4)));
typedef float f32x4 __attribute__((ext_vector_type(4)));

typedef __attribute__((address_space(1))) void* as1ptr;
typedef __attribute__((address_space(3))) void* as3ptr;

__device__ __forceinline__ void gload16(const void* g, void* l) {
  __builtin_amdgcn_global_load_lds((as1ptr)(uintptr_t)g, (as3ptr)(uintptr_t)l,
                                   16, 0, 0);
}

// ================= fused QKV projection (z = 0:Q, 1:K, 2:V) =================
// All-fp16, BK=64 swizzled units.  LDS 48 KiB -> 3 blocks/CU.
// slots: 0,1 = A0 (row-units); 2,3 = A1; 4,5 = B
// XCD swizzle on the (x,y) plane (256 blocks per z, 256%8==0 -> bijective).
__global__ __launch_bounds__(256)
void qkv_proj(const f16_t* __restrict__ qh, const f16_t* __restrict__ ql,
              const f16_t* __restrict__ wq, const float* __restrict__ wq_b,
              const f16_t* __restrict__ kh, const f16_t* __restrict__ kl,
              const f16_t* __restrict__ wk, const float* __restrict__ wk_b,
              const f16_t* __restrict__ vh, const f16_t* __restrict__ wv,
              const float* __restrict__ wv_b,
              f16_t* __restrict__ QPh, f16_t* __restrict__ QPl,
              f16_t* __restrict__ KPh, f16_t* __restrict__ VPt)
{
  __shared__ __align__(16) f16_t lds[6 * UNITE];   // 48 KiB

  const int z = blockIdx.z;
  const f16_t *A0, *A1 = nullptr, *B0;
  const float* bias;
  if (z == 0)      { A0 = qh; A1 = ql; B0 = wq; bias = wq_b; }
  else if (z == 1) { A0 = kh; A1 = kl; B0 = wk; bias = wk_b; }
  else             { A0 = vh;          B0 = wv; bias = wv_b; }
  const bool twop = (z < 2);

  const int M = N_SEQ, Nc = DMODEL, K = DMODEL;
  const int t = threadIdx.x;
  const int lane = t & 63;
  const int wave = t >> 6;
  const int wm = wave >> 1;     // 0..1 (row half of 128)
  const int wn = wave & 1;      // 0..1 (col half of 128)

  // XCD-aware swizzle within the 8x32 (x,y) plane
  const int gx = gridDim.x;                       // 8
  const int nwg = gx * gridDim.y;                 // 256
  const int flat = blockIdx.y * gx + blockIdx.x;
  const int swz = (flat & 7) * (nwg >> 3) + (flat >> 3);
  const int row0 = (swz / gx) * BM;
  const int col0 = (swz % gx) * BN;

  const int srw = t >> 3;                                // 0..31
  const int scol = 8 * ((t & 7) ^ ((t >> 3) & 7));       // pre-swizzled src
  const int sdst = t * 8;

  const int fr = lane & 15;
  const int kq = (lane >> 4) * 8;
  const int sw = (fr & 7) << 3;                          // read-side swizzle

  f32x4 acc[4][4] = {};

  for (int k0 = 0; k0 < K; k0 += 64) {
#pragma unroll
    for (int h = 0; h < 2; ++h) {
      const int r = h * 32 + srw;
      gload16(A0 + (size_t)(row0 + r) * K + k0 + scol,
              &lds[0 * UNITE + h * 2048 + sdst]);
      gload16(A0 + (size_t)(row0 + 64 + r) * K + k0 + scol,
              &lds[1 * UNITE + h * 2048 + sdst]);
      gload16(B0 + (size_t)(col0 + r) * K + k0 + scol,
              &lds[4 * UNITE + h * 2048 + sdst]);
      gload16(B0 + (size_t)(col0 + 64 + r) * K + k0 + scol,
              &lds[5 * UNITE + h * 2048 + sdst]);
      if (twop) {
        gload16(A1 + (size_t)(row0 + r) * K + k0 + scol,
                &lds[2 * UNITE + h * 2048 + sdst]);
        gload16(A1 + (size_t)(row0 + 64 + r) * K + k0 + scol,
                &lds[3 * UNITE + h * 2048 + sdst]);
      }
    }
    __syncthreads();

    f16x8 ah[4][2], al[4][2], bh[4][2];
#pragma unroll
    for (int m = 0; m < 4; ++m) {
      const int r = (m * 16 + fr) * 64;
#pragma unroll
      for (int ks = 0; ks < 2; ++ks) {
        const int c = (ks * 32 + kq) ^ sw;
        ah[m][ks] = *(const f16x8*)&lds[wm * UNITE + r + c];
        if (twop) al[m][ks] = *(const f16x8*)&lds[(2 + wm) * UNITE + r + c];
      }
    }
#pragma unroll
    for (int n = 0; n < 4; ++n) {
      const int r = (n * 16 + fr) * 64;
#pragma unroll
      for (int ks = 0; ks < 2; ++ks)
        bh[n][ks] = *(const f16x8*)&lds[(4 + wn) * UNITE + r +
                                        (((ks * 32 + kq)) ^ sw)];
    }

#pragma unroll
    for (int m = 0; m < 4; ++m)
#pragma unroll
      for (int n = 0; n < 4; ++n)
#pragma unroll
        for (int ks = 0; ks < 2; ++ks) {
          acc[m][n] = __builtin_amdgcn_mfma_f32_16x16x32_f16(
              ah[m][ks], bh[n][ks], acc[m][n], 0, 0, 0);
          if (twop)
            acc[m][n] = __builtin_amdgcn_mfma_f32_16x16x32_f16(
                al[m][ks], bh[n][ks], acc[m][n], 0, 0, 0);
        }
    __syncthreads();
  }

#pragma unroll
  for (int m = 0; m < 4; ++m) {
#pragma unroll
    for (int n = 0; n < 4; ++n) {
      const int grow0 = row0 + wm * 64 + m * 16 + (lane >> 4) * 4;
      const int gcol = col0 + wn * 64 + n * 16 + (lane & 15);
      const float bv = bias[gcol];
      if (z == 2) {
        f16x4 p;
#pragma unroll
        for (int r = 0; r < 4; ++r) p[r] = (f16_t)(acc[m][n][r] + bv);
        *(f16x4*)&VPt[(size_t)gcol * M + grow0] = p;
      } else if (z == 0) {
#pragma unroll
        for (int r = 0; r < 4; ++r) {
          const float val = acc[m][n][r] + bv;
          const size_t idx = (size_t)(grow0 + r) * Nc + gcol;
          const f16_t h = (f16_t)val;
          QPh[idx] = h;
          QPl[idx] = (f16_t)(val - (float)h);
        }
      } else {
#pragma unroll
        for (int r = 0; r < 4; ++r) {
          const float val = acc[m][n][r] + bv;
          KPh[(size_t)(grow0 + r) * Nc + gcol] = (f16_t)val;
        }
      }
    }
  }
}

// ========== direct fp16 GEMM, 128x64 tile, BK=128, swizzled units ==========
template <int OUT_F32>
__global__ __launch_bounds__(256)
void gemm_f16e(const f16_t* __restrict__ A, const f16_t* __restrict__ B,
               const float* __restrict__ bias,
               f16_t* __restrict__ Cf16, float* __restrict__ Cf32,
               int M, int Nc, int K)
{
  __shared__ __align__(16) f16_t lds[6 * UNITE];   // 48 KiB

  const int gx = gridDim.x;
  const int nwg = gx * gridDim.y;
  const int flat = blockIdx.y * gx + blockIdx.x;
  const int swz = (flat & 7) * (nwg >> 3) + (flat >> 3);
  const int bx = swz % gx;
  const int by = swz / gx;

  const int t = threadIdx.x;
  const int lane = t & 63;
  const int wave = t >> 6;
  const int wm = wave >> 1;
  const int wn = wave & 1;
  const int row0 = by * BM;
  const int col0 = bx * BN2;

  const int srw = t >> 3;
  const int scol = 8 * ((t & 7) ^ ((t >> 3) & 7));
  const int sdst = t * 8;

  const int fr = lane & 15;
  const int kq = (lane >> 4) * 8;
  const int sw = (fr & 7) << 3;

  f32x4 acc[4][2] = {};

  for (int k0 = 0; k0 < K; k0 += 128) {
#pragma unroll
    for (int h = 0; h < 2; ++h) {
      const int r = h * 32 + srw;
      gload16(A + (size_t)(row0 + r) * K + k0 + scol,
              &lds[0 * UNITE + h * 2048 + sdst]);
      gload16(A + (size_t)(row0 + r) * K + k0 + 64 + scol,
              &lds[1 * UNITE + h * 2048 + sdst]);
      gload16(A + (size_t)(row0 + 64 + r) * K + k0 + scol,
              &lds[2 * UNITE + h * 2048 + sdst]);
      gload16(A + (size_t)(row0 + 64 + r) * K + k0 + 64 + scol,
              &lds[3 * UNITE + h * 2048 + sdst]);
      gload16(B + (size_t)(col0 + r) * K + k0 + scol,
              &lds[4 * UNITE + h * 2048 + sdst]);
      gload16(B + (size_t)(col0 + r) * K + k0 + 64 + scol,
              &lds[5 * UNITE + h * 2048 + sdst]);
    }
    __syncthreads();

    f16x8 ah[4][4], bh[2][4];
#pragma unroll
    for (int m = 0; m < 4; ++m) {
      const int r = (m * 16 + fr) * 64;
#pragma unroll
      for (int ks = 0; ks < 4; ++ks) {
        const int unit = wm * 2 + (ks >> 1);
        ah[m][ks] = *(const f16x8*)&lds[unit * UNITE + r +
                                        ((((ks & 1) * 32 + kq)) ^ sw)];
      }
    }
#pragma unroll
    for (int n = 0; n < 2; ++n) {
      const int r = (wn * 32 + n * 16 + fr) * 64;
#pragma unroll
      for (int ks = 0; ks < 4; ++ks) {
        const int unit = 4 + (ks >> 1);
        bh[n][ks] = *(const f16x8*)&lds[unit * UNITE + r +
                                        ((((ks & 1) * 32 + kq)) ^ sw)];
      }
    }

#pragma unroll
    for (int m = 0; m < 4; ++m)
#pragma unroll
      for (int n = 0; n < 2; ++n)
#pragma unroll
        for (int ks = 0; ks < 4; ++ks)
          acc[m][n] = __builtin_amdgcn_mfma_f32_16x16x32_f16(
              ah[m][ks], bh[n][ks], acc[m][n], 0, 0, 0);
    __syncthreads();
  }

#pragma unroll
  for (int m = 0; m < 4; ++m) {
#pragma unroll
    for (int n = 0; n < 2; ++n) {
      const int grow0 = row0 + wm * 64 + m * 16 + (lane >> 4) * 4;
      const int gcol = col0 + wn * 32 + n * 16 + (lane & 15);
#pragma unroll
      for (int r = 0; r < 4; ++r) {
        const size_t idx = (size_t)(grow0 + r) * Nc + gcol;
        if (OUT_F32) Cf32[idx] = acc[m][n][r] + bias[gcol];
        else         Cf16[idx] = (f16_t)acc[m][n][r];
      }
    }
  }
}

// ============ fp16 2-pass 256x256 scores GEMM (R4 structure) ============
#define TILE_ELEMS 16384   // 256 rows x 64 cols
#define UNIT_ELEMS 4096    // 64 rows x 64 cols
#define NT_SC 32

template <int V> struct ic { static constexpr int value = V; };

#define SBAR() asm volatile("s_barrier" ::: "memory")
#define WAITLGKM(n)                                              \
  do {                                                           \
    asm volatile("s_waitcnt lgkmcnt(" #n ")" ::: "memory");      \
    __builtin_amdgcn_sched_barrier(0);                           \
  } while (0)

template <int MH>
__device__ __forceinline__ void load_A8f(const f16_t* Ab, int wm, int fr,
                                         int kq, int sw, f16x8 (&af)[4][2]) {
#pragma unroll
  for (int m = 0; m < 4; ++m) {
    const int row = wm * 128 + (MH * 4 + m) * 16 + fr;
#pragma unroll
    for (int ks = 0; ks < 2; ++ks)
      af[m][ks] = *(const f16x8*)&Ab[row * 64 + ((ks * 32 + kq) ^ sw)];
  }
}

template <int NH>
__device__ __forceinline__ void load_B4f(const f16_t* Bb, int wn, int fr,
                                         int kq, int sw, f16x8 (&bfr)[2][2]) {
#pragma unroll
  for (int n = 0; n < 2; ++n) {
    const int row = wn * 64 + (NH * 2 + n) * 16 + fr;
#pragma unroll
    for (int ks = 0; ks < 2; ++ks)
      bfr[n][ks] = *(const f16x8*)&Bb[row * 64 + ((ks * 32 + kq) ^ sw)];
  }
}

template <int MH, int NH>
__device__ __forceinline__ void mfma16f(const f16x8 (&af)[4][2],
                                        const f16x8 (&bfr)[2][2],
                                        f32x4 (&acc)[8][4]) {
#pragma unroll
  for (int m = 0; m < 4; ++m)
#pragma unroll
    for (int n = 0; n < 2; ++n)
#pragma unroll
      for (int ks = 0; ks < 2; ++ks)
        acc[MH * 4 + m][NH * 2 + n] = __builtin_amdgcn_mfma_f32_16x16x32_f16(
            af[m][ks], bfr[n][ks], acc[MH * 4 + m][NH * 2 + n], 0, 0, 0);
}

__global__ __launch_bounds__(512, 1)
void gemm8f_scores(const f16_t* __restrict__ Qh, const f16_t* __restrict__ Ql,
                   const f16_t* __restrict__ Kh, float* __restrict__ C)
{
  __shared__ __align__(16) f16_t sm[2 * 2 * TILE_ELEMS];  // 128 KiB

  const int t = threadIdx.x;
  const int lane = t & 63;
  const int wave = t >> 6;
  const int wm = wave >> 2;      // 0..1
  const int wn = wave & 3;       // 0..3

  // XCD-aware block swizzle: grid 16x16 = 256 blocks, 256 = 8*32 (bijective)
  const int flat = blockIdx.y * 16 + blockIdx.x;
  const int swzb = (flat & 7) * 32 + (flat >> 3);
  const int brow = (swzb >> 4) * 256;
  const int bcol = (swzb & 15) * 256;

  const int srow = t >> 3;                               // 0..63
  const int scol = 8 * ((t & 7) ^ ((t >> 3) & 7));       // involution
  const int sdst = t * 8;

  const int fr = lane & 15;
  const int kq = (lane >> 4) * 8;
  const int sw = (fr & 7) << 3;                          // read-side swizzle

  auto stageA = [&](int buf, int u, int kt) {
    const f16_t* src = (kt >= 16) ? Ql : Qh;
    const int kk = (kt & 15) << 6;
    gload16(src + (size_t)(brow + u * 64 + srow) * DMODEL + kk + scol,
            &sm[(buf * 2 + 0) * TILE_ELEMS + u * UNIT_ELEMS + sdst]);
  };
  auto stageB = [&](int buf, int u, int kt) {
    const int kk = (kt & 15) << 6;
    gload16(Kh + (size_t)(bcol + u * 64 + srow) * DMODEL + kk + scol,
            &sm[(buf * 2 + 1) * TILE_ELEMS + u * UNIT_ELEMS + sdst]);
  };

  f32x4 acc[8][4] = {};
  f16x8 af0[4][2], af1[4][2];
  f16x8 b0[2][2], b1[2][2];

  // ---- prologue: tile0 all 8 units; tile1's Ua, V01, Ub (6 loads).
#pragma unroll
  for (int u = 0; u < 4; ++u) stageA(0, u, 0);
#pragma unroll
  for (int u = 0; u < 4; ++u) stageB(0, u, 0);
  stageA(1, 0, 1); stageA(1, 2, 1);   // Ua(1)
  stageB(1, 0, 1); stageB(1, 1, 1);   // V01(1)
  stageA(1, 1, 1); stageA(1, 3, 1);   // Ub(1)
  asm volatile("s_waitcnt vmcnt(6)" ::: "memory");  // tile0's 8 landed
  SBAR();

  auto tile = [&](auto Pc, int kt) {
    constexpr int p = decltype(Pc)::value;
    constexpr int q = p ^ 1;
    const bool n1 = (kt + 1 < NT_SC);
    const bool n2 = (kt + 2 < NT_SC);
    const f16_t* Ab = &sm[(p * 2 + 0) * TILE_ELEMS];
    const f16_t* Bb = &sm[(p * 2 + 1) * TILE_ELEMS];

    // ---- Phase 1
    load_A8f<0>(Ab, wm, fr, kq, sw, af0);
    load_B4f<0>(Bb, wn, fr, kq, sw, b0);
    if (n1) { stageB(q, 2, kt + 1); stageB(q, 3, kt + 1); }
    load_B4f<1>(Bb, wn, fr, kq, sw, b1);
    WAITLGKM(4);
    __builtin_amdgcn_s_setprio(1);
    mfma16f<0, 0>(af0, b0, acc);
    __builtin_amdgcn_s_setprio(0);
    __builtin_amdgcn_sched_barrier(0);
    SBAR();

    // ---- Phase 2
    if (n2) { stageA(p, 0, kt + 2); stageA(p, 2, kt + 2); }
    load_A8f<1>(Ab, wm, fr, kq, sw, af1);
    WAITLGKM(8);
    __builtin_amdgcn_s_setprio(1);
    mfma16f<0, 1>(af0, b1, acc);
    __builtin_amdgcn_s_setprio(0);
    __builtin_amdgcn_sched_barrier(0);
    SBAR();

    // ---- Phase 3
    if (n2) { stageB(p, 0, kt + 2); stageB(p, 1, kt + 2); }
    WAITLGKM(0);
    __builtin_amdgcn_s_setprio(1);
    mfma16f<1, 0>(af1, b0, acc);
    __builtin_amdgcn_s_setprio(0);
    __builtin_amdgcn_sched_barrier(0);
    SBAR();

    // ---- Phase 4
    if (n2) { stageA(p, 1, kt + 2); stageA(p, 3, kt + 2); }
    __builtin_amdgcn_s_setprio(1);
    mfma16f<1, 1>(af1, b1, acc);
    __builtin_amdgcn_s_setprio(0);
    __builtin_amdgcn_sched_barrier(0);
    if (n2)      asm volatile("s_waitcnt vmcnt(6)" ::: "memory");
    else if (n1) asm volatile("s_waitcnt vmcnt(0)" ::: "memory");
    SBAR();
  };

  for (int kt = 0; kt < NT_SC; kt += 2) {
    tile(ic<0>{}, kt);
    tile(ic<1>{}, kt + 1);
  }

  // ---- epilogue
#pragma unroll
  for (int mf = 0; mf < 8; ++mf) {
#pragma unroll
    for (int nf = 0; nf < 4; ++nf) {
      const int r0 = brow + wm * 128 + mf * 16 + (lane >> 4) * 4;
      const int c  = bcol + wn * 64 + nf * 16 + (lane & 15);
#pragma unroll
      for (int r = 0; r < 4; ++r)
        C[(size_t)(r0 + r) * N_SEQ + c] = acc[mf][nf][r];
    }
  }
}

// ======================= fused split (all fp16) =======================
struct SplitDesc {
  const float* src[7];
  f16_t* hi[7];
  f16_t* lo[7];
  int mode[7];
  int blk_start[8];
};

__global__ __launch_bounds__(256)
void split_all(SplitDesc d)
{
  const int b = blockIdx.x;
  int seg = 0;
#pragma unroll
  for (int s = 1; s < 7; ++s) seg += (b >= d.blk_start[s]) ? 1 : 0;
  const int i = (b - d.blk_start[seg]) * 256 + threadIdx.x;
  const float4 v = ((const float4*)d.src[seg])[i];
  const float vv[4] = {v.x, v.y, v.z, v.w};
  f16x4 h, l;
#pragma unroll
  for (int j = 0; j < 4; ++j) {
    const f16_t hh = (f16_t)vv[j];
    h[j] = hh;
    l[j] = (f16_t)(vv[j] - (float)hh);
  }
  ((f16x4*)d.hi[seg])[i] = h;
  if (d.mode[seg] == 2) ((f16x4*)d.lo[seg])[i] = l;
}

// ======================= softmax =======================
__global__ __launch_bounds__(256)
void softmax_rows(float* __restrict__ S, f16_t* __restrict__ P, int n)
{
  const int row = blockIdx.x;
  float* srow = S + (size_t)row * n;
  f16_t* prow = P + (size_t)row * n;
  const int t = threadIdx.x;
  const int lane = t & 63;
  const int wave = t >> 6;
  __shared__ float red[8];

  float4 v[4];
  float mx = -3.4e38f;
#pragma unroll
  for (int i = 0; i < 4; ++i) {
    v[i] = *(const float4*)(srow + (size_t)(i * 256 + t) * 4);
    mx = fmaxf(mx, fmaxf(fmaxf(v[i].x, v[i].y), fmaxf(v[i].z, v[i].w)));
  }
#pragma unroll
  for (int off = 32; off > 0; off >>= 1) mx = fmaxf(mx, __shfl_xor(mx, off));
  if (lane == 0) red[wave] = mx;
  __syncthreads();
  mx = fmaxf(fmaxf(red[0], red[1]), fmaxf(red[2], red[3]));

  float e[16];
  float sum = 0.f;
#pragma unroll
  for (int i = 0; i < 4; ++i) {
    e[4 * i + 0] = __expf(v[i].x - mx);
    e[4 * i + 1] = __expf(v[i].y - mx);
    e[4 * i + 2] = __expf(v[i].z - mx);
    e[4 * i + 3] = __expf(v[i].w - mx);
    sum += e[4 * i + 0] + e[4 * i + 1] + e[4 * i + 2] + e[4 * i + 3];
  }
#pragma unroll
  for (int off = 32; off > 0; off >>= 1) sum += __shfl_xor(sum, off);
  if (lane == 0) red[4 + wave] = sum;
  __syncthreads();
  sum = red[4] + red[5] + red[6] + red[7];
  const float inv = 1.0f / sum;

#pragma unroll
  for (int i = 0; i < 4; ++i) {
    float4 w;
    w.x = e[4 * i + 0] * inv;
    w.y = e[4 * i + 1] * inv;
    w.z = e[4 * i + 2] * inv;
    w.w = e[4 * i + 3] * inv;
    *(float4*)(srow + (size_t)(i * 256 + t) * 4) = w;
    f16x4 p;
    p[0] = (f16_t)w.x;
    p[1] = (f16_t)w.y;
    p[2] = (f16_t)w.z;
    p[3] = (f16_t)w.w;
    *(f16x4*)(prow + (size_t)(i * 256 + t) * 4) = p;
  }
}

extern "C" void kernel_launch(void* const* d_in, const int* in_sizes, int n_in,
                              void* d_out, int out_size, void* d_ws, size_t ws_size,
                              hipStream_t stream) {
  const int N = N_SEQ, D = DMODEL;
  const float* q    = (const float*)d_in[0];
  const float* k    = (const float*)d_in[1];
  const float* v    = (const float*)d_in[2];
  const float* wq_w = (const float*)d_in[3];
  const float* wq_b = (const float*)d_in[4];
  const float* wk_w = (const float*)d_in[5];
  const float* wk_b = (const float*)d_in[6];
  const float* wv_w = (const float*)d_in[7];
  const float* wv_b = (const float*)d_in[8];
  const float* wo_w = (const float*)d_in[9];
  const float* wo_b = (const float*)d_in[10];

  float* x_out = (float*)d_out;                 // [N, D]
  float* attn  = x_out + (size_t)N * D;         // [N, N]

  char* wsp = (char*)d_ws;
  auto alloc = [&](size_t bytes) { char* p = wsp; wsp += bytes; return p; };
  const size_t ND = (size_t)N * D, DD = (size_t)D * D;
  f16_t*  qh16  = (f16_t*)alloc(ND * 2);
  f16_t*  ql16  = (f16_t*)alloc(ND * 2);
  f16_t*  kh16  = (f16_t*)alloc(ND * 2);
  f16_t*  kl16  = (f16_t*)alloc(ND * 2);
  f16_t*  vh16  = (f16_t*)alloc(ND * 2);
  f16_t*  wq16  = (f16_t*)alloc(DD * 2);
  f16_t*  wk16  = (f16_t*)alloc(DD * 2);
  f16_t*  wv16  = (f16_t*)alloc(DD * 2);
  f16_t*  wo16  = (f16_t*)alloc(DD * 2);
  f16_t*  QPh   = (f16_t*)alloc(ND * 2);        // fp16 qp hi
  f16_t*  QPl   = (f16_t*)alloc(ND * 2);        // fp16 qp lo
  f16_t*  KPh   = (f16_t*)alloc(ND * 2);        // fp16 kp
  f16_t*  spare = (f16_t*)alloc(ND * 2);        // pad (keeps Pb region 32MB)
  f16_t*  VPt   = (f16_t*)alloc(ND * 2);        // [D][N] transposed fp16
  // aliases (producers run strictly after last readers of the underlying bufs)
  f16_t*  Pb    = QPh;          // 32 MB over QPh..spare (dead after scores)
  f16_t*  Xb    = vh16;         // 8 MB over vh16 (dead after qkv_proj)
  (void)spare;

  // fused split: q,k -> fp16 hi+lo; v -> fp16; all weights -> fp16
  SplitDesc sd;
  sd.src[0] = q;    sd.hi[0] = qh16;  sd.lo[0] = ql16;    sd.mode[0] = 2;
  sd.src[1] = k;    sd.hi[1] = kh16;  sd.lo[1] = kl16;    sd.mode[1] = 2;
  sd.src[2] = v;    sd.hi[2] = vh16;  sd.lo[2] = nullptr; sd.mode[2] = 3;
  sd.src[3] = wq_w; sd.hi[3] = wq16;  sd.lo[3] = nullptr; sd.mode[3] = 3;
  sd.src[4] = wk_w; sd.hi[4] = wk16;  sd.lo[4] = nullptr; sd.mode[4] = 3;
  sd.src[5] = wv_w; sd.hi[5] = wv16;  sd.lo[5] = nullptr; sd.mode[5] = 3;
  sd.src[6] = wo_w; sd.hi[6] = wo16;  sd.lo[6] = nullptr; sd.mode[6] = 3;
  const int nb_nd = (int)(ND / 4 / 256);   // 4096
  const int nb_dd = (int)(DD / 4 / 256);   // 1024
  sd.blk_start[0] = 0;
  sd.blk_start[1] = nb_nd;
  sd.blk_start[2] = 2 * nb_nd;
  sd.blk_start[3] = 3 * nb_nd;
  sd.blk_start[4] = 3 * nb_nd + nb_dd;
  sd.blk_start[5] = 3 * nb_nd + 2 * nb_dd;
  sd.blk_start[6] = 3 * nb_nd + 3 * nb_dd;
  sd.blk_start[7] = 3 * nb_nd + 4 * nb_dd;
  split_all<<<dim3(sd.blk_start[7]), dim3(256), 0, stream>>>(sd);

  const dim3 blk(256);
  const dim3 gsc(N / 256, N / 256);    // (16, 16)
  const dim3 gd(D / BN2, N / BM);      // (16, 32) = 512 blocks

  // fused Q/K/V projections: grid (8,32,3) -> 3 blocks/CU, all-fp16, BK=64
  qkv_proj<<<dim3(D / BN, N / BM, 3), blk, 0, stream>>>(
      qh16, ql16, wq16, wq_b,
      kh16, kl16, wk16, wk_b,
      vh16, wv16, wv_b,
      QPh, QPl, KPh, VPt);

  // scores = (Qh+Ql) @ Kh^T  (fp16 2-pass, logical K=2048)
  gemm8f_scores<<<gsc, dim3(512), 0, stream>>>(QPh, QPl, KPh, attn);

  // softmax rows in-place + fp16 copy (Pb aliases QP/KP region: dead now)
  softmax_rows<<<dim3(N), blk, 0, stream>>>(attn, Pb, N);

  // X = P @ VP  (BK=128 swizzled, full K=4096 -> fp16 Xb)
  gemm_f16e<0><<<gd, blk, 0, stream>>>(
      Pb, VPt, nullptr, Xb, nullptr, N, D, N);

  // out = X @ wo^T + b  (BK=128 swizzled, full K=1024 -> fp32 d_out + bias)
  gemm_f16e<1><<<gd, blk, 0, stream>>>(
      Xb, wo16, wo_b, nullptr, x_out, N, D, D);
}

// Round 14
// 219.376 us; speedup vs baseline: 1.2980x; 1.0753x over previous
//
#include <hip/hip_runtime.h>
#include <cstdint>

// Problem constants (fixed by the reference)
#define N_SEQ 4096
#define DMODEL 1024

#define BM 128
#define BN 128
#define BN2 64
#define UNITE 4096   // one 64x64 f16 unit (8 KiB)

typedef __bf16 bf16_t;
typedef _Float16 f16_t;
typedef f16_t f16x8 __attribute__((ext_vector_type(8)));
typedef f16_t f16x4 __attribute__((ext_vector_type(4)));
typedef float f32x4 __attribute__((ext_vector_type(4)));

typedef __attribute__((address_space(1))) void* as1ptr;
typedef __attribute__((address_space(3))) void* as3ptr;

__device__ __forceinline__ void gload16(const void* g, void* l) {
  __builtin_amdgcn_global_load_lds((as1ptr)(uintptr_t)g, (as3ptr)(uintptr_t)l,
                                   16, 0, 0);
}

#define SBAR() asm volatile("s_barrier" ::: "memory")
#define WAITLGKM(n)                                              \
  do {                                                           \
    asm volatile("s_waitcnt lgkmcnt(" #n ")" ::: "memory");      \
    __builtin_amdgcn_sched_barrier(0);                           \
  } while (0)
#define WAITVM(n) asm volatile("s_waitcnt vmcnt(" #n ")" ::: "memory")

// ================= fused QKV projection (z = 0:Q, 1:K, 2:V) =================
// All-fp16, BK=64 swizzled units.  LDS 48 KiB -> 3 blocks/CU.
// slots: 0,1 = A0 (row-units); 2,3 = A1; 4,5 = B
// XCD swizzle on the (x,y) plane (256 blocks per z, 256%8==0 -> bijective).
__global__ __launch_bounds__(256)
void qkv_proj(const f16_t* __restrict__ qh, const f16_t* __restrict__ ql,
              const f16_t* __restrict__ wq, const float* __restrict__ wq_b,
              const f16_t* __restrict__ kh, const f16_t* __restrict__ kl,
              const f16_t* __restrict__ wk, const float* __restrict__ wk_b,
              const f16_t* __restrict__ vh, const f16_t* __restrict__ wv,
              const float* __restrict__ wv_b,
              f16_t* __restrict__ QPh, f16_t* __restrict__ QPl,
              f16_t* __restrict__ KPh, f16_t* __restrict__ VPt)
{
  __shared__ __align__(16) f16_t lds[6 * UNITE];   // 48 KiB

  const int z = blockIdx.z;
  const f16_t *A0, *A1 = nullptr, *B0;
  const float* bias;
  if (z == 0)      { A0 = qh; A1 = ql; B0 = wq; bias = wq_b; }
  else if (z == 1) { A0 = kh; A1 = kl; B0 = wk; bias = wk_b; }
  else             { A0 = vh;          B0 = wv; bias = wv_b; }
  const bool twop = (z < 2);

  const int M = N_SEQ, Nc = DMODEL, K = DMODEL;
  const int t = threadIdx.x;
  const int lane = t & 63;
  const int wave = t >> 6;
  const int wm = wave >> 1;     // 0..1 (row half of 128)
  const int wn = wave & 1;      // 0..1 (col half of 128)

  // XCD-aware swizzle within the 8x32 (x,y) plane
  const int gx = gridDim.x;                       // 8
  const int nwg = gx * gridDim.y;                 // 256
  const int flat = blockIdx.y * gx + blockIdx.x;
  const int swz = (flat & 7) * (nwg >> 3) + (flat >> 3);
  const int row0 = (swz / gx) * BM;
  const int col0 = (swz % gx) * BN;

  const int srw = t >> 3;                                // 0..31
  const int scol = 8 * ((t & 7) ^ ((t >> 3) & 7));       // pre-swizzled src
  const int sdst = t * 8;

  const int fr = lane & 15;
  const int kq = (lane >> 4) * 8;
  const int sw = (fr & 7) << 3;                          // read-side swizzle

  f32x4 acc[4][4] = {};

  for (int k0 = 0; k0 < K; k0 += 64) {
#pragma unroll
    for (int h = 0; h < 2; ++h) {
      const int r = h * 32 + srw;
      gload16(A0 + (size_t)(row0 + r) * K + k0 + scol,
              &lds[0 * UNITE + h * 2048 + sdst]);
      gload16(A0 + (size_t)(row0 + 64 + r) * K + k0 + scol,
              &lds[1 * UNITE + h * 2048 + sdst]);
      gload16(B0 + (size_t)(col0 + r) * K + k0 + scol,
              &lds[4 * UNITE + h * 2048 + sdst]);
      gload16(B0 + (size_t)(col0 + 64 + r) * K + k0 + scol,
              &lds[5 * UNITE + h * 2048 + sdst]);
      if (twop) {
        gload16(A1 + (size_t)(row0 + r) * K + k0 + scol,
                &lds[2 * UNITE + h * 2048 + sdst]);
        gload16(A1 + (size_t)(row0 + 64 + r) * K + k0 + scol,
                &lds[3 * UNITE + h * 2048 + sdst]);
      }
    }
    __syncthreads();

    f16x8 ah[4][2], al[4][2], bh[4][2];
#pragma unroll
    for (int m = 0; m < 4; ++m) {
      const int r = (m * 16 + fr) * 64;
#pragma unroll
      for (int ks = 0; ks < 2; ++ks) {
        const int c = (ks * 32 + kq) ^ sw;
        ah[m][ks] = *(const f16x8*)&lds[wm * UNITE + r + c];
        if (twop) al[m][ks] = *(const f16x8*)&lds[(2 + wm) * UNITE + r + c];
      }
    }
#pragma unroll
    for (int n = 0; n < 4; ++n) {
      const int r = (n * 16 + fr) * 64;
#pragma unroll
      for (int ks = 0; ks < 2; ++ks)
        bh[n][ks] = *(const f16x8*)&lds[(4 + wn) * UNITE + r +
                                        (((ks * 32 + kq)) ^ sw)];
    }

#pragma unroll
    for (int m = 0; m < 4; ++m)
#pragma unroll
      for (int n = 0; n < 4; ++n)
#pragma unroll
        for (int ks = 0; ks < 2; ++ks) {
          acc[m][n] = __builtin_amdgcn_mfma_f32_16x16x32_f16(
              ah[m][ks], bh[n][ks], acc[m][n], 0, 0, 0);
          if (twop)
            acc[m][n] = __builtin_amdgcn_mfma_f32_16x16x32_f16(
                al[m][ks], bh[n][ks], acc[m][n], 0, 0, 0);
        }
    __syncthreads();
  }

#pragma unroll
  for (int m = 0; m < 4; ++m) {
#pragma unroll
    for (int n = 0; n < 4; ++n) {
      const int grow0 = row0 + wm * 64 + m * 16 + (lane >> 4) * 4;
      const int gcol = col0 + wn * 64 + n * 16 + (lane & 15);
      const float bv = bias[gcol];
      if (z == 2) {
        f16x4 p;
#pragma unroll
        for (int r = 0; r < 4; ++r) p[r] = (f16_t)(acc[m][n][r] + bv);
        *(f16x4*)&VPt[(size_t)gcol * M + grow0] = p;
      } else if (z == 0) {
#pragma unroll
        for (int r = 0; r < 4; ++r) {
          const float val = acc[m][n][r] + bv;
          const size_t idx = (size_t)(grow0 + r) * Nc + gcol;
          const f16_t h = (f16_t)val;
          QPh[idx] = h;
          QPl[idx] = (f16_t)(val - (float)h);
        }
      } else {
#pragma unroll
        for (int r = 0; r < 4; ++r) {
          const float val = acc[m][n][r] + bv;
          KPh[(size_t)(grow0 + r) * Nc + gcol] = (f16_t)val;
        }
      }
    }
  }
}

// ====== pipelined fp16 GEMM, 128x64 tile, BK=64 double-buffered ======
// OUT_F32=0: C = A@B^T        -> f16 Cf16
// OUT_F32=1: C = A@B^T + bias -> f32 Cf32
// LDS 48 KiB: 2 bufs x {A0, A1, B} swizzled 64x64 units.
// Stage 2 tiles ahead; counted vmcnt(6)/lgkmcnt(4); 2 light s_barriers/tile
// (no vmcnt(0)/lgkmcnt(0) drains in the main loop).
template <int OUT_F32>
__global__ __launch_bounds__(256)
void gemm_f16p(const f16_t* __restrict__ A, const f16_t* __restrict__ B,
               const float* __restrict__ bias,
               f16_t* __restrict__ Cf16, float* __restrict__ Cf32,
               int M, int Nc, int K)
{
  __shared__ __align__(16) f16_t lds[2 * 3 * UNITE];   // 48 KiB

  const int gx = gridDim.x;
  const int nwg = gx * gridDim.y;
  const int flat = blockIdx.y * gx + blockIdx.x;
  const int swz = (flat & 7) * (nwg >> 3) + (flat >> 3);
  const int bx = swz % gx;
  const int by = swz / gx;

  const int t = threadIdx.x;
  const int lane = t & 63;
  const int wave = t >> 6;
  const int wm = wave >> 1;     // 0..1 (64-row half)
  const int wn = wave & 1;      // 0..1 (32-col half)
  const int row0 = by * BM;
  const int col0 = bx * BN2;

  const int srw = t >> 3;                                // 0..31
  const int scol = 8 * ((t & 7) ^ ((t >> 3) & 7));       // pre-swizzled src
  const int sdst = t * 8;

  const int fr = lane & 15;
  const int kq = (lane >> 4) * 8;
  const int sw = (fr & 7) << 3;                          // read-side swizzle

  auto stage = [&](int buf, int kt) {
    const int k0 = kt << 6;
#pragma unroll
    for (int h = 0; h < 2; ++h) {
      const int r = h * 32 + srw;
      gload16(A + (size_t)(row0 + r) * K + k0 + scol,
              &lds[(buf * 3 + 0) * UNITE + h * 2048 + sdst]);
      gload16(A + (size_t)(row0 + 64 + r) * K + k0 + scol,
              &lds[(buf * 3 + 1) * UNITE + h * 2048 + sdst]);
      gload16(B + (size_t)(col0 + r) * K + k0 + scol,
              &lds[(buf * 3 + 2) * UNITE + h * 2048 + sdst]);
    }
  };

  f32x4 acc[4][2] = {};
  const int NT = K >> 6;

  // prologue: tiles 0 and 1 staged; wait for tile 0 (own 6 newest in flight)
  stage(0, 0);
  stage(1, 1);
  WAITVM(6);
  SBAR();

  for (int kt = 0; kt < NT; ++kt) {
    const int p = kt & 1;
    const f16_t* Ab = &lds[(p * 3 + wm) * UNITE];
    const f16_t* Bb = &lds[(p * 3 + 2) * UNITE];

    f16x8 ah[4][2], bh[2][2];
    // set-1 reads: A m0,m1 (4) + B all (4)
#pragma unroll
    for (int m = 0; m < 2; ++m)
#pragma unroll
      for (int ks = 0; ks < 2; ++ks)
        ah[m][ks] = *(const f16x8*)&Ab[(m * 16 + fr) * 64 +
                                       ((ks * 32 + kq) ^ sw)];
#pragma unroll
    for (int n = 0; n < 2; ++n)
#pragma unroll
      for (int ks = 0; ks < 2; ++ks)
        bh[n][ks] = *(const f16x8*)&Bb[(wn * 32 + n * 16 + fr) * 64 +
                                       ((ks * 32 + kq) ^ sw)];
    // set-2 reads: A m2,m3 (4), pipelined behind set-1 MFMA
#pragma unroll
    for (int m = 2; m < 4; ++m)
#pragma unroll
      for (int ks = 0; ks < 2; ++ks)
        ah[m][ks] = *(const f16x8*)&Ab[(m * 16 + fr) * 64 +
                                       ((ks * 32 + kq) ^ sw)];

    WAITLGKM(4);                 // set-1 (8 oldest) drained
#pragma unroll
    for (int m = 0; m < 2; ++m)
#pragma unroll
      for (int n = 0; n < 2; ++n)
#pragma unroll
        for (int ks = 0; ks < 2; ++ks)
          acc[m][n] = __builtin_amdgcn_mfma_f32_16x16x32_f16(
              ah[m][ks], bh[n][ks], acc[m][n], 0, 0, 0);
    WAITLGKM(0);                 // set-2 drained
#pragma unroll
    for (int m = 2; m < 4; ++m)
#pragma unroll
      for (int n = 0; n < 2; ++n)
#pragma unroll
        for (int ks = 0; ks < 2; ++ks)
          acc[m][n] = __builtin_amdgcn_mfma_f32_16x16x32_f16(
              ah[m][ks], bh[n][ks], acc[m][n], 0, 0, 0);

    SBAR();                      // all waves done reading buf p
    if (kt + 2 < NT) {
      stage(p, kt + 2);          // overwrite p (safe: reads done block-wide)
      WAITVM(6);                 // own tile-(kt+1) stages landed
    } else if (kt + 1 < NT) {
      WAITVM(0);                 // final drain before last tile
    }
    SBAR();                      // all waves' tile-(kt+1) stages landed
  }

#pragma unroll
  for (int m = 0; m < 4; ++m) {
#pragma unroll
    for (int n = 0; n < 2; ++n) {
      const int grow0 = row0 + wm * 64 + m * 16 + (lane >> 4) * 4;
      const int gcol = col0 + wn * 32 + n * 16 + (lane & 15);
#pragma unroll
      for (int r = 0; r < 4; ++r) {
        const size_t idx = (size_t)(grow0 + r) * Nc + gcol;
        if (OUT_F32) Cf32[idx] = acc[m][n][r] + bias[gcol];
        else         Cf16[idx] = (f16_t)acc[m][n][r];
      }
    }
  }
}

// ============ fp16 2-pass 256x256 scores GEMM (R4 structure) ============
#define TILE_ELEMS 16384   // 256 rows x 64 cols
#define UNIT_ELEMS 4096    // 64 rows x 64 cols
#define NT_SC 32

template <int V> struct ic { static constexpr int value = V; };

template <int MH>
__device__ __forceinline__ void load_A8f(const f16_t* Ab, int wm, int fr,
                                         int kq, int sw, f16x8 (&af)[4][2]) {
#pragma unroll
  for (int m = 0; m < 4; ++m) {
    const int row = wm * 128 + (MH * 4 + m) * 16 + fr;
#pragma unroll
    for (int ks = 0; ks < 2; ++ks)
      af[m][ks] = *(const f16x8*)&Ab[row * 64 + ((ks * 32 + kq) ^ sw)];
  }
}

template <int NH>
__device__ __forceinline__ void load_B4f(const f16_t* Bb, int wn, int fr,
                                         int kq, int sw, f16x8 (&bfr)[2][2]) {
#pragma unroll
  for (int n = 0; n < 2; ++n) {
    const int row = wn * 64 + (NH * 2 + n) * 16 + fr;
#pragma unroll
    for (int ks = 0; ks < 2; ++ks)
      bfr[n][ks] = *(const f16x8*)&Bb[row * 64 + ((ks * 32 + kq) ^ sw)];
  }
}

template <int MH, int NH>
__device__ __forceinline__ void mfma16f(const f16x8 (&af)[4][2],
                                        const f16x8 (&bfr)[2][2],
                                        f32x4 (&acc)[8][4]) {
#pragma unroll
  for (int m = 0; m < 4; ++m)
#pragma unroll
    for (int n = 0; n < 2; ++n)
#pragma unroll
      for (int ks = 0; ks < 2; ++ks)
        acc[MH * 4 + m][NH * 2 + n] = __builtin_amdgcn_mfma_f32_16x16x32_f16(
            af[m][ks], bfr[n][ks], acc[MH * 4 + m][NH * 2 + n], 0, 0, 0);
}

__global__ __launch_bounds__(512, 1)
void gemm8f_scores(const f16_t* __restrict__ Qh, const f16_t* __restrict__ Ql,
                   const f16_t* __restrict__ Kh, float* __restrict__ C)
{
  __shared__ __align__(16) f16_t sm[2 * 2 * TILE_ELEMS];  // 128 KiB

  const int t = threadIdx.x;
  const int lane = t & 63;
  const int wave = t >> 6;
  const int wm = wave >> 2;      // 0..1
  const int wn = wave & 3;       // 0..3

  // XCD-aware block swizzle: grid 16x16 = 256 blocks, 256 = 8*32 (bijective)
  const int flat = blockIdx.y * 16 + blockIdx.x;
  const int swzb = (flat & 7) * 32 + (flat >> 3);
  const int brow = (swzb >> 4) * 256;
  const int bcol = (swzb & 15) * 256;

  const int srow = t >> 3;                               // 0..63
  const int scol = 8 * ((t & 7) ^ ((t >> 3) & 7));       // involution
  const int sdst = t * 8;

  const int fr = lane & 15;
  const int kq = (lane >> 4) * 8;
  const int sw = (fr & 7) << 3;                          // read-side swizzle

  auto stageA = [&](int buf, int u, int kt) {
    const f16_t* src = (kt >= 16) ? Ql : Qh;
    const int kk = (kt & 15) << 6;
    gload16(src + (size_t)(brow + u * 64 + srow) * DMODEL + kk + scol,
            &sm[(buf * 2 + 0) * TILE_ELEMS + u * UNIT_ELEMS + sdst]);
  };
  auto stageB = [&](int buf, int u, int kt) {
    const int kk = (kt & 15) << 6;
    gload16(Kh + (size_t)(bcol + u * 64 + srow) * DMODEL + kk + scol,
            &sm[(buf * 2 + 1) * TILE_ELEMS + u * UNIT_ELEMS + sdst]);
  };

  f32x4 acc[8][4] = {};
  f16x8 af0[4][2], af1[4][2];
  f16x8 b0[2][2], b1[2][2];

  // ---- prologue: tile0 all 8 units; tile1's Ua, V01, Ub (6 loads).
#pragma unroll
  for (int u = 0; u < 4; ++u) stageA(0, u, 0);
#pragma unroll
  for (int u = 0; u < 4; ++u) stageB(0, u, 0);
  stageA(1, 0, 1); stageA(1, 2, 1);   // Ua(1)
  stageB(1, 0, 1); stageB(1, 1, 1);   // V01(1)
  stageA(1, 1, 1); stageA(1, 3, 1);   // Ub(1)
  WAITVM(6);  // tile0's 8 landed
  SBAR();

  auto tile = [&](auto Pc, int kt) {
    constexpr int p = decltype(Pc)::value;
    constexpr int q = p ^ 1;
    const bool n1 = (kt + 1 < NT_SC);
    const bool n2 = (kt + 2 < NT_SC);
    const f16_t* Ab = &sm[(p * 2 + 0) * TILE_ELEMS];
    const f16_t* Bb = &sm[(p * 2 + 1) * TILE_ELEMS];

    // ---- Phase 1
    load_A8f<0>(Ab, wm, fr, kq, sw, af0);
    load_B4f<0>(Bb, wn, fr, kq, sw, b0);
    if (n1) { stageB(q, 2, kt + 1); stageB(q, 3, kt + 1); }
    load_B4f<1>(Bb, wn, fr, kq, sw, b1);
    WAITLGKM(4);
    __builtin_amdgcn_s_setprio(1);
    mfma16f<0, 0>(af0, b0, acc);
    __builtin_amdgcn_s_setprio(0);
    __builtin_amdgcn_sched_barrier(0);
    SBAR();

    // ---- Phase 2
    if (n2) { stageA(p, 0, kt + 2); stageA(p, 2, kt + 2); }
    load_A8f<1>(Ab, wm, fr, kq, sw, af1);
    WAITLGKM(8);
    __builtin_amdgcn_s_setprio(1);
    mfma16f<0, 1>(af0, b1, acc);
    __builtin_amdgcn_s_setprio(0);
    __builtin_amdgcn_sched_barrier(0);
    SBAR();

    // ---- Phase 3
    if (n2) { stageB(p, 0, kt + 2); stageB(p, 1, kt + 2); }
    WAITLGKM(0);
    __builtin_amdgcn_s_setprio(1);
    mfma16f<1, 0>(af1, b0, acc);
    __builtin_amdgcn_s_setprio(0);
    __builtin_amdgcn_sched_barrier(0);
    SBAR();

    // ---- Phase 4
    if (n2) { stageA(p, 1, kt + 2); stageA(p, 3, kt + 2); }
    __builtin_amdgcn_s_setprio(1);
    mfma16f<1, 1>(af1, b1, acc);
    __builtin_amdgcn_s_setprio(0);
    __builtin_amdgcn_sched_barrier(0);
    if (n2)      WAITVM(6);
    else if (n1) WAITVM(0);
    SBAR();
  };

  for (int kt = 0; kt < NT_SC; kt += 2) {
    tile(ic<0>{}, kt);
    tile(ic<1>{}, kt + 1);
  }

  // ---- epilogue
#pragma unroll
  for (int mf = 0; mf < 8; ++mf) {
#pragma unroll
    for (int nf = 0; nf < 4; ++nf) {
      const int r0 = brow + wm * 128 + mf * 16 + (lane >> 4) * 4;
      const int c  = bcol + wn * 64 + nf * 16 + (lane & 15);
#pragma unroll
      for (int r = 0; r < 4; ++r)
        C[(size_t)(r0 + r) * N_SEQ + c] = acc[mf][nf][r];
    }
  }
}

// ======================= fused split (all fp16) =======================
struct SplitDesc {
  const float* src[7];
  f16_t* hi[7];
  f16_t* lo[7];
  int mode[7];
  int blk_start[8];
};

__global__ __launch_bounds__(256)
void split_all(SplitDesc d)
{
  const int b = blockIdx.x;
  int seg = 0;
#pragma unroll
  for (int s = 1; s < 7; ++s) seg += (b >= d.blk_start[s]) ? 1 : 0;
  const int i = (b - d.blk_start[seg]) * 256 + threadIdx.x;
  const float4 v = ((const float4*)d.src[seg])[i];
  const float vv[4] = {v.x, v.y, v.z, v.w};
  f16x4 h, l;
#pragma unroll
  for (int j = 0; j < 4; ++j) {
    const f16_t hh = (f16_t)vv[j];
    h[j] = hh;
    l[j] = (f16_t)(vv[j] - (float)hh);
  }
  ((f16x4*)d.hi[seg])[i] = h;
  if (d.mode[seg] == 2) ((f16x4*)d.lo[seg])[i] = l;
}

// ======================= softmax =======================
__global__ __launch_bounds__(256)
void softmax_rows(float* __restrict__ S, f16_t* __restrict__ P, int n)
{
  const int row = blockIdx.x;
  float* srow = S + (size_t)row * n;
  f16_t* prow = P + (size_t)row * n;
  const int t = threadIdx.x;
  const int lane = t & 63;
  const int wave = t >> 6;
  __shared__ float red[8];

  float4 v[4];
  float mx = -3.4e38f;
#pragma unroll
  for (int i = 0; i < 4; ++i) {
    v[i] = *(const float4*)(srow + (size_t)(i * 256 + t) * 4);
    mx = fmaxf(mx, fmaxf(fmaxf(v[i].x, v[i].y), fmaxf(v[i].z, v[i].w)));
  }
#pragma unroll
  for (int off = 32; off > 0; off >>= 1) mx = fmaxf(mx, __shfl_xor(mx, off));
  if (lane == 0) red[wave] = mx;
  __syncthreads();
  mx = fmaxf(fmaxf(red[0], red[1]), fmaxf(red[2], red[3]));

  float e[16];
  float sum = 0.f;
#pragma unroll
  for (int i = 0; i < 4; ++i) {
    e[4 * i + 0] = __expf(v[i].x - mx);
    e[4 * i + 1] = __expf(v[i].y - mx);
    e[4 * i + 2] = __expf(v[i].z - mx);
    e[4 * i + 3] = __expf(v[i].w - mx);
    sum += e[4 * i + 0] + e[4 * i + 1] + e[4 * i + 2] + e[4 * i + 3];
  }
#pragma unroll
  for (int off = 32; off > 0; off >>= 1) sum += __shfl_xor(sum, off);
  if (lane == 0) red[4 + wave] = sum;
  __syncthreads();
  sum = red[4] + red[5] + red[6] + red[7];
  const float inv = 1.0f / sum;

#pragma unroll
  for (int i = 0; i < 4; ++i) {
    float4 w;
    w.x = e[4 * i + 0] * inv;
    w.y = e[4 * i + 1] * inv;
    w.z = e[4 * i + 2] * inv;
    w.w = e[4 * i + 3] * inv;
    *(float4*)(srow + (size_t)(i * 256 + t) * 4) = w;
    f16x4 p;
    p[0] = (f16_t)w.x;
    p[1] = (f16_t)w.y;
    p[2] = (f16_t)w.z;
    p[3] = (f16_t)w.w;
    *(f16x4*)(prow + (size_t)(i * 256 + t) * 4) = p;
  }
}

extern "C" void kernel_launch(void* const* d_in, const int* in_sizes, int n_in,
                              void* d_out, int out_size, void* d_ws, size_t ws_size,
                              hipStream_t stream) {
  const int N = N_SEQ, D = DMODEL;
  const float* q    = (const float*)d_in[0];
  const float* k    = (const float*)d_in[1];
  const float* v    = (const float*)d_in[2];
  const float* wq_w = (const float*)d_in[3];
  const float* wq_b = (const float*)d_in[4];
  const float* wk_w = (const float*)d_in[5];
  const float* wk_b = (const float*)d_in[6];
  const float* wv_w = (const float*)d_in[7];
  const float* wv_b = (const float*)d_in[8];
  const float* wo_w = (const float*)d_in[9];
  const float* wo_b = (const float*)d_in[10];

  float* x_out = (float*)d_out;                 // [N, D]
  float* attn  = x_out + (size_t)N * D;         // [N, N]

  char* wsp = (char*)d_ws;
  auto alloc = [&](size_t bytes) { char* p = wsp; wsp += bytes; return p; };
  const size_t ND = (size_t)N * D, DD = (size_t)D * D;
  f16_t*  qh16  = (f16_t*)alloc(ND * 2);
  f16_t*  ql16  = (f16_t*)alloc(ND * 2);
  f16_t*  kh16  = (f16_t*)alloc(ND * 2);
  f16_t*  kl16  = (f16_t*)alloc(ND * 2);
  f16_t*  vh16  = (f16_t*)alloc(ND * 2);
  f16_t*  wq16  = (f16_t*)alloc(DD * 2);
  f16_t*  wk16  = (f16_t*)alloc(DD * 2);
  f16_t*  wv16  = (f16_t*)alloc(DD * 2);
  f16_t*  wo16  = (f16_t*)alloc(DD * 2);
  f16_t*  QPh   = (f16_t*)alloc(ND * 2);        // fp16 qp hi
  f16_t*  QPl   = (f16_t*)alloc(ND * 2);        // fp16 qp lo
  f16_t*  KPh   = (f16_t*)alloc(ND * 2);        // fp16 kp
  f16_t*  spare = (f16_t*)alloc(ND * 2);        // pad (keeps Pb region 32MB)
  f16_t*  VPt   = (f16_t*)alloc(ND * 2);        // [D][N] transposed fp16
  // aliases (producers run strictly after last readers of the underlying bufs)
  f16_t*  Pb    = QPh;          // 32 MB over QPh..spare (dead after scores)
  f16_t*  Xb    = vh16;         // 8 MB over vh16 (dead after qkv_proj)
  (void)spare;

  // fused split: q,k -> fp16 hi+lo; v -> fp16; all weights -> fp16
  SplitDesc sd;
  sd.src[0] = q;    sd.hi[0] = qh16;  sd.lo[0] = ql16;    sd.mode[0] = 2;
  sd.src[1] = k;    sd.hi[1] = kh16;  sd.lo[1] = kl16;    sd.mode[1] = 2;
  sd.src[2] = v;    sd.hi[2] = vh16;  sd.lo[2] = nullptr; sd.mode[2] = 3;
  sd.src[3] = wq_w; sd.hi[3] = wq16;  sd.lo[3] = nullptr; sd.mode[3] = 3;
  sd.src[4] = wk_w; sd.hi[4] = wk16;  sd.lo[4] = nullptr; sd.mode[4] = 3;
  sd.src[5] = wv_w; sd.hi[5] = wv16;  sd.lo[5] = nullptr; sd.mode[5] = 3;
  sd.src[6] = wo_w; sd.hi[6] = wo16;  sd.lo[6] = nullptr; sd.mode[6] = 3;
  const int nb_nd = (int)(ND / 4 / 256);   // 4096
  const int nb_dd = (int)(DD / 4 / 256);   // 1024
  sd.blk_start[0] = 0;
  sd.blk_start[1] = nb_nd;
  sd.blk_start[2] = 2 * nb_nd;
  sd.blk_start[3] = 3 * nb_nd;
  sd.blk_start[4] = 3 * nb_nd + nb_dd;
  sd.blk_start[5] = 3 * nb_nd + 2 * nb_dd;
  sd.blk_start[6] = 3 * nb_nd + 3 * nb_dd;
  sd.blk_start[7] = 3 * nb_nd + 4 * nb_dd;
  split_all<<<dim3(sd.blk_start[7]), dim3(256), 0, stream>>>(sd);

  const dim3 blk(256);
  const dim3 gsc(N / 256, N / 256);    // (16, 16)
  const dim3 gd(D / BN2, N / BM);      // (16, 32) = 512 blocks

  // fused Q/K/V projections: grid (8,32,3) -> 3 blocks/CU, all-fp16, BK=64
  qkv_proj<<<dim3(D / BN, N / BM, 3), blk, 0, stream>>>(
      qh16, ql16, wq16, wq_b,
      kh16, kl16, wk16, wk_b,
      vh16, wv16, wv_b,
      QPh, QPl, KPh, VPt);

  // scores = (Qh+Ql) @ Kh^T  (fp16 2-pass, logical K=2048)
  gemm8f_scores<<<gsc, dim3(512), 0, stream>>>(QPh, QPl, KPh, attn);

  // softmax rows in-place + fp16 copy (Pb aliases QP/KP region: dead now)
  softmax_rows<<<dim3(N), blk, 0, stream>>>(attn, Pb, N);

  // X = P @ VP  (pipelined dbuf BK=64, full K=4096 -> fp16 Xb)
  gemm_f16p<0><<<gd, blk, 0, stream>>>(
      Pb, VPt, nullptr, Xb, nullptr, N, D, N);

  // out = X @ wo^T + b  (pipelined dbuf BK=64, K=1024 -> fp32 d_out + bias)
  gemm_f16p<1><<<gd, blk, 0, stream>>>(
      Xb, wo16, wo_b, nullptr, x_out, N, D, D);
}

// Round 15
// 218.628 us; speedup vs baseline: 1.3024x; 1.0034x over previous
//
#include <hip/hip_runtime.h>
#include <cstdint>

// Problem constants (fixed by the reference)
#define N_SEQ 4096
#define DMODEL 1024

#define BM 128
#define BN 128
#define BN2 64
#define UNITE 4096   // one 64x64 f16 unit (8 KiB)

typedef __bf16 bf16_t;
typedef _Float16 f16_t;
typedef f16_t f16x8 __attribute__((ext_vector_type(8)));
typedef f16_t f16x4 __attribute__((ext_vector_type(4)));
typedef float f32x4 __attribute__((ext_vector_type(4)));

typedef __attribute__((address_space(1))) void* as1ptr;
typedef __attribute__((address_space(3))) void* as3ptr;

__device__ __forceinline__ void gload16(const void* g, void* l) {
  __builtin_amdgcn_global_load_lds((as1ptr)(uintptr_t)g, (as3ptr)(uintptr_t)l,
                                   16, 0, 0);
}

#define SBAR() asm volatile("s_barrier" ::: "memory")
#define WAITLGKM(n)                                              \
  do {                                                           \
    asm volatile("s_waitcnt lgkmcnt(" #n ")" ::: "memory");      \
    __builtin_amdgcn_sched_barrier(0);                           \
  } while (0)
#define WAITVM(n) asm volatile("s_waitcnt vmcnt(" #n ")" ::: "memory")

// ================= fused QKV projection (z = 0:Q, 1:K, 2:V) =================
// All-fp16, BK=64 swizzled units.  LDS 64 KiB -> 2 blocks/CU.
// z=0 (Q, 2-pass):  qp = (qh+ql)@wq^T + b       -> single fp16 QPh
// z=1 (K, 3-pass):  kp = (kh+kl)@(wkh+wkl)^T + b -> single fp16 KPh
// z=2 (V, 1-pass):  vp = vh@wv^T + b            -> fp16 transposed VPt
// units: 0,1=A0 rows; 2,3=A1; 4,5=B0 cols; 6,7=B1.
__global__ __launch_bounds__(256)
void qkv_proj(const f16_t* __restrict__ qh, const f16_t* __restrict__ ql,
              const f16_t* __restrict__ wq, const float* __restrict__ wq_b,
              const f16_t* __restrict__ kh, const f16_t* __restrict__ kl,
              const f16_t* __restrict__ wkh, const f16_t* __restrict__ wkl,
              const float* __restrict__ wk_b,
              const f16_t* __restrict__ vh, const f16_t* __restrict__ wv,
              const float* __restrict__ wv_b,
              f16_t* __restrict__ QPh, f16_t* __restrict__ KPh,
              f16_t* __restrict__ VPt)
{
  __shared__ __align__(16) f16_t lds[8 * UNITE];   // 64 KiB

  const int z = blockIdx.z;
  const f16_t *A0, *A1 = nullptr, *B0, *B1 = nullptr;
  const float* bias;
  if (z == 0)      { A0 = qh; A1 = ql; B0 = wq;               bias = wq_b; }
  else if (z == 1) { A0 = kh; A1 = kl; B0 = wkh; B1 = wkl;    bias = wk_b; }
  else             { A0 = vh;          B0 = wv;               bias = wv_b; }
  const bool p2 = (z < 2);    // second pass: al*bh
  const bool p3 = (z == 1);   // third pass:  ah*bl

  const int M = N_SEQ, Nc = DMODEL, K = DMODEL;
  const int t = threadIdx.x;
  const int lane = t & 63;
  const int wave = t >> 6;
  const int wm = wave >> 1;     // 0..1 (row half of 128)
  const int wn = wave & 1;      // 0..1 (col half of 128)

  // XCD-aware swizzle within the 8x32 (x,y) plane (256 blocks, bijective)
  const int gx = gridDim.x;                       // 8
  const int nwg = gx * gridDim.y;                 // 256
  const int flat = blockIdx.y * gx + blockIdx.x;
  const int swz = (flat & 7) * (nwg >> 3) + (flat >> 3);
  const int row0 = (swz / gx) * BM;
  const int col0 = (swz % gx) * BN;

  const int srw = t >> 3;                                // 0..31
  const int scol = 8 * ((t & 7) ^ ((t >> 3) & 7));       // pre-swizzled src
  const int sdst = t * 8;

  const int fr = lane & 15;
  const int kq = (lane >> 4) * 8;
  const int sw = (fr & 7) << 3;                          // read-side swizzle

  f32x4 acc[4][4] = {};

  for (int k0 = 0; k0 < K; k0 += 64) {
#pragma unroll
    for (int h = 0; h < 2; ++h) {
      const int r = h * 32 + srw;
      gload16(A0 + (size_t)(row0 + r) * K + k0 + scol,
              &lds[0 * UNITE + h * 2048 + sdst]);
      gload16(A0 + (size_t)(row0 + 64 + r) * K + k0 + scol,
              &lds[1 * UNITE + h * 2048 + sdst]);
      gload16(B0 + (size_t)(col0 + r) * K + k0 + scol,
              &lds[4 * UNITE + h * 2048 + sdst]);
      gload16(B0 + (size_t)(col0 + 64 + r) * K + k0 + scol,
              &lds[5 * UNITE + h * 2048 + sdst]);
      if (p2) {
        gload16(A1 + (size_t)(row0 + r) * K + k0 + scol,
                &lds[2 * UNITE + h * 2048 + sdst]);
        gload16(A1 + (size_t)(row0 + 64 + r) * K + k0 + scol,
                &lds[3 * UNITE + h * 2048 + sdst]);
      }
      if (p3) {
        gload16(B1 + (size_t)(col0 + r) * K + k0 + scol,
                &lds[6 * UNITE + h * 2048 + sdst]);
        gload16(B1 + (size_t)(col0 + 64 + r) * K + k0 + scol,
                &lds[7 * UNITE + h * 2048 + sdst]);
      }
    }
    __syncthreads();

    f16x8 ah[4][2], al[4][2], bh[4][2], bl[4][2];
#pragma unroll
    for (int m = 0; m < 4; ++m) {
      const int r = (m * 16 + fr) * 64;
#pragma unroll
      for (int ks = 0; ks < 2; ++ks) {
        const int c = (ks * 32 + kq) ^ sw;
        ah[m][ks] = *(const f16x8*)&lds[wm * UNITE + r + c];
        if (p2) al[m][ks] = *(const f16x8*)&lds[(2 + wm) * UNITE + r + c];
      }
    }
#pragma unroll
    for (int n = 0; n < 4; ++n) {
      const int r = (n * 16 + fr) * 64;
#pragma unroll
      for (int ks = 0; ks < 2; ++ks) {
        const int c = (ks * 32 + kq) ^ sw;
        bh[n][ks] = *(const f16x8*)&lds[(4 + wn) * UNITE + r + c];
        if (p3) bl[n][ks] = *(const f16x8*)&lds[(6 + wn) * UNITE + r + c];
      }
    }

#pragma unroll
    for (int m = 0; m < 4; ++m)
#pragma unroll
      for (int n = 0; n < 4; ++n)
#pragma unroll
        for (int ks = 0; ks < 2; ++ks) {
          acc[m][n] = __builtin_amdgcn_mfma_f32_16x16x32_f16(
              ah[m][ks], bh[n][ks], acc[m][n], 0, 0, 0);
          if (p2)
            acc[m][n] = __builtin_amdgcn_mfma_f32_16x16x32_f16(
                al[m][ks], bh[n][ks], acc[m][n], 0, 0, 0);
          if (p3)
            acc[m][n] = __builtin_amdgcn_mfma_f32_16x16x32_f16(
                ah[m][ks], bl[n][ks], acc[m][n], 0, 0, 0);
        }
    __syncthreads();
  }

#pragma unroll
  for (int m = 0; m < 4; ++m) {
#pragma unroll
    for (int n = 0; n < 4; ++n) {
      const int grow0 = row0 + wm * 64 + m * 16 + (lane >> 4) * 4;
      const int gcol = col0 + wn * 64 + n * 16 + (lane & 15);
      const float bv = bias[gcol];
      if (z == 2) {
        f16x4 p;
#pragma unroll
        for (int r = 0; r < 4; ++r) p[r] = (f16_t)(acc[m][n][r] + bv);
        *(f16x4*)&VPt[(size_t)gcol * M + grow0] = p;
      } else {
        f16_t* out = (z == 0) ? QPh : KPh;
#pragma unroll
        for (int r = 0; r < 4; ++r)
          out[(size_t)(grow0 + r) * Nc + gcol] = (f16_t)(acc[m][n][r] + bv);
      }
    }
  }
}

// ====== pipelined fp16 GEMM, 128x64 tile, BK=64 double-buffered ======
template <int OUT_F32>
__global__ __launch_bounds__(256)
void gemm_f16p(const f16_t* __restrict__ A, const f16_t* __restrict__ B,
               const float* __restrict__ bias,
               f16_t* __restrict__ Cf16, float* __restrict__ Cf32,
               int M, int Nc, int K)
{
  __shared__ __align__(16) f16_t lds[2 * 3 * UNITE];   // 48 KiB

  const int gx = gridDim.x;
  const int nwg = gx * gridDim.y;
  const int flat = blockIdx.y * gx + blockIdx.x;
  const int swz = (flat & 7) * (nwg >> 3) + (flat >> 3);
  const int bx = swz % gx;
  const int by = swz / gx;

  const int t = threadIdx.x;
  const int lane = t & 63;
  const int wave = t >> 6;
  const int wm = wave >> 1;     // 0..1 (64-row half)
  const int wn = wave & 1;      // 0..1 (32-col half)
  const int row0 = by * BM;
  const int col0 = bx * BN2;

  const int srw = t >> 3;                                // 0..31
  const int scol = 8 * ((t & 7) ^ ((t >> 3) & 7));       // pre-swizzled src
  const int sdst = t * 8;

  const int fr = lane & 15;
  const int kq = (lane >> 4) * 8;
  const int sw = (fr & 7) << 3;                          // read-side swizzle

  auto stage = [&](int buf, int kt) {
    const int k0 = kt << 6;
#pragma unroll
    for (int h = 0; h < 2; ++h) {
      const int r = h * 32 + srw;
      gload16(A + (size_t)(row0 + r) * K + k0 + scol,
              &lds[(buf * 3 + 0) * UNITE + h * 2048 + sdst]);
      gload16(A + (size_t)(row0 + 64 + r) * K + k0 + scol,
              &lds[(buf * 3 + 1) * UNITE + h * 2048 + sdst]);
      gload16(B + (size_t)(col0 + r) * K + k0 + scol,
              &lds[(buf * 3 + 2) * UNITE + h * 2048 + sdst]);
    }
  };

  f32x4 acc[4][2] = {};
  const int NT = K >> 6;

  stage(0, 0);
  stage(1, 1);
  WAITVM(6);
  SBAR();

  for (int kt = 0; kt < NT; ++kt) {
    const int p = kt & 1;
    const f16_t* Ab = &lds[(p * 3 + wm) * UNITE];
    const f16_t* Bb = &lds[(p * 3 + 2) * UNITE];

    f16x8 ah[4][2], bh[2][2];
#pragma unroll
    for (int m = 0; m < 2; ++m)
#pragma unroll
      for (int ks = 0; ks < 2; ++ks)
        ah[m][ks] = *(const f16x8*)&Ab[(m * 16 + fr) * 64 +
                                       ((ks * 32 + kq) ^ sw)];
#pragma unroll
    for (int n = 0; n < 2; ++n)
#pragma unroll
      for (int ks = 0; ks < 2; ++ks)
        bh[n][ks] = *(const f16x8*)&Bb[(wn * 32 + n * 16 + fr) * 64 +
                                       ((ks * 32 + kq) ^ sw)];
#pragma unroll
    for (int m = 2; m < 4; ++m)
#pragma unroll
      for (int ks = 0; ks < 2; ++ks)
        ah[m][ks] = *(const f16x8*)&Ab[(m * 16 + fr) * 64 +
                                       ((ks * 32 + kq) ^ sw)];

    WAITLGKM(4);
#pragma unroll
    for (int m = 0; m < 2; ++m)
#pragma unroll
      for (int n = 0; n < 2; ++n)
#pragma unroll
        for (int ks = 0; ks < 2; ++ks)
          acc[m][n] = __builtin_amdgcn_mfma_f32_16x16x32_f16(
              ah[m][ks], bh[n][ks], acc[m][n], 0, 0, 0);
    WAITLGKM(0);
#pragma unroll
    for (int m = 2; m < 4; ++m)
#pragma unroll
      for (int n = 0; n < 2; ++n)
#pragma unroll
        for (int ks = 0; ks < 2; ++ks)
          acc[m][n] = __builtin_amdgcn_mfma_f32_16x16x32_f16(
              ah[m][ks], bh[n][ks], acc[m][n], 0, 0, 0);

    SBAR();
    if (kt + 2 < NT) {
      stage(p, kt + 2);
      WAITVM(6);
    } else if (kt + 1 < NT) {
      WAITVM(0);
    }
    SBAR();
  }

#pragma unroll
  for (int m = 0; m < 4; ++m) {
#pragma unroll
    for (int n = 0; n < 2; ++n) {
      const int grow0 = row0 + wm * 64 + m * 16 + (lane >> 4) * 4;
      const int gcol = col0 + wn * 32 + n * 16 + (lane & 15);
#pragma unroll
      for (int r = 0; r < 4; ++r) {
        const size_t idx = (size_t)(grow0 + r) * Nc + gcol;
        if (OUT_F32) Cf32[idx] = acc[m][n][r] + bias[gcol];
        else         Cf16[idx] = (f16_t)acc[m][n][r];
      }
    }
  }
}

// ============ single-pass fp16 256x256 scores GEMM (8-phase) ============
// scores = QPh @ KPh^T, K = 1024, NT = 16.
#define TILE_ELEMS 16384   // 256 rows x 64 cols
#define UNIT_ELEMS 4096    // 64 rows x 64 cols
#define NT_SC 16

template <int V> struct ic { static constexpr int value = V; };

template <int MH>
__device__ __forceinline__ void load_A8f(const f16_t* Ab, int wm, int fr,
                                         int kq, int sw, f16x8 (&af)[4][2]) {
#pragma unroll
  for (int m = 0; m < 4; ++m) {
    const int row = wm * 128 + (MH * 4 + m) * 16 + fr;
#pragma unroll
    for (int ks = 0; ks < 2; ++ks)
      af[m][ks] = *(const f16x8*)&Ab[row * 64 + ((ks * 32 + kq) ^ sw)];
  }
}

template <int NH>
__device__ __forceinline__ void load_B4f(const f16_t* Bb, int wn, int fr,
                                         int kq, int sw, f16x8 (&bfr)[2][2]) {
#pragma unroll
  for (int n = 0; n < 2; ++n) {
    const int row = wn * 64 + (NH * 2 + n) * 16 + fr;
#pragma unroll
    for (int ks = 0; ks < 2; ++ks)
      bfr[n][ks] = *(const f16x8*)&Bb[row * 64 + ((ks * 32 + kq) ^ sw)];
  }
}

template <int MH, int NH>
__device__ __forceinline__ void mfma16f(const f16x8 (&af)[4][2],
                                        const f16x8 (&bfr)[2][2],
                                        f32x4 (&acc)[8][4]) {
#pragma unroll
  for (int m = 0; m < 4; ++m)
#pragma unroll
    for (int n = 0; n < 2; ++n)
#pragma unroll
      for (int ks = 0; ks < 2; ++ks)
        acc[MH * 4 + m][NH * 2 + n] = __builtin_amdgcn_mfma_f32_16x16x32_f16(
            af[m][ks], bfr[n][ks], acc[MH * 4 + m][NH * 2 + n], 0, 0, 0);
}

__global__ __launch_bounds__(512, 1)
void gemm8f_scores(const f16_t* __restrict__ Qh, const f16_t* __restrict__ Kh,
                   float* __restrict__ C)
{
  __shared__ __align__(16) f16_t sm[2 * 2 * TILE_ELEMS];  // 128 KiB

  const int t = threadIdx.x;
  const int lane = t & 63;
  const int wave = t >> 6;
  const int wm = wave >> 2;      // 0..1
  const int wn = wave & 3;       // 0..3

  // XCD-aware block swizzle: grid 16x16 = 256 blocks, 256 = 8*32 (bijective)
  const int flat = blockIdx.y * 16 + blockIdx.x;
  const int swzb = (flat & 7) * 32 + (flat >> 3);
  const int brow = (swzb >> 4) * 256;
  const int bcol = (swzb & 15) * 256;

  const int srow = t >> 3;                               // 0..63
  const int scol = 8 * ((t & 7) ^ ((t >> 3) & 7));       // involution
  const int sdst = t * 8;

  const int fr = lane & 15;
  const int kq = (lane >> 4) * 8;
  const int sw = (fr & 7) << 3;                          // read-side swizzle

  auto stageA = [&](int buf, int u, int kt) {
    const int kk = kt << 6;
    gload16(Qh + (size_t)(brow + u * 64 + srow) * DMODEL + kk + scol,
            &sm[(buf * 2 + 0) * TILE_ELEMS + u * UNIT_ELEMS + sdst]);
  };
  auto stageB = [&](int buf, int u, int kt) {
    const int kk = kt << 6;
    gload16(Kh + (size_t)(bcol + u * 64 + srow) * DMODEL + kk + scol,
            &sm[(buf * 2 + 1) * TILE_ELEMS + u * UNIT_ELEMS + sdst]);
  };

  f32x4 acc[8][4] = {};
  f16x8 af0[4][2], af1[4][2];
  f16x8 b0[2][2], b1[2][2];

  // ---- prologue: tile0 all 8 units; tile1's Ua, V01, Ub (6 loads).
#pragma unroll
  for (int u = 0; u < 4; ++u) stageA(0, u, 0);
#pragma unroll
  for (int u = 0; u < 4; ++u) stageB(0, u, 0);
  stageA(1, 0, 1); stageA(1, 2, 1);   // Ua(1)
  stageB(1, 0, 1); stageB(1, 1, 1);   // V01(1)
  stageA(1, 1, 1); stageA(1, 3, 1);   // Ub(1)
  WAITVM(6);  // tile0's 8 landed
  SBAR();

  auto tile = [&](auto Pc, int kt) {
    constexpr int p = decltype(Pc)::value;
    constexpr int q = p ^ 1;
    const bool n1 = (kt + 1 < NT_SC);
    const bool n2 = (kt + 2 < NT_SC);
    const f16_t* Ab = &sm[(p * 2 + 0) * TILE_ELEMS];
    const f16_t* Bb = &sm[(p * 2 + 1) * TILE_ELEMS];

    // ---- Phase 1
    load_A8f<0>(Ab, wm, fr, kq, sw, af0);
    load_B4f<0>(Bb, wn, fr, kq, sw, b0);
    if (n1) { stageB(q, 2, kt + 1); stageB(q, 3, kt + 1); }
    load_B4f<1>(Bb, wn, fr, kq, sw, b1);
    WAITLGKM(4);
    __builtin_amdgcn_s_setprio(1);
    mfma16f<0, 0>(af0, b0, acc);
    __builtin_amdgcn_s_setprio(0);
    __builtin_amdgcn_sched_barrier(0);
    SBAR();

    // ---- Phase 2
    if (n2) { stageA(p, 0, kt + 2); stageA(p, 2, kt + 2); }
    load_A8f<1>(Ab, wm, fr, kq, sw, af1);
    WAITLGKM(8);
    __builtin_amdgcn_s_setprio(1);
    mfma16f<0, 1>(af0, b1, acc);
    __builtin_amdgcn_s_setprio(0);
    __builtin_amdgcn_sched_barrier(0);
    SBAR();

    // ---- Phase 3
    if (n2) { stageB(p, 0, kt + 2); stageB(p, 1, kt + 2); }
    WAITLGKM(0);
    __builtin_amdgcn_s_setprio(1);
    mfma16f<1, 0>(af1, b0, acc);
    __builtin_amdgcn_s_setprio(0);
    __builtin_amdgcn_sched_barrier(0);
    SBAR();

    // ---- Phase 4
    if (n2) { stageA(p, 1, kt + 2); stageA(p, 3, kt + 2); }
    __builtin_amdgcn_s_setprio(1);
    mfma16f<1, 1>(af1, b1, acc);
    __builtin_amdgcn_s_setprio(0);
    __builtin_amdgcn_sched_barrier(0);
    if (n2)      WAITVM(6);
    else if (n1) WAITVM(0);
    SBAR();
  };

  for (int kt = 0; kt < NT_SC; kt += 2) {
    tile(ic<0>{}, kt);
    tile(ic<1>{}, kt + 1);
  }

  // ---- epilogue
#pragma unroll
  for (int mf = 0; mf < 8; ++mf) {
#pragma unroll
    for (int nf = 0; nf < 4; ++nf) {
      const int r0 = brow + wm * 128 + mf * 16 + (lane >> 4) * 4;
      const int c  = bcol + wn * 64 + nf * 16 + (lane & 15);
#pragma unroll
      for (int r = 0; r < 4; ++r)
        C[(size_t)(r0 + r) * N_SEQ + c] = acc[mf][nf][r];
    }
  }
}

// ======================= fused split (all fp16) =======================
struct SplitDesc {
  const float* src[7];
  f16_t* hi[7];
  f16_t* lo[7];
  int mode[7];
  int blk_start[8];
};

__global__ __launch_bounds__(256)
void split_all(SplitDesc d)
{
  const int b = blockIdx.x;
  int seg = 0;
#pragma unroll
  for (int s = 1; s < 7; ++s) seg += (b >= d.blk_start[s]) ? 1 : 0;
  const int i = (b - d.blk_start[seg]) * 256 + threadIdx.x;
  const float4 v = ((const float4*)d.src[seg])[i];
  const float vv[4] = {v.x, v.y, v.z, v.w};
  f16x4 h, l;
#pragma unroll
  for (int j = 0; j < 4; ++j) {
    const f16_t hh = (f16_t)vv[j];
    h[j] = hh;
    l[j] = (f16_t)(vv[j] - (float)hh);
  }
  ((f16x4*)d.hi[seg])[i] = h;
  if (d.mode[seg] == 2) ((f16x4*)d.lo[seg])[i] = l;
}

// ======================= softmax =======================
__global__ __launch_bounds__(256)
void softmax_rows(float* __restrict__ S, f16_t* __restrict__ P, int n)
{
  const int row = blockIdx.x;
  float* srow = S + (size_t)row * n;
  f16_t* prow = P + (size_t)row * n;
  const int t = threadIdx.x;
  const int lane = t & 63;
  const int wave = t >> 6;
  __shared__ float red[8];

  float4 v[4];
  float mx = -3.4e38f;
#pragma unroll
  for (int i = 0; i < 4; ++i) {
    v[i] = *(const float4*)(srow + (size_t)(i * 256 + t) * 4);
    mx = fmaxf(mx, fmaxf(fmaxf(v[i].x, v[i].y), fmaxf(v[i].z, v[i].w)));
  }
#pragma unroll
  for (int off = 32; off > 0; off >>= 1) mx = fmaxf(mx, __shfl_xor(mx, off));
  if (lane == 0) red[wave] = mx;
  __syncthreads();
  mx = fmaxf(fmaxf(red[0], red[1]), fmaxf(red[2], red[3]));

  float e[16];
  float sum = 0.f;
#pragma unroll
  for (int i = 0; i < 4; ++i) {
    e[4 * i + 0] = __expf(v[i].x - mx);
    e[4 * i + 1] = __expf(v[i].y - mx);
    e[4 * i + 2] = __expf(v[i].z - mx);
    e[4 * i + 3] = __expf(v[i].w - mx);
    sum += e[4 * i + 0] + e[4 * i + 1] + e[4 * i + 2] + e[4 * i + 3];
  }
#pragma unroll
  for (int off = 32; off > 0; off >>= 1) sum += __shfl_xor(sum, off);
  if (lane == 0) red[4 + wave] = sum;
  __syncthreads();
  sum = red[4] + red[5] + red[6] + red[7];
  const float inv = 1.0f / sum;

#pragma unroll
  for (int i = 0; i < 4; ++i) {
    float4 w;
    w.x = e[4 * i + 0] * inv;
    w.y = e[4 * i + 1] * inv;
    w.z = e[4 * i + 2] * inv;
    w.w = e[4 * i + 3] * inv;
    *(float4*)(srow + (size_t)(i * 256 + t) * 4) = w;
    f16x4 p;
    p[0] = (f16_t)w.x;
    p[1] = (f16_t)w.y;
    p[2] = (f16_t)w.z;
    p[3] = (f16_t)w.w;
    *(f16x4*)(prow + (size_t)(i * 256 + t) * 4) = p;
  }
}

extern "C" void kernel_launch(void* const* d_in, const int* in_sizes, int n_in,
                              void* d_out, int out_size, void* d_ws, size_t ws_size,
                              hipStream_t stream) {
  const int N = N_SEQ, D = DMODEL;
  const float* q    = (const float*)d_in[0];
  const float* k    = (const float*)d_in[1];
  const float* v    = (const float*)d_in[2];
  const float* wq_w = (const float*)d_in[3];
  const float* wq_b = (const float*)d_in[4];
  const float* wk_w = (const float*)d_in[5];
  const float* wk_b = (const float*)d_in[6];
  const float* wv_w = (const float*)d_in[7];
  const float* wv_b = (const float*)d_in[8];
  const float* wo_w = (const float*)d_in[9];
  const float* wo_b = (const float*)d_in[10];

  float* x_out = (float*)d_out;                 // [N, D]
  float* attn  = x_out + (size_t)N * D;         // [N, N]

  char* wsp = (char*)d_ws;
  auto alloc = [&](size_t bytes) { char* p = wsp; wsp += bytes; return p; };
  const size_t ND = (size_t)N * D, DD = (size_t)D * D;
  f16_t*  qh16  = (f16_t*)alloc(ND * 2);
  f16_t*  ql16  = (f16_t*)alloc(ND * 2);
  f16_t*  kh16  = (f16_t*)alloc(ND * 2);
  f16_t*  kl16  = (f16_t*)alloc(ND * 2);
  f16_t*  vh16  = (f16_t*)alloc(ND * 2);
  f16_t*  wq16  = (f16_t*)alloc(DD * 2);
  f16_t*  wk16  = (f16_t*)alloc(DD * 2);
  f16_t*  wk16l = (f16_t*)alloc(DD * 2);
  f16_t*  wv16  = (f16_t*)alloc(DD * 2);
  f16_t*  wo16  = (f16_t*)alloc(DD * 2);
  f16_t*  QPh   = (f16_t*)alloc(ND * 2);        // fp16 qp
  f16_t*  pad1  = (f16_t*)alloc(ND * 2);        // keeps Pb region contiguous
  f16_t*  KPh   = (f16_t*)alloc(ND * 2);        // fp16 kp
  f16_t*  pad2  = (f16_t*)alloc(ND * 2);
  f16_t*  VPt   = (f16_t*)alloc(ND * 2);        // [D][N] transposed fp16
  // aliases (producers run strictly after last readers of the underlying bufs)
  f16_t*  Pb    = QPh;          // 32 MB over QPh..pad2 (dead after scores)
  f16_t*  Xb    = vh16;         // 8 MB over vh16 (dead after qkv_proj)
  (void)pad1; (void)pad2;

  // fused split: q,k -> fp16 hi+lo; wk -> hi+lo; v,wq,wv,wo -> fp16
  SplitDesc sd;
  sd.src[0] = q;    sd.hi[0] = qh16;  sd.lo[0] = ql16;    sd.mode[0] = 2;
  sd.src[1] = k;    sd.hi[1] = kh16;  sd.lo[1] = kl16;    sd.mode[1] = 2;
  sd.src[2] = v;    sd.hi[2] = vh16;  sd.lo[2] = nullptr; sd.mode[2] = 3;
  sd.src[3] = wq_w; sd.hi[3] = wq16;  sd.lo[3] = nullptr; sd.mode[3] = 3;
  sd.src[4] = wk_w; sd.hi[4] = wk16;  sd.lo[4] = wk16l;   sd.mode[4] = 2;
  sd.src[5] = wv_w; sd.hi[5] = wv16;  sd.lo[5] = nullptr; sd.mode[5] = 3;
  sd.src[6] = wo_w; sd.hi[6] = wo16;  sd.lo[6] = nullptr; sd.mode[6] = 3;
  const int nb_nd = (int)(ND / 4 / 256);   // 4096
  const int nb_dd = (int)(DD / 4 / 256);   // 1024
  sd.blk_start[0] = 0;
  sd.blk_start[1] = nb_nd;
  sd.blk_start[2] = 2 * nb_nd;
  sd.blk_start[3] = 3 * nb_nd;
  sd.blk_start[4] = 3 * nb_nd + nb_dd;
  sd.blk_start[5] = 3 * nb_nd + 2 * nb_dd;
  sd.blk_start[6] = 3 * nb_nd + 3 * nb_dd;
  sd.blk_start[7] = 3 * nb_nd + 4 * nb_dd;
  split_all<<<dim3(sd.blk_start[7]), dim3(256), 0, stream>>>(sd);

  const dim3 blk(256);
  const dim3 gsc(N / 256, N / 256);    // (16, 16)
  const dim3 gd(D / BN2, N / BM);      // (16, 32) = 512 blocks

  // fused Q/K/V projections: Q 2-pass, K 3-pass, V 1-pass
  qkv_proj<<<dim3(D / BN, N / BM, 3), blk, 0, stream>>>(
      qh16, ql16, wq16, wq_b,
      kh16, kl16, wk16, wk16l, wk_b,
      vh16, wv16, wv_b,
      QPh, KPh, VPt);

  // scores = QPh @ KPh^T  (single-pass fp16, K=1024)
  gemm8f_scores<<<gsc, dim3(512), 0, stream>>>(QPh, KPh, attn);

  // softmax rows in-place + fp16 copy (Pb aliases QP/KP region: dead now)
  softmax_rows<<<dim3(N), blk, 0, stream>>>(attn, Pb, N);

  // X = P @ VP  (pipelined dbuf BK=64, full K=4096 -> fp16 Xb)
  gemm_f16p<0><<<gd, blk, 0, stream>>>(
      Pb, VPt, nullptr, Xb, nullptr, N, D, N);

  // out = X @ wo^T + b  (pipelined dbuf BK=64, K=1024 -> fp32 d_out + bias)
  gemm_f16p<1><<<gd, blk, 0, stream>>>(
      Xb, wo16, wo_b, nullptr, x_out, N, D, D);
}

// Round 16
// 209.135 us; speedup vs baseline: 1.3616x; 1.0454x over previous
//
#include <hip/hip_runtime.h>
#include <cstdint>

// Problem constants (fixed by the reference)
#define N_SEQ 4096
#define DMODEL 1024

#define BM 128
#define BN 128
#define BN2 64
#define UNITE 4096   // one 64x64 f16 unit (8 KiB)

typedef __bf16 bf16_t;
typedef _Float16 f16_t;
typedef f16_t f16x8 __attribute__((ext_vector_type(8)));
typedef f16_t f16x4 __attribute__((ext_vector_type(4)));
typedef float f32x4 __attribute__((ext_vector_type(4)));

typedef __attribute__((address_space(1))) void* as1ptr;
typedef __attribute__((address_space(3))) void* as3ptr;

__device__ __forceinline__ void gload16(const void* g, void* l) {
  __builtin_amdgcn_global_load_lds((as1ptr)(uintptr_t)g, (as3ptr)(uintptr_t)l,
                                   16, 0, 0);
}

#define SBAR() asm volatile("s_barrier" ::: "memory")
#define WAITLGKM(n)                                              \
  do {                                                           \
    asm volatile("s_waitcnt lgkmcnt(" #n ")" ::: "memory");      \
    __builtin_amdgcn_sched_barrier(0);                           \
  } while (0)
#define WAITVM(n) asm volatile("s_waitcnt vmcnt(" #n ")" ::: "memory")

// ================= fused QKV projection (z = 0:Q, 1:K, 2:V) =================
// All-fp16, BK=64 swizzled units.  LDS 48 KiB -> 3 blocks/CU.
// z=0 (Q, 2-pass): qp = (qh+ql)@wq^T + b -> single fp16 QPh
// z=1 (K, 2-pass): kp = (kh+kl)@wk^T + b -> single fp16 KPh
// z=2 (V, 1-pass): vp = vh@wv^T + b      -> fp16 transposed VPt
// units: 0,1 = A0 row-halves; 2,3 = A1; 4,5 = B.
__global__ __launch_bounds__(256)
void qkv_proj(const f16_t* __restrict__ qh, const f16_t* __restrict__ ql,
              const f16_t* __restrict__ wq, const float* __restrict__ wq_b,
              const f16_t* __restrict__ kh, const f16_t* __restrict__ kl,
              const f16_t* __restrict__ wk, const float* __restrict__ wk_b,
              const f16_t* __restrict__ vh, const f16_t* __restrict__ wv,
              const float* __restrict__ wv_b,
              f16_t* __restrict__ QPh, f16_t* __restrict__ KPh,
              f16_t* __restrict__ VPt)
{
  __shared__ __align__(16) f16_t lds[6 * UNITE];   // 48 KiB

  const int z = blockIdx.z;
  const f16_t *A0, *A1 = nullptr, *B0;
  const float* bias;
  if (z == 0)      { A0 = qh; A1 = ql; B0 = wq; bias = wq_b; }
  else if (z == 1) { A0 = kh; A1 = kl; B0 = wk; bias = wk_b; }
  else             { A0 = vh;          B0 = wv; bias = wv_b; }
  const bool twop = (z < 2);

  const int M = N_SEQ, Nc = DMODEL, K = DMODEL;
  const int t = threadIdx.x;
  const int lane = t & 63;
  const int wave = t >> 6;
  const int wm = wave >> 1;     // 0..1 (row half of 128)
  const int wn = wave & 1;      // 0..1 (col half of 128)

  // XCD-aware swizzle within the 8x32 (x,y) plane (256 blocks, bijective)
  const int gx = gridDim.x;                       // 8
  const int nwg = gx * gridDim.y;                 // 256
  const int flat = blockIdx.y * gx + blockIdx.x;
  const int swz = (flat & 7) * (nwg >> 3) + (flat >> 3);
  const int row0 = (swz / gx) * BM;
  const int col0 = (swz % gx) * BN;

  const int srw = t >> 3;                                // 0..31
  const int scol = 8 * ((t & 7) ^ ((t >> 3) & 7));       // pre-swizzled src
  const int sdst = t * 8;

  const int fr = lane & 15;
  const int kq = (lane >> 4) * 8;
  const int sw = (fr & 7) << 3;                          // read-side swizzle

  f32x4 acc[4][4] = {};

  for (int k0 = 0; k0 < K; k0 += 64) {
#pragma unroll
    for (int h = 0; h < 2; ++h) {
      const int r = h * 32 + srw;
      gload16(A0 + (size_t)(row0 + r) * K + k0 + scol,
              &lds[0 * UNITE + h * 2048 + sdst]);
      gload16(A0 + (size_t)(row0 + 64 + r) * K + k0 + scol,
              &lds[1 * UNITE + h * 2048 + sdst]);
      gload16(B0 + (size_t)(col0 + r) * K + k0 + scol,
              &lds[4 * UNITE + h * 2048 + sdst]);
      gload16(B0 + (size_t)(col0 + 64 + r) * K + k0 + scol,
              &lds[5 * UNITE + h * 2048 + sdst]);
      if (twop) {
        gload16(A1 + (size_t)(row0 + r) * K + k0 + scol,
                &lds[2 * UNITE + h * 2048 + sdst]);
        gload16(A1 + (size_t)(row0 + 64 + r) * K + k0 + scol,
                &lds[3 * UNITE + h * 2048 + sdst]);
      }
    }
    __syncthreads();

    f16x8 ah[4][2], al[4][2], bh[4][2];
#pragma unroll
    for (int m = 0; m < 4; ++m) {
      const int r = (m * 16 + fr) * 64;
#pragma unroll
      for (int ks = 0; ks < 2; ++ks) {
        const int c = (ks * 32 + kq) ^ sw;
        ah[m][ks] = *(const f16x8*)&lds[wm * UNITE + r + c];
        if (twop) al[m][ks] = *(const f16x8*)&lds[(2 + wm) * UNITE + r + c];
      }
    }
#pragma unroll
    for (int n = 0; n < 4; ++n) {
      const int r = (n * 16 + fr) * 64;
#pragma unroll
      for (int ks = 0; ks < 2; ++ks)
        bh[n][ks] = *(const f16x8*)&lds[(4 + wn) * UNITE + r +
                                        (((ks * 32 + kq)) ^ sw)];
    }

#pragma unroll
    for (int m = 0; m < 4; ++m)
#pragma unroll
      for (int n = 0; n < 4; ++n)
#pragma unroll
        for (int ks = 0; ks < 2; ++ks) {
          acc[m][n] = __builtin_amdgcn_mfma_f32_16x16x32_f16(
              ah[m][ks], bh[n][ks], acc[m][n], 0, 0, 0);
          if (twop)
            acc[m][n] = __builtin_amdgcn_mfma_f32_16x16x32_f16(
                al[m][ks], bh[n][ks], acc[m][n], 0, 0, 0);
        }
    __syncthreads();
  }

#pragma unroll
  for (int m = 0; m < 4; ++m) {
#pragma unroll
    for (int n = 0; n < 4; ++n) {
      const int grow0 = row0 + wm * 64 + m * 16 + (lane >> 4) * 4;
      const int gcol = col0 + wn * 64 + n * 16 + (lane & 15);
      const float bv = bias[gcol];
      if (z == 2) {
        f16x4 p;
#pragma unroll
        for (int r = 0; r < 4; ++r) p[r] = (f16_t)(acc[m][n][r] + bv);
        *(f16x4*)&VPt[(size_t)gcol * M + grow0] = p;
      } else {
        f16_t* out = (z == 0) ? QPh : KPh;
#pragma unroll
        for (int r = 0; r < 4; ++r)
          out[(size_t)(grow0 + r) * Nc + gcol] = (f16_t)(acc[m][n][r] + bv);
      }
    }
  }
}

// ====== pipelined fp16 GEMM, 128x64 tile, BK=64 double-buffered ======
template <int OUT_F32>
__global__ __launch_bounds__(256)
void gemm_f16p(const f16_t* __restrict__ A, const f16_t* __restrict__ B,
               const float* __restrict__ bias,
               f16_t* __restrict__ Cf16, float* __restrict__ Cf32,
               int M, int Nc, int K)
{
  __shared__ __align__(16) f16_t lds[2 * 3 * UNITE];   // 48 KiB

  const int gx = gridDim.x;
  const int nwg = gx * gridDim.y;
  const int flat = blockIdx.y * gx + blockIdx.x;
  const int swz = (flat & 7) * (nwg >> 3) + (flat >> 3);
  const int bx = swz % gx;
  const int by = swz / gx;

  const int t = threadIdx.x;
  const int lane = t & 63;
  const int wave = t >> 6;
  const int wm = wave >> 1;     // 0..1 (64-row half)
  const int wn = wave & 1;      // 0..1 (32-col half)
  const int row0 = by * BM;
  const int col0 = bx * BN2;

  const int srw = t >> 3;                                // 0..31
  const int scol = 8 * ((t & 7) ^ ((t >> 3) & 7));       // pre-swizzled src
  const int sdst = t * 8;

  const int fr = lane & 15;
  const int kq = (lane >> 4) * 8;
  const int sw = (fr & 7) << 3;                          // read-side swizzle

  auto stage = [&](int buf, int kt) {
    const int k0 = kt << 6;
#pragma unroll
    for (int h = 0; h < 2; ++h) {
      const int r = h * 32 + srw;
      gload16(A + (size_t)(row0 + r) * K + k0 + scol,
              &lds[(buf * 3 + 0) * UNITE + h * 2048 + sdst]);
      gload16(A + (size_t)(row0 + 64 + r) * K + k0 + scol,
              &lds[(buf * 3 + 1) * UNITE + h * 2048 + sdst]);
      gload16(B + (size_t)(col0 + r) * K + k0 + scol,
              &lds[(buf * 3 + 2) * UNITE + h * 2048 + sdst]);
    }
  };

  f32x4 acc[4][2] = {};
  const int NT = K >> 6;

  stage(0, 0);
  stage(1, 1);
  WAITVM(6);
  SBAR();

  for (int kt = 0; kt < NT; ++kt) {
    const int p = kt & 1;
    const f16_t* Ab = &lds[(p * 3 + wm) * UNITE];
    const f16_t* Bb = &lds[(p * 3 + 2) * UNITE];

    f16x8 ah[4][2], bh[2][2];
#pragma unroll
    for (int m = 0; m < 2; ++m)
#pragma unroll
      for (int ks = 0; ks < 2; ++ks)
        ah[m][ks] = *(const f16x8*)&Ab[(m * 16 + fr) * 64 +
                                       ((ks * 32 + kq) ^ sw)];
#pragma unroll
    for (int n = 0; n < 2; ++n)
#pragma unroll
      for (int ks = 0; ks < 2; ++ks)
        bh[n][ks] = *(const f16x8*)&Bb[(wn * 32 + n * 16 + fr) * 64 +
                                       ((ks * 32 + kq) ^ sw)];
#pragma unroll
    for (int m = 2; m < 4; ++m)
#pragma unroll
      for (int ks = 0; ks < 2; ++ks)
        ah[m][ks] = *(const f16x8*)&Ab[(m * 16 + fr) * 64 +
                                       ((ks * 32 + kq) ^ sw)];

    WAITLGKM(4);
#pragma unroll
    for (int m = 0; m < 2; ++m)
#pragma unroll
      for (int n = 0; n < 2; ++n)
#pragma unroll
        for (int ks = 0; ks < 2; ++ks)
          acc[m][n] = __builtin_amdgcn_mfma_f32_16x16x32_f16(
              ah[m][ks], bh[n][ks], acc[m][n], 0, 0, 0);
    WAITLGKM(0);
#pragma unroll
    for (int m = 2; m < 4; ++m)
#pragma unroll
      for (int n = 0; n < 2; ++n)
#pragma unroll
        for (int ks = 0; ks < 2; ++ks)
          acc[m][n] = __builtin_amdgcn_mfma_f32_16x16x32_f16(
              ah[m][ks], bh[n][ks], acc[m][n], 0, 0, 0);

    SBAR();
    if (kt + 2 < NT) {
      stage(p, kt + 2);
      WAITVM(6);
    } else if (kt + 1 < NT) {
      WAITVM(0);
    }
    SBAR();
  }

#pragma unroll
  for (int m = 0; m < 4; ++m) {
#pragma unroll
    for (int n = 0; n < 2; ++n) {
      const int grow0 = row0 + wm * 64 + m * 16 + (lane >> 4) * 4;
      const int gcol = col0 + wn * 32 + n * 16 + (lane & 15);
#pragma unroll
      for (int r = 0; r < 4; ++r) {
        const size_t idx = (size_t)(grow0 + r) * Nc + gcol;
        if (OUT_F32) Cf32[idx] = acc[m][n][r] + bias[gcol];
        else         Cf16[idx] = (f16_t)acc[m][n][r];
      }
    }
  }
}

// ============ single-pass fp16 256x256 scores GEMM (8-phase) ============
// scores = QPh @ KPh^T, K = 1024, NT = 16.
#define TILE_ELEMS 16384   // 256 rows x 64 cols
#define UNIT_ELEMS 4096    // 64 rows x 64 cols
#define NT_SC 16

template <int V> struct ic { static constexpr int value = V; };

template <int MH>
__device__ __forceinline__ void load_A8f(const f16_t* Ab, int wm, int fr,
                                         int kq, int sw, f16x8 (&af)[4][2]) {
#pragma unroll
  for (int m = 0; m < 4; ++m) {
    const int row = wm * 128 + (MH * 4 + m) * 16 + fr;
#pragma unroll
    for (int ks = 0; ks < 2; ++ks)
      af[m][ks] = *(const f16x8*)&Ab[row * 64 + ((ks * 32 + kq) ^ sw)];
  }
}

template <int NH>
__device__ __forceinline__ void load_B4f(const f16_t* Bb, int wn, int fr,
                                         int kq, int sw, f16x8 (&bfr)[2][2]) {
#pragma unroll
  for (int n = 0; n < 2; ++n) {
    const int row = wn * 64 + (NH * 2 + n) * 16 + fr;
#pragma unroll
    for (int ks = 0; ks < 2; ++ks)
      bfr[n][ks] = *(const f16x8*)&Bb[row * 64 + ((ks * 32 + kq) ^ sw)];
  }
}

template <int MH, int NH>
__device__ __forceinline__ void mfma16f(const f16x8 (&af)[4][2],
                                        const f16x8 (&bfr)[2][2],
                                        f32x4 (&acc)[8][4]) {
#pragma unroll
  for (int m = 0; m < 4; ++m)
#pragma unroll
    for (int n = 0; n < 2; ++n)
#pragma unroll
      for (int ks = 0; ks < 2; ++ks)
        acc[MH * 4 + m][NH * 2 + n] = __builtin_amdgcn_mfma_f32_16x16x32_f16(
            af[m][ks], bfr[n][ks], acc[MH * 4 + m][NH * 2 + n], 0, 0, 0);
}

__global__ __launch_bounds__(512, 1)
void gemm8f_scores(const f16_t* __restrict__ Qh, const f16_t* __restrict__ Kh,
                   float* __restrict__ C)
{
  __shared__ __align__(16) f16_t sm[2 * 2 * TILE_ELEMS];  // 128 KiB

  const int t = threadIdx.x;
  const int lane = t & 63;
  const int wave = t >> 6;
  const int wm = wave >> 2;      // 0..1
  const int wn = wave & 3;       // 0..3

  // XCD-aware block swizzle: grid 16x16 = 256 blocks, 256 = 8*32 (bijective)
  const int flat = blockIdx.y * 16 + blockIdx.x;
  const int swzb = (flat & 7) * 32 + (flat >> 3);
  const int brow = (swzb >> 4) * 256;
  const int bcol = (swzb & 15) * 256;

  const int srow = t >> 3;                               // 0..63
  const int scol = 8 * ((t & 7) ^ ((t >> 3) & 7));       // involution
  const int sdst = t * 8;

  const int fr = lane & 15;
  const int kq = (lane >> 4) * 8;
  const int sw = (fr & 7) << 3;                          // read-side swizzle

  auto stageA = [&](int buf, int u, int kt) {
    const int kk = kt << 6;
    gload16(Qh + (size_t)(brow + u * 64 + srow) * DMODEL + kk + scol,
            &sm[(buf * 2 + 0) * TILE_ELEMS + u * UNIT_ELEMS + sdst]);
  };
  auto stageB = [&](int buf, int u, int kt) {
    const int kk = kt << 6;
    gload16(Kh + (size_t)(bcol + u * 64 + srow) * DMODEL + kk + scol,
            &sm[(buf * 2 + 1) * TILE_ELEMS + u * UNIT_ELEMS + sdst]);
  };

  f32x4 acc[8][4] = {};
  f16x8 af0[4][2], af1[4][2];
  f16x8 b0[2][2], b1[2][2];

  // ---- prologue: tile0 all 8 units; tile1's Ua, V01, Ub (6 loads).
#pragma unroll
  for (int u = 0; u < 4; ++u) stageA(0, u, 0);
#pragma unroll
  for (int u = 0; u < 4; ++u) stageB(0, u, 0);
  stageA(1, 0, 1); stageA(1, 2, 1);   // Ua(1)
  stageB(1, 0, 1); stageB(1, 1, 1);   // V01(1)
  stageA(1, 1, 1); stageA(1, 3, 1);   // Ub(1)
  WAITVM(6);  // tile0's 8 landed
  SBAR();

  auto tile = [&](auto Pc, int kt) {
    constexpr int p = decltype(Pc)::value;
    constexpr int q = p ^ 1;
    const bool n1 = (kt + 1 < NT_SC);
    const bool n2 = (kt + 2 < NT_SC);
    const f16_t* Ab = &sm[(p * 2 + 0) * TILE_ELEMS];
    const f16_t* Bb = &sm[(p * 2 + 1) * TILE_ELEMS];

    // ---- Phase 1
    load_A8f<0>(Ab, wm, fr, kq, sw, af0);
    load_B4f<0>(Bb, wn, fr, kq, sw, b0);
    if (n1) { stageB(q, 2, kt + 1); stageB(q, 3, kt + 1); }
    load_B4f<1>(Bb, wn, fr, kq, sw, b1);
    WAITLGKM(4);
    __builtin_amdgcn_s_setprio(1);
    mfma16f<0, 0>(af0, b0, acc);
    __builtin_amdgcn_s_setprio(0);
    __builtin_amdgcn_sched_barrier(0);
    SBAR();

    // ---- Phase 2
    if (n2) { stageA(p, 0, kt + 2); stageA(p, 2, kt + 2); }
    load_A8f<1>(Ab, wm, fr, kq, sw, af1);
    WAITLGKM(8);
    __builtin_amdgcn_s_setprio(1);
    mfma16f<0, 1>(af0, b1, acc);
    __builtin_amdgcn_s_setprio(0);
    __builtin_amdgcn_sched_barrier(0);
    SBAR();

    // ---- Phase 3
    if (n2) { stageB(p, 0, kt + 2); stageB(p, 1, kt + 2); }
    WAITLGKM(0);
    __builtin_amdgcn_s_setprio(1);
    mfma16f<1, 0>(af1, b0, acc);
    __builtin_amdgcn_s_setprio(0);
    __builtin_amdgcn_sched_barrier(0);
    SBAR();

    // ---- Phase 4
    if (n2) { stageA(p, 1, kt + 2); stageA(p, 3, kt + 2); }
    __builtin_amdgcn_s_setprio(1);
    mfma16f<1, 1>(af1, b1, acc);
    __builtin_amdgcn_s_setprio(0);
    __builtin_amdgcn_sched_barrier(0);
    if (n2)      WAITVM(6);
    else if (n1) WAITVM(0);
    SBAR();
  };

  for (int kt = 0; kt < NT_SC; kt += 2) {
    tile(ic<0>{}, kt);
    tile(ic<1>{}, kt + 1);
  }

  // ---- epilogue
#pragma unroll
  for (int mf = 0; mf < 8; ++mf) {
#pragma unroll
    for (int nf = 0; nf < 4; ++nf) {
      const int r0 = brow + wm * 128 + mf * 16 + (lane >> 4) * 4;
      const int c  = bcol + wn * 64 + nf * 16 + (lane & 15);
#pragma unroll
      for (int r = 0; r < 4; ++r)
        C[(size_t)(r0 + r) * N_SEQ + c] = acc[mf][nf][r];
    }
  }
}

// ======================= fused split (all fp16) =======================
struct SplitDesc {
  const float* src[7];
  f16_t* hi[7];
  f16_t* lo[7];
  int mode[7];
  int blk_start[8];
};

__global__ __launch_bounds__(256)
void split_all(SplitDesc d)
{
  const int b = blockIdx.x;
  int seg = 0;
#pragma unroll
  for (int s = 1; s < 7; ++s) seg += (b >= d.blk_start[s]) ? 1 : 0;
  const int i = (b - d.blk_start[seg]) * 256 + threadIdx.x;
  const float4 v = ((const float4*)d.src[seg])[i];
  const float vv[4] = {v.x, v.y, v.z, v.w};
  f16x4 h, l;
#pragma unroll
  for (int j = 0; j < 4; ++j) {
    const f16_t hh = (f16_t)vv[j];
    h[j] = hh;
    l[j] = (f16_t)(vv[j] - (float)hh);
  }
  ((f16x4*)d.hi[seg])[i] = h;
  if (d.mode[seg] == 2) ((f16x4*)d.lo[seg])[i] = l;
}

// ======================= softmax =======================
__global__ __launch_bounds__(256)
void softmax_rows(float* __restrict__ S, f16_t* __restrict__ P, int n)
{
  const int row = blockIdx.x;
  float* srow = S + (size_t)row * n;
  f16_t* prow = P + (size_t)row * n;
  const int t = threadIdx.x;
  const int lane = t & 63;
  const int wave = t >> 6;
  __shared__ float red[8];

  float4 v[4];
  float mx = -3.4e38f;
#pragma unroll
  for (int i = 0; i < 4; ++i) {
    v[i] = *(const float4*)(srow + (size_t)(i * 256 + t) * 4);
    mx = fmaxf(mx, fmaxf(fmaxf(v[i].x, v[i].y), fmaxf(v[i].z, v[i].w)));
  }
#pragma unroll
  for (int off = 32; off > 0; off >>= 1) mx = fmaxf(mx, __shfl_xor(mx, off));
  if (lane == 0) red[wave] = mx;
  __syncthreads();
  mx = fmaxf(fmaxf(red[0], red[1]), fmaxf(red[2], red[3]));

  float e[16];
  float sum = 0.f;
#pragma unroll
  for (int i = 0; i < 4; ++i) {
    e[4 * i + 0] = __expf(v[i].x - mx);
    e[4 * i + 1] = __expf(v[i].y - mx);
    e[4 * i + 2] = __expf(v[i].z - mx);
    e[4 * i + 3] = __expf(v[i].w - mx);
    sum += e[4 * i + 0] + e[4 * i + 1] + e[4 * i + 2] + e[4 * i + 3];
  }
#pragma unroll
  for (int off = 32; off > 0; off >>= 1) sum += __shfl_xor(sum, off);
  if (lane == 0) red[4 + wave] = sum;
  __syncthreads();
  sum = red[4] + red[5] + red[6] + red[7];
  const float inv = 1.0f / sum;

#pragma unroll
  for (int i = 0; i < 4; ++i) {
    float4 w;
    w.x = e[4 * i + 0] * inv;
    w.y = e[4 * i + 1] * inv;
    w.z = e[4 * i + 2] * inv;
    w.w = e[4 * i + 3] * inv;
    *(float4*)(srow + (size_t)(i * 256 + t) * 4) = w;
    f16x4 p;
    p[0] = (f16_t)w.x;
    p[1] = (f16_t)w.y;
    p[2] = (f16_t)w.z;
    p[3] = (f16_t)w.w;
    *(f16x4*)(prow + (size_t)(i * 256 + t) * 4) = p;
  }
}

extern "C" void kernel_launch(void* const* d_in, const int* in_sizes, int n_in,
                              void* d_out, int out_size, void* d_ws, size_t ws_size,
                              hipStream_t stream) {
  const int N = N_SEQ, D = DMODEL;
  const float* q    = (const float*)d_in[0];
  const float* k    = (const float*)d_in[1];
  const float* v    = (const float*)d_in[2];
  const float* wq_w = (const float*)d_in[3];
  const float* wq_b = (const float*)d_in[4];
  const float* wk_w = (const float*)d_in[5];
  const float* wk_b = (const float*)d_in[6];
  const float* wv_w = (const float*)d_in[7];
  const float* wv_b = (const float*)d_in[8];
  const float* wo_w = (const float*)d_in[9];
  const float* wo_b = (const float*)d_in[10];

  float* x_out = (float*)d_out;                 // [N, D]
  float* attn  = x_out + (size_t)N * D;         // [N, N]

  char* wsp = (char*)d_ws;
  auto alloc = [&](size_t bytes) { char* p = wsp; wsp += bytes; return p; };
  const size_t ND = (size_t)N * D, DD = (size_t)D * D;
  f16_t*  qh16  = (f16_t*)alloc(ND * 2);
  f16_t*  ql16  = (f16_t*)alloc(ND * 2);
  f16_t*  kh16  = (f16_t*)alloc(ND * 2);
  f16_t*  kl16  = (f16_t*)alloc(ND * 2);
  f16_t*  vh16  = (f16_t*)alloc(ND * 2);
  f16_t*  wq16  = (f16_t*)alloc(DD * 2);
  f16_t*  wk16  = (f16_t*)alloc(DD * 2);
  f16_t*  wv16  = (f16_t*)alloc(DD * 2);
  f16_t*  wo16  = (f16_t*)alloc(DD * 2);
  f16_t*  QPh   = (f16_t*)alloc(ND * 2);        // fp16 qp
  f16_t*  pad1  = (f16_t*)alloc(ND * 2);        // keeps Pb region contiguous
  f16_t*  KPh   = (f16_t*)alloc(ND * 2);        // fp16 kp
  f16_t*  pad2  = (f16_t*)alloc(ND * 2);
  f16_t*  VPt   = (f16_t*)alloc(ND * 2);        // [D][N] transposed fp16
  // aliases (producers run strictly after last readers of the underlying bufs)
  f16_t*  Pb    = QPh;          // 32 MB over QPh..pad2 (dead after scores)
  f16_t*  Xb    = vh16;         // 8 MB over vh16 (dead after qkv_proj)
  (void)pad1; (void)pad2;

  // fused split: q,k -> fp16 hi+lo; v + all weights -> single fp16
  SplitDesc sd;
  sd.src[0] = q;    sd.hi[0] = qh16;  sd.lo[0] = ql16;    sd.mode[0] = 2;
  sd.src[1] = k;    sd.hi[1] = kh16;  sd.lo[1] = kl16;    sd.mode[1] = 2;
  sd.src[2] = v;    sd.hi[2] = vh16;  sd.lo[2] = nullptr; sd.mode[2] = 3;
  sd.src[3] = wq_w; sd.hi[3] = wq16;  sd.lo[3] = nullptr; sd.mode[3] = 3;
  sd.src[4] = wk_w; sd.hi[4] = wk16;  sd.lo[4] = nullptr; sd.mode[4] = 3;
  sd.src[5] = wv_w; sd.hi[5] = wv16;  sd.lo[5] = nullptr; sd.mode[5] = 3;
  sd.src[6] = wo_w; sd.hi[6] = wo16;  sd.lo[6] = nullptr; sd.mode[6] = 3;
  const int nb_nd = (int)(ND / 4 / 256);   // 4096
  const int nb_dd = (int)(DD / 4 / 256);   // 1024
  sd.blk_start[0] = 0;
  sd.blk_start[1] = nb_nd;
  sd.blk_start[2] = 2 * nb_nd;
  sd.blk_start[3] = 3 * nb_nd;
  sd.blk_start[4] = 3 * nb_nd + nb_dd;
  sd.blk_start[5] = 3 * nb_nd + 2 * nb_dd;
  sd.blk_start[6] = 3 * nb_nd + 3 * nb_dd;
  sd.blk_start[7] = 3 * nb_nd + 4 * nb_dd;
  split_all<<<dim3(sd.blk_start[7]), dim3(256), 0, stream>>>(sd);

  const dim3 blk(256);
  const dim3 gsc(N / 256, N / 256);    // (16, 16)
  const dim3 gd(D / BN2, N / BM);      // (16, 32) = 512 blocks

  // fused Q/K/V projections: Q 2-pass, K 2-pass, V 1-pass (48 KiB LDS)
  qkv_proj<<<dim3(D / BN, N / BM, 3), blk, 0, stream>>>(
      qh16, ql16, wq16, wq_b,
      kh16, kl16, wk16, wk_b,
      vh16, wv16, wv_b,
      QPh, KPh, VPt);

  // scores = QPh @ KPh^T  (single-pass fp16, K=1024)
  gemm8f_scores<<<gsc, dim3(512), 0, stream>>>(QPh, KPh, attn);

  // softmax rows in-place + fp16 copy (Pb aliases QP/KP region: dead now)
  softmax_rows<<<dim3(N), blk, 0, stream>>>(attn, Pb, N);

  // X = P @ VP  (pipelined dbuf BK=64, full K=4096 -> fp16 Xb)
  gemm_f16p<0><<<gd, blk, 0, stream>>>(
      Pb, VPt, nullptr, Xb, nullptr, N, D, N);

  // out = X @ wo^T + b  (pipelined dbuf BK=64, K=1024 -> fp32 d_out + bias)
  gemm_f16p<1><<<gd, blk, 0, stream>>>(
      Xb, wo16, wo_b, nullptr, x_out, N, D, D);
}

// Round 18
// 195.633 us; speedup vs baseline: 1.4555x; 1.0690x over previous
//
#include <hip/hip_runtime.h>
#include <cstdint>

// Problem constants (fixed by the reference)
#define N_SEQ 4096
#define DMODEL 1024

#define BM 128
#define BN 128
#define BN2 64
#define UNITE 4096   // one 64x64 f16 unit (8 KiB)

typedef __bf16 bf16_t;
typedef _Float16 f16_t;
typedef f16_t f16x8 __attribute__((ext_vector_type(8)));
typedef f16_t f16x4 __attribute__((ext_vector_type(4)));
typedef float f32x4 __attribute__((ext_vector_type(4)));

typedef __attribute__((address_space(1))) void* as1ptr;
typedef __attribute__((address_space(3))) void* as3ptr;

__device__ __forceinline__ void gload16(const void* g, void* l) {
  __builtin_amdgcn_global_load_lds((as1ptr)(uintptr_t)g, (as3ptr)(uintptr_t)l,
                                   16, 0, 0);
}

#define SBAR() asm volatile("s_barrier" ::: "memory")
#define WAITLGKM(n)                                              \
  do {                                                           \
    asm volatile("s_waitcnt lgkmcnt(" #n ")" ::: "memory");      \
    __builtin_amdgcn_sched_barrier(0);                           \
  } while (0)
#define WAITVM(n) asm volatile("s_waitcnt vmcnt(" #n ")" ::: "memory")

// ================= fused QKV projection (z = 0:Q, 1:K, 2:V) =================
// All-fp16, BK=64 swizzled units.  LDS 48 KiB -> 3 blocks/CU.
__global__ __launch_bounds__(256)
void qkv_proj(const f16_t* __restrict__ qh, const f16_t* __restrict__ ql,
              const f16_t* __restrict__ wq, const float* __restrict__ wq_b,
              const f16_t* __restrict__ kh, const f16_t* __restrict__ kl,
              const f16_t* __restrict__ wk, const float* __restrict__ wk_b,
              const f16_t* __restrict__ vh, const f16_t* __restrict__ wv,
              const float* __restrict__ wv_b,
              f16_t* __restrict__ QPh, f16_t* __restrict__ KPh,
              f16_t* __restrict__ VPt)
{
  __shared__ __align__(16) f16_t lds[6 * UNITE];   // 48 KiB

  const int z = blockIdx.z;
  const f16_t *A0, *A1 = nullptr, *B0;
  const float* bias;
  if (z == 0)      { A0 = qh; A1 = ql; B0 = wq; bias = wq_b; }
  else if (z == 1) { A0 = kh; A1 = kl; B0 = wk; bias = wk_b; }
  else             { A0 = vh;          B0 = wv; bias = wv_b; }
  const bool twop = (z < 2);

  const int M = N_SEQ, Nc = DMODEL, K = DMODEL;
  const int t = threadIdx.x;
  const int lane = t & 63;
  const int wave = t >> 6;
  const int wm = wave >> 1;
  const int wn = wave & 1;

  const int gx = gridDim.x;                       // 8
  const int nwg = gx * gridDim.y;                 // 256
  const int flat = blockIdx.y * gx + blockIdx.x;
  const int swz = (flat & 7) * (nwg >> 3) + (flat >> 3);
  const int row0 = (swz / gx) * BM;
  const int col0 = (swz % gx) * BN;

  const int srw = t >> 3;                                // 0..31
  const int scol = 8 * ((t & 7) ^ ((t >> 3) & 7));       // pre-swizzled src
  const int sdst = t * 8;

  const int fr = lane & 15;
  const int kq = (lane >> 4) * 8;
  const int sw = (fr & 7) << 3;                          // read-side swizzle

  f32x4 acc[4][4] = {};

  for (int k0 = 0; k0 < K; k0 += 64) {
#pragma unroll
    for (int h = 0; h < 2; ++h) {
      const int r = h * 32 + srw;
      gload16(A0 + (size_t)(row0 + r) * K + k0 + scol,
              &lds[0 * UNITE + h * 2048 + sdst]);
      gload16(A0 + (size_t)(row0 + 64 + r) * K + k0 + scol,
              &lds[1 * UNITE + h * 2048 + sdst]);
      gload16(B0 + (size_t)(col0 + r) * K + k0 + scol,
              &lds[4 * UNITE + h * 2048 + sdst]);
      gload16(B0 + (size_t)(col0 + 64 + r) * K + k0 + scol,
              &lds[5 * UNITE + h * 2048 + sdst]);
      if (twop) {
        gload16(A1 + (size_t)(row0 + r) * K + k0 + scol,
                &lds[2 * UNITE + h * 2048 + sdst]);
        gload16(A1 + (size_t)(row0 + 64 + r) * K + k0 + scol,
                &lds[3 * UNITE + h * 2048 + sdst]);
      }
    }
    __syncthreads();

    f16x8 ah[4][2], al[4][2], bh[4][2];
#pragma unroll
    for (int m = 0; m < 4; ++m) {
      const int r = (m * 16 + fr) * 64;
#pragma unroll
      for (int ks = 0; ks < 2; ++ks) {
        const int c = (ks * 32 + kq) ^ sw;
        ah[m][ks] = *(const f16x8*)&lds[wm * UNITE + r + c];
        if (twop) al[m][ks] = *(const f16x8*)&lds[(2 + wm) * UNITE + r + c];
      }
    }
#pragma unroll
    for (int n = 0; n < 4; ++n) {
      const int r = (n * 16 + fr) * 64;
#pragma unroll
      for (int ks = 0; ks < 2; ++ks)
        bh[n][ks] = *(const f16x8*)&lds[(4 + wn) * UNITE + r +
                                        (((ks * 32 + kq)) ^ sw)];
    }

#pragma unroll
    for (int m = 0; m < 4; ++m)
#pragma unroll
      for (int n = 0; n < 4; ++n)
#pragma unroll
        for (int ks = 0; ks < 2; ++ks) {
          acc[m][n] = __builtin_amdgcn_mfma_f32_16x16x32_f16(
              ah[m][ks], bh[n][ks], acc[m][n], 0, 0, 0);
          if (twop)
            acc[m][n] = __builtin_amdgcn_mfma_f32_16x16x32_f16(
                al[m][ks], bh[n][ks], acc[m][n], 0, 0, 0);
        }
    __syncthreads();
  }

#pragma unroll
  for (int m = 0; m < 4; ++m) {
#pragma unroll
    for (int n = 0; n < 4; ++n) {
      const int grow0 = row0 + wm * 64 + m * 16 + (lane >> 4) * 4;
      const int gcol = col0 + wn * 64 + n * 16 + (lane & 15);
      const float bv = bias[gcol];
      if (z == 2) {
        f16x4 p;
#pragma unroll
        for (int r = 0; r < 4; ++r) p[r] = (f16_t)(acc[m][n][r] + bv);
        *(f16x4*)&VPt[(size_t)gcol * M + grow0] = p;
      } else {
        f16_t* out = (z == 0) ? QPh : KPh;
#pragma unroll
        for (int r = 0; r < 4; ++r)
          out[(size_t)(grow0 + r) * Nc + gcol] = (f16_t)(acc[m][n][r] + bv);
      }
    }
  }
}

// ====== pipelined fp16 GEMM, 128x64 tile, BK=64 double-buffered ======
template <int OUT_F32>
__global__ __launch_bounds__(256)
void gemm_f16p(const f16_t* __restrict__ A, const f16_t* __restrict__ B,
               const float* __restrict__ bias,
               f16_t* __restrict__ Cf16, float* __restrict__ Cf32,
               int M, int Nc, int K)
{
  __shared__ __align__(16) f16_t lds[2 * 3 * UNITE];   // 48 KiB

  const int gx = gridDim.x;
  const int nwg = gx * gridDim.y;
  const int flat = blockIdx.y * gx + blockIdx.x;
  const int swz = (flat & 7) * (nwg >> 3) + (flat >> 3);
  const int bx = swz % gx;
  const int by = swz / gx;

  const int t = threadIdx.x;
  const int lane = t & 63;
  const int wave = t >> 6;
  const int wm = wave >> 1;
  const int wn = wave & 1;
  const int row0 = by * BM;
  const int col0 = bx * BN2;

  const int srw = t >> 3;
  const int scol = 8 * ((t & 7) ^ ((t >> 3) & 7));
  const int sdst = t * 8;

  const int fr = lane & 15;
  const int kq = (lane >> 4) * 8;
  const int sw = (fr & 7) << 3;

  auto stage = [&](int buf, int kt) {
    const int k0 = kt << 6;
#pragma unroll
    for (int h = 0; h < 2; ++h) {
      const int r = h * 32 + srw;
      gload16(A + (size_t)(row0 + r) * K + k0 + scol,
              &lds[(buf * 3 + 0) * UNITE + h * 2048 + sdst]);
      gload16(A + (size_t)(row0 + 64 + r) * K + k0 + scol,
              &lds[(buf * 3 + 1) * UNITE + h * 2048 + sdst]);
      gload16(B + (size_t)(col0 + r) * K + k0 + scol,
              &lds[(buf * 3 + 2) * UNITE + h * 2048 + sdst]);
    }
  };

  f32x4 acc[4][2] = {};
  const int NT = K >> 6;

  stage(0, 0);
  stage(1, 1);
  WAITVM(6);
  SBAR();

  for (int kt = 0; kt < NT; ++kt) {
    const int p = kt & 1;
    const f16_t* Ab = &lds[(p * 3 + wm) * UNITE];
    const f16_t* Bb = &lds[(p * 3 + 2) * UNITE];

    f16x8 ah[4][2], bh[2][2];
#pragma unroll
    for (int m = 0; m < 2; ++m)
#pragma unroll
      for (int ks = 0; ks < 2; ++ks)
        ah[m][ks] = *(const f16x8*)&Ab[(m * 16 + fr) * 64 +
                                       ((ks * 32 + kq) ^ sw)];
#pragma unroll
    for (int n = 0; n < 2; ++n)
#pragma unroll
      for (int ks = 0; ks < 2; ++ks)
        bh[n][ks] = *(const f16x8*)&Bb[(wn * 32 + n * 16 + fr) * 64 +
                                       ((ks * 32 + kq) ^ sw)];
#pragma unroll
    for (int m = 2; m < 4; ++m)
#pragma unroll
      for (int ks = 0; ks < 2; ++ks)
        ah[m][ks] = *(const f16x8*)&Ab[(m * 16 + fr) * 64 +
                                       ((ks * 32 + kq) ^ sw)];

    WAITLGKM(4);
#pragma unroll
    for (int m = 0; m < 2; ++m)
#pragma unroll
      for (int n = 0; n < 2; ++n)
#pragma unroll
        for (int ks = 0; ks < 2; ++ks)
          acc[m][n] = __builtin_amdgcn_mfma_f32_16x16x32_f16(
              ah[m][ks], bh[n][ks], acc[m][n], 0, 0, 0);
    WAITLGKM(0);
#pragma unroll
    for (int m = 2; m < 4; ++m)
#pragma unroll
      for (int n = 0; n < 2; ++n)
#pragma unroll
        for (int ks = 0; ks < 2; ++ks)
          acc[m][n] = __builtin_amdgcn_mfma_f32_16x16x32_f16(
              ah[m][ks], bh[n][ks], acc[m][n], 0, 0, 0);

    SBAR();
    if (kt + 2 < NT) {
      stage(p, kt + 2);
      WAITVM(6);
    } else if (kt + 1 < NT) {
      WAITVM(0);
    }
    SBAR();
  }

#pragma unroll
  for (int m = 0; m < 4; ++m) {
#pragma unroll
    for (int n = 0; n < 2; ++n) {
      const int grow0 = row0 + wm * 64 + m * 16 + (lane >> 4) * 4;
      const int gcol = col0 + wn * 32 + n * 16 + (lane & 15);
#pragma unroll
      for (int r = 0; r < 4; ++r) {
        const size_t idx = (size_t)(grow0 + r) * Nc + gcol;
        if (OUT_F32) Cf32[idx] = acc[m][n][r] + bias[gcol];
        else         Cf16[idx] = (f16_t)acc[m][n][r];
      }
    }
  }
}

// ====== pipelined fp16 scores GEMM, 128x128 tile, BK=64 dbuf -> fp32 ======
// S = A @ B^T, K = 1024 (16 tiles).  LDS 64 KiB -> 2 blocks/CU.
// Grid (32,32) = 1024 blocks (4x the 256^2 version) for overlap.
__global__ __launch_bounds__(256)
void gemm_f16s(const f16_t* __restrict__ A, const f16_t* __restrict__ B,
               float* __restrict__ C, int M, int Nc, int K)
{
  __shared__ __align__(16) f16_t lds[2 * 4 * UNITE];   // 64 KiB

  const int gx = gridDim.x;
  const int nwg = gx * gridDim.y;
  const int flat = blockIdx.y * gx + blockIdx.x;
  const int swz = (flat & 7) * (nwg >> 3) + (flat >> 3);
  const int bx = swz % gx;
  const int by = swz / gx;

  const int t = threadIdx.x;
  const int lane = t & 63;
  const int wave = t >> 6;
  const int wm = wave >> 1;     // 0..1 (64-row half)
  const int wn = wave & 1;      // 0..1 (64-col half)
  const int row0 = by * BM;
  const int col0 = bx * BN;

  const int srw = t >> 3;                                // 0..31
  const int scol = 8 * ((t & 7) ^ ((t >> 3) & 7));       // pre-swizzled src
  const int sdst = t * 8;

  const int fr = lane & 15;
  const int kq = (lane >> 4) * 8;
  const int sw = (fr & 7) << 3;                          // read-side swizzle

  auto stage = [&](int buf, int kt) {
    const int k0 = kt << 6;
#pragma unroll
    for (int h = 0; h < 2; ++h) {
      const int r = h * 32 + srw;
      gload16(A + (size_t)(row0 + r) * K + k0 + scol,
              &lds[(buf * 4 + 0) * UNITE + h * 2048 + sdst]);
      gload16(A + (size_t)(row0 + 64 + r) * K + k0 + scol,
              &lds[(buf * 4 + 1) * UNITE + h * 2048 + sdst]);
      gload16(B + (size_t)(col0 + r) * K + k0 + scol,
              &lds[(buf * 4 + 2) * UNITE + h * 2048 + sdst]);
      gload16(B + (size_t)(col0 + 64 + r) * K + k0 + scol,
              &lds[(buf * 4 + 3) * UNITE + h * 2048 + sdst]);
    }
  };

  f32x4 acc[4][4] = {};
  const int NT = K >> 6;   // 16

  stage(0, 0);
  stage(1, 1);
  WAITVM(8);
  SBAR();

  for (int kt = 0; kt < NT; ++kt) {
    const int p = kt & 1;
    const f16_t* Ab = &lds[(p * 4 + wm) * UNITE];
    const f16_t* Bb = &lds[(p * 4 + 2 + wn) * UNITE];

    f16x8 ah[4][2], bh[4][2];
    // set-1: A all (8 reads) + B n0,n1 (4 reads)
#pragma unroll
    for (int m = 0; m < 4; ++m)
#pragma unroll
      for (int ks = 0; ks < 2; ++ks)
        ah[m][ks] = *(const f16x8*)&Ab[(m * 16 + fr) * 64 +
                                       ((ks * 32 + kq) ^ sw)];
#pragma unroll
    for (int n = 0; n < 2; ++n)
#pragma unroll
      for (int ks = 0; ks < 2; ++ks)
        bh[n][ks] = *(const f16x8*)&Bb[(n * 16 + fr) * 64 +
                                       ((ks * 32 + kq) ^ sw)];
    // set-2: B n2,n3 (4 reads), pipelined behind set-1 MFMA
#pragma unroll
    for (int n = 2; n < 4; ++n)
#pragma unroll
      for (int ks = 0; ks < 2; ++ks)
        bh[n][ks] = *(const f16x8*)&Bb[(n * 16 + fr) * 64 +
                                       ((ks * 32 + kq) ^ sw)];

    WAITLGKM(4);                 // set-1 (12 oldest) drained
#pragma unroll
    for (int m = 0; m < 4; ++m)
#pragma unroll
      for (int n = 0; n < 2; ++n)
#pragma unroll
        for (int ks = 0; ks < 2; ++ks)
          acc[m][n] = __builtin_amdgcn_mfma_f32_16x16x32_f16(
              ah[m][ks], bh[n][ks], acc[m][n], 0, 0, 0);
    WAITLGKM(0);                 // set-2 drained
#pragma unroll
    for (int m = 0; m < 4; ++m)
#pragma unroll
      for (int n = 2; n < 4; ++n)
#pragma unroll
        for (int ks = 0; ks < 2; ++ks)
          acc[m][n] = __builtin_amdgcn_mfma_f32_16x16x32_f16(
              ah[m][ks], bh[n][ks], acc[m][n], 0, 0, 0);

    SBAR();                      // all waves done reading buf p
    if (kt + 2 < NT) {
      stage(p, kt + 2);
      WAITVM(8);                 // own tile-(kt+1) stages landed
    } else if (kt + 1 < NT) {
      WAITVM(0);
    }
    SBAR();                      // all waves' tile-(kt+1) stages landed
  }

  // epilogue: fp32 write
#pragma unroll
  for (int m = 0; m < 4; ++m) {
#pragma unroll
    for (int n = 0; n < 4; ++n) {
      const int grow0 = row0 + wm * 64 + m * 16 + (lane >> 4) * 4;
      const int gcol = col0 + wn * 64 + n * 16 + (lane & 15);
#pragma unroll
      for (int r = 0; r < 4; ++r)
        C[(size_t)(grow0 + r) * Nc + gcol] = acc[m][n][r];
    }
  }
}

// ======================= fused split (all fp16) =======================
struct SplitDesc {
  const float* src[7];
  f16_t* hi[7];
  f16_t* lo[7];
  int mode[7];
  int blk_start[8];
};

__global__ __launch_bounds__(256)
void split_all(SplitDesc d)
{
  const int b = blockIdx.x;
  int seg = 0;
#pragma unroll
  for (int s = 1; s < 7; ++s) seg += (b >= d.blk_start[s]) ? 1 : 0;
  const int i = (b - d.blk_start[seg]) * 256 + threadIdx.x;
  const float4 v = ((const float4*)d.src[seg])[i];
  const float vv[4] = {v.x, v.y, v.z, v.w};
  f16x4 h, l;
#pragma unroll
  for (int j = 0; j < 4; ++j) {
    const f16_t hh = (f16_t)vv[j];
    h[j] = hh;
    l[j] = (f16_t)(vv[j] - (float)hh);
  }
  ((f16x4*)d.hi[seg])[i] = h;
  if (d.mode[seg] == 2) ((f16x4*)d.lo[seg])[i] = l;
}

// ======================= softmax (fp32 in-place + fp16 P) =======================
__global__ __launch_bounds__(256)
void softmax_rows(float* __restrict__ S, f16_t* __restrict__ P, int n)
{
  const int row = blockIdx.x;
  float* srow = S + (size_t)row * n;
  f16_t* prow = P + (size_t)row * n;
  const int t = threadIdx.x;
  const int lane = t & 63;
  const int wave = t >> 6;
  __shared__ float red[8];

  float4 v[4];
  float mx = -3.4e38f;
#pragma unroll
  for (int i = 0; i < 4; ++i) {
    v[i] = *(const float4*)(srow + (size_t)(i * 256 + t) * 4);
    mx = fmaxf(mx, fmaxf(fmaxf(v[i].x, v[i].y), fmaxf(v[i].z, v[i].w)));
  }
#pragma unroll
  for (int off = 32; off > 0; off >>= 1) mx = fmaxf(mx, __shfl_xor(mx, off));
  if (lane == 0) red[wave] = mx;
  __syncthreads();
  mx = fmaxf(fmaxf(red[0], red[1]), fmaxf(red[2], red[3]));

  float e[16];
  float sum = 0.f;
#pragma unroll
  for (int i = 0; i < 4; ++i) {
    e[4 * i + 0] = __expf(v[i].x - mx);
    e[4 * i + 1] = __expf(v[i].y - mx);
    e[4 * i + 2] = __expf(v[i].z - mx);
    e[4 * i + 3] = __expf(v[i].w - mx);
    sum += e[4 * i + 0] + e[4 * i + 1] + e[4 * i + 2] + e[4 * i + 3];
  }
#pragma unroll
  for (int off = 32; off > 0; off >>= 1) sum += __shfl_xor(sum, off);
  if (lane == 0) red[4 + wave] = sum;
  __syncthreads();
  sum = red[4] + red[5] + red[6] + red[7];
  const float inv = 1.0f / sum;

#pragma unroll
  for (int i = 0; i < 4; ++i) {
    float4 w;
    w.x = e[4 * i + 0] * inv;
    w.y = e[4 * i + 1] * inv;
    w.z = e[4 * i + 2] * inv;
    w.w = e[4 * i + 3] * inv;
    *(float4*)(srow + (size_t)(i * 256 + t) * 4) = w;
    f16x4 p;
    p[0] = (f16_t)w.x;
    p[1] = (f16_t)w.y;
    p[2] = (f16_t)w.z;
    p[3] = (f16_t)w.w;
    *(f16x4*)(prow + (size_t)(i * 256 + t) * 4) = p;
  }
}

extern "C" void kernel_launch(void* const* d_in, const int* in_sizes, int n_in,
                              void* d_out, int out_size, void* d_ws, size_t ws_size,
                              hipStream_t stream) {
  const int N = N_SEQ, D = DMODEL;
  const float* q    = (const float*)d_in[0];
  const float* k    = (const float*)d_in[1];
  const float* v    = (const float*)d_in[2];
  const float* wq_w = (const float*)d_in[3];
  const float* wq_b = (const float*)d_in[4];
  const float* wk_w = (const float*)d_in[5];
  const float* wk_b = (const float*)d_in[6];
  const float* wv_w = (const float*)d_in[7];
  const float* wv_b = (const float*)d_in[8];
  const float* wo_w = (const float*)d_in[9];
  const float* wo_b = (const float*)d_in[10];

  float* x_out = (float*)d_out;                 // [N, D]
  float* attn  = x_out + (size_t)N * D;         // [N, N]

  char* wsp = (char*)d_ws;
  auto alloc = [&](size_t bytes) { char* p = wsp; wsp += bytes; return p; };
  const size_t ND = (size_t)N * D, DD = (size_t)D * D;
  f16_t*  qh16  = (f16_t*)alloc(ND * 2);
  f16_t*  ql16  = (f16_t*)alloc(ND * 2);
  f16_t*  kh16  = (f16_t*)alloc(ND * 2);
  f16_t*  kl16  = (f16_t*)alloc(ND * 2);
  f16_t*  vh16  = (f16_t*)alloc(ND * 2);
  f16_t*  wq16  = (f16_t*)alloc(DD * 2);
  f16_t*  wk16  = (f16_t*)alloc(DD * 2);
  f16_t*  wv16  = (f16_t*)alloc(DD * 2);
  f16_t*  wo16  = (f16_t*)alloc(DD * 2);
  f16_t*  QPh   = (f16_t*)alloc(ND * 2);        // fp16 qp
  f16_t*  pad1  = (f16_t*)alloc(ND * 2);
  f16_t*  KPh   = (f16_t*)alloc(ND * 2);        // fp16 kp
  f16_t*  pad2  = (f16_t*)alloc(ND * 2);
  f16_t*  VPt   = (f16_t*)alloc(ND * 2);        // [D][N] transposed fp16
  // aliases (producers run strictly after last readers of the underlying bufs)
  f16_t*  Pb    = QPh;    // 32 MB over QPh..pad2 (dead after scores)
  f16_t*  Xb    = vh16;   // 8 MB over vh16 (dead after qkv_proj)
  (void)pad1; (void)pad2;

  // fused split: q,k -> fp16 hi+lo; v + all weights -> single fp16
  SplitDesc sd;
  sd.src[0] = q;    sd.hi[0] = qh16;  sd.lo[0] = ql16;    sd.mode[0] = 2;
  sd.src[1] = k;    sd.hi[1] = kh16;  sd.lo[1] = kl16;    sd.mode[1] = 2;
  sd.src[2] = v;    sd.hi[2] = vh16;  sd.lo[2] = nullptr; sd.mode[2] = 3;
  sd.src[3] = wq_w; sd.hi[3] = wq16;  sd.lo[3] = nullptr; sd.mode[3] = 3;
  sd.src[4] = wk_w; sd.hi[4] = wk16;  sd.lo[4] = nullptr; sd.mode[4] = 3;
  sd.src[5] = wv_w; sd.hi[5] = wv16;  sd.lo[5] = nullptr; sd.mode[5] = 3;
  sd.src[6] = wo_w; sd.hi[6] = wo16;  sd.lo[6] = nullptr; sd.mode[6] = 3;
  const int nb_nd = (int)(ND / 4 / 256);   // 4096
  const int nb_dd = (int)(DD / 4 / 256);   // 1024
  sd.blk_start[0] = 0;
  sd.blk_start[1] = nb_nd;
  sd.blk_start[2] = 2 * nb_nd;
  sd.blk_start[3] = 3 * nb_nd;
  sd.blk_start[4] = 3 * nb_nd + nb_dd;
  sd.blk_start[5] = 3 * nb_nd + 2 * nb_dd;
  sd.blk_start[6] = 3 * nb_nd + 3 * nb_dd;
  sd.blk_start[7] = 3 * nb_nd + 4 * nb_dd;
  split_all<<<dim3(sd.blk_start[7]), dim3(256), 0, stream>>>(sd);

  const dim3 blk(256);
  const dim3 gsc(N / BN, N / BM);      // (32, 32) = 1024 blocks
  const dim3 gd(D / BN2, N / BM);      // (16, 32) = 512 blocks

  // fused Q/K/V projections: Q 2-pass, K 2-pass, V 1-pass (48 KiB LDS)
  qkv_proj<<<dim3(D / BN, N / BM, 3), blk, 0, stream>>>(
      qh16, ql16, wq16, wq_b,
      kh16, kl16, wk16, wk_b,
      vh16, wv16, wv_b,
      QPh, KPh, VPt);

  // scores = QPh @ KPh^T  (128x128 pipelined, K=1024, fp32 into d_out)
  gemm_f16s<<<gsc, blk, 0, stream>>>(QPh, KPh, attn, N, N, D);

  // softmax rows in-place + fp16 copy (Pb aliases QP/KP region: dead now)
  softmax_rows<<<dim3(N), blk, 0, stream>>>(attn, Pb, N);

  // X = P @ VP  (pipelined dbuf BK=64, full K=4096 -> fp16 Xb)
  gemm_f16p<0><<<gd, blk, 0, stream>>>(
      Pb, VPt, nullptr, Xb, nullptr, N, D, N);

  // out = X @ wo^T + b  (pipelined dbuf BK=64, K=1024 -> fp32 d_out + bias)
  gemm_f16p<1><<<gd, blk, 0, stream>>>(
      Xb, wo16, wo_b, nullptr, x_out, N, D, D);
}